// Round 8
// baseline (607.967 us; speedup 1.0000x reference)
//
#include <hip/hip_runtime.h>

#define B_ 32
#define L_ 256
#define D_ 768
#define H_ 12
#define DK_ 64
#define MEM_ 384

typedef __attribute__((ext_vector_type(8))) short bfrag8;    // 8 bf16 (4 VGPRs)
typedef __attribute__((ext_vector_type(8))) unsigned short us8;
typedef __attribute__((ext_vector_type(4))) float f32x4;

// f32 -> bf16 round-to-nearest-even (finite inputs only)
__device__ inline unsigned short f2bf(float f) {
  unsigned u = __float_as_uint(f);
  return (unsigned short)((u + 0x7fffu + ((u >> 16) & 1u)) >> 16);
}
__device__ inline float bf2f(unsigned short u) {
  return __uint_as_float(((unsigned)u) << 16);
}
__device__ inline float tanh_fast(float x) {
  x = fminf(fmaxf(x, -30.f), 30.f);
  float e = __expf(2.f * x);
  return (e - 1.f) * __builtin_amdgcn_rcpf(e + 1.f);
}

// ---------------- block reduce helpers (256 threads = 4 waves) ----------------
__device__ inline float waveRedSum(float v) {
#pragma unroll
  for (int o = 32; o; o >>= 1) v += __shfl_xor(v, o, 64);
  return v;
}
__device__ inline float waveRedMax(float v) {
#pragma unroll
  for (int o = 32; o; o >>= 1) v = fmaxf(v, __shfl_xor(v, o, 64));
  return v;
}
__device__ inline float blkRedSum(float v, float* red) {
  v = waveRedSum(v);
  int w = threadIdx.x >> 6;
  __syncthreads();
  if ((threadIdx.x & 63) == 0) red[w] = v;
  __syncthreads();
  return red[0] + red[1] + red[2] + red[3];
}
__device__ inline float blkRedMax(float v, float* red) {
  v = waveRedMax(v);
  int w = threadIdx.x >> 6;
  __syncthreads();
  if ((threadIdx.x & 63) == 0) red[w] = v;
  __syncthreads();
  return fmaxf(fmaxf(red[0], red[1]), fmaxf(red[2], red[3]));
}

// ---------------- LayerNorm (dual f32 + bf16 output) ----------------
__global__ __launch_bounds__(256) void ln_kernel(const float* __restrict__ in,
                                                 const float* __restrict__ g,
                                                 const float* __restrict__ bt,
                                                 float* __restrict__ out,
                                                 unsigned short* __restrict__ outbf) {
  long row = blockIdx.x;
  const float* p = in + row * D_;
  float v[3];
#pragma unroll
  for (int i = 0; i < 3; ++i) v[i] = p[threadIdx.x + i * 256];
  __shared__ float red[4];
  float s = v[0] + v[1] + v[2];
  s = blkRedSum(s, red);
  float mu = s * (1.f / D_);
  float ss = 0.f;
#pragma unroll
  for (int i = 0; i < 3; ++i) { float d = v[i] - mu; ss += d * d; }
  ss = blkRedSum(ss, red);
  float sd = sqrtf(ss * (1.f / (D_ - 1)));
  float inv = 1.f / (sd + 1e-6f);
#pragma unroll
  for (int i = 0; i < 3; ++i) {
    int c = threadIdx.x + i * 256;
    float o = g[c] * (v[i] - mu) * inv + bt[c];
    out[row * D_ + c] = o;
    outbf[row * D_ + c] = f2bf(o);
  }
}

// ---------------- transpose + convert: dst[C][R] bf16 = src[R][C] f32 ----------------
__global__ __launch_bounds__(256) void tc_pair(const float* __restrict__ s1,
                                               unsigned short* __restrict__ d1,
                                               const float* __restrict__ s2,
                                               unsigned short* __restrict__ d2,
                                               int R, int C) {
  const float* src = blockIdx.z ? s2 : s1;
  unsigned short* dst = blockIdx.z ? d2 : d1;
  __shared__ float tile[64][65];
  int c0 = blockIdx.x * 64, r0 = blockIdx.y * 64;
  int tx = threadIdx.x & 63, ty = threadIdx.x >> 6;
#pragma unroll
  for (int i = 0; i < 16; ++i)
    tile[ty + i * 4][tx] = src[(long)(r0 + ty + i * 4) * C + c0 + tx];
  __syncthreads();
#pragma unroll
  for (int i = 0; i < 16; ++i)
    dst[(long)(c0 + ty + i * 4) * R + r0 + tx] = f2bf(tile[tx][ty + i * 4]);
}

// ---------------- per-head transpose: wmT[h][e][d] = wm[h][d][e], bf16 ----------------
__global__ __launch_bounds__(256) void tc_wm(const float* __restrict__ wm,
                                             unsigned short* __restrict__ wmT) {
  int h = blockIdx.x;
  __shared__ float tile[64][65];
  int tx = threadIdx.x & 63, ty = threadIdx.x >> 6;
#pragma unroll
  for (int i = 0; i < 16; ++i)
    tile[ty + i * 4][tx] = wm[h * 4096 + (ty + i * 4) * 64 + tx];
  __syncthreads();
#pragma unroll
  for (int i = 0; i < 16; ++i)
    wmT[h * 4096 + (ty + i * 4) * 64 + tx] = f2bf(tile[tx][ty + i * 4]);
}

// ---------------- asp = bf16(mask_row * (x @ wd) + bd), MFMA, no LDS ----------------
__global__ __launch_bounds__(256) void asp_mfma(const unsigned short* __restrict__ xbf,
                                                const unsigned short* __restrict__ wdT,
                                                const float* __restrict__ amask,
                                                const float* __restrict__ bd,
                                                unsigned short* __restrict__ aspbf) {
  int l0 = blockIdx.x << 4;
  int t = threadIdx.x;
  int w = t >> 6, l = t & 63;
  int lr = l & 15, kg = (l >> 4) * 8;
  const unsigned short* ap = xbf + (long)(l0 + lr) * D_ + kg;
  const unsigned short* bp = wdT + (long)(w * 16 + lr) * D_ + kg;
  f32x4 acc = {};
#pragma unroll
  for (int k0 = 0; k0 < D_; k0 += 32) {
    bfrag8 af = *(const bfrag8*)(ap + k0);
    bfrag8 bf = *(const bfrag8*)(bp + k0);
    acc = __builtin_amdgcn_mfma_f32_16x16x32_bf16(af, bf, acc, 0, 0, 0);
  }
  int col = w * 16 + lr;
#pragma unroll
  for (int r = 0; r < 4; ++r) {
    int row = l0 + (l >> 4) * 4 + r;
    float v = acc[r] * amask[row] + bd[col];
    aspbf[(long)row * DK_ + col] = f2bf(v);
  }
}

// ---------------- tmpA[b,h] = aspbf[b] @ Wm[h], MFMA, no LDS ----------------
__global__ __launch_bounds__(256) void asp_wm_v2(const unsigned short* __restrict__ aspbf,
                                                 const unsigned short* __restrict__ wmT,
                                                 unsigned short* __restrict__ tmpA) {
  int bh = blockIdx.x;
  int b = bh / H_, h = bh % H_;
  int t = threadIdx.x;
  int w = t >> 6, l = t & 63;
  int lr = l & 15, kg = (l >> 4) * 8;
  const unsigned short* wp = wmT + h * 4096;
  f32x4 acc[4][4] = {};
#pragma unroll
  for (int ks = 0; ks < 2; ++ks) {
    int k0 = ks * 32;
    bfrag8 af[4], bf[4];
#pragma unroll
    for (int m = 0; m < 4; ++m)
      af[m] = *(const bfrag8*)(aspbf + (long)(b * L_ + w * 64 + m * 16 + lr) * DK_ + k0 + kg);
#pragma unroll
    for (int n = 0; n < 4; ++n)
      bf[n] = *(const bfrag8*)(wp + (n * 16 + lr) * 64 + k0 + kg);
#pragma unroll
    for (int m = 0; m < 4; ++m)
#pragma unroll
      for (int n = 0; n < 4; ++n)
        acc[m][n] = __builtin_amdgcn_mfma_f32_16x16x32_bf16(af[m], bf[n], acc[m][n], 0, 0, 0);
  }
#pragma unroll
  for (int m = 0; m < 4; ++m)
#pragma unroll
    for (int n = 0; n < 4; ++n)
#pragma unroll
      for (int r = 0; r < 4; ++r) {
        int row = w * 64 + m * 16 + (l >> 4) * 4 + r;
        int col = n * 16 + lr;
        tmpA[(((long)b * H_ + h) * L_ + row) * DK_ + col] = f2bf(acc[m][n][r]);
      }
}

// ---------------- all-bf16 MFMA GEMM, direct-global fragments (no operand LDS) -------
// A bf16 [m][k]; Bt bf16 [n][k]. 128x128 tile, 4 waves (2x2), 4x4 frags.
// Outputs: C f32, Cbf row-major bf16, CT bf16 transposed-per-256-row-group.
// Second operand set (z >= zsplit) pairs two independent same-shape GEMMs.
__global__ __launch_bounds__(256) void gemm_bb(
    const unsigned short* __restrict__ A, const unsigned short* __restrict__ Bt,
    float* __restrict__ C, unsigned short* __restrict__ Cbf,
    unsigned short* __restrict__ CT,
    int M, int N, int K, long sA, long sB, long sC, long sCT,
    const float* __restrict__ bias, const float* __restrict__ rowDiv, int relu,
    const unsigned short* __restrict__ A2, const unsigned short* __restrict__ Bt2,
    float* __restrict__ C2, unsigned short* __restrict__ Cbf2,
    unsigned short* __restrict__ CT2,
    const float* __restrict__ bias2, const float* __restrict__ rowDiv2, int zsplit) {
  __shared__ unsigned short Ts[64][136];  // CT epilogue only (17.4 KB)
  const int tid = threadIdx.x;
  const int bn = blockIdx.x, bm = blockIdx.y;
  int bz = blockIdx.z;
  const unsigned short* Ap = A; const unsigned short* Btp = Bt;
  float* Cp = C; unsigned short* Cbp = Cbf; unsigned short* CTp = CT;
  const float* biasp = bias; const float* rowDivp = rowDiv;
  if (zsplit > 0 && bz >= zsplit) {
    bz -= zsplit;
    Ap = A2; Btp = Bt2; Cp = C2; Cbp = Cbf2; CTp = CT2; biasp = bias2; rowDivp = rowDiv2;
  }
  Ap += (long)bz * sA; Btp += (long)bz * sB;
  if (Cp) Cp += (long)bz * sC;
  if (Cbp) Cbp += (long)bz * sC;
  if (CTp) CTp += (long)bz * sCT;

  f32x4 acc[4][4] = {};
  const int l = tid & 63, w = tid >> 6;
  const int wr = w >> 1, wc = w & 1;
  const int lr = l & 15, kg = (l >> 4) * 8;

  const unsigned short* ap[4];
  const unsigned short* bp[4];
#pragma unroll
  for (int m = 0; m < 4; ++m)
    ap[m] = Ap + (long)(bm * 128 + wr * 64 + m * 16 + lr) * K + kg;
#pragma unroll
  for (int n = 0; n < 4; ++n)
    bp[n] = Btp + (long)(bn * 128 + wc * 64 + n * 16 + lr) * K + kg;

#pragma unroll 4
  for (int k0 = 0; k0 < K; k0 += 32) {
    bfrag8 af[4], bf[4];
#pragma unroll
    for (int m = 0; m < 4; ++m) af[m] = *(const bfrag8*)(ap[m] + k0);
#pragma unroll
    for (int n = 0; n < 4; ++n) bf[n] = *(const bfrag8*)(bp[n] + k0);
#pragma unroll
    for (int m = 0; m < 4; ++m)
#pragma unroll
      for (int n = 0; n < 4; ++n)
        acc[m][n] = __builtin_amdgcn_mfma_f32_16x16x32_bf16(af[m], bf[n], acc[m][n], 0, 0, 0);
  }

  if (Cp || Cbp) {
#pragma unroll
    for (int m = 0; m < 4; ++m) {
#pragma unroll
      for (int r = 0; r < 4; ++r) {
        int row = bm * 128 + wr * 64 + m * 16 + (l >> 4) * 4 + r;
        float rd = rowDivp ? 1.f / rowDivp[(long)bz * M + row] : 1.f;
#pragma unroll
        for (int n = 0; n < 4; ++n) {
          int col = bn * 128 + wc * 64 + n * 16 + lr;
          float v = acc[m][n][r];
          if (biasp) v += biasp[col];
          v *= rd;
          if (relu) v = fmaxf(v, 0.f);
          if (Cp) Cp[(long)row * N + col] = v;
          if (Cbp) Cbp[(long)row * N + col] = f2bf(v);
        }
      }
    }
  }
  if (CT) {
#pragma unroll
    for (int ch = 0; ch < 2; ++ch) {
      __syncthreads();
      if (wc == ch) {
#pragma unroll
        for (int m = 0; m < 4; ++m) {
#pragma unroll
          for (int r = 0; r < 4; ++r) {
            int rowl = wr * 64 + m * 16 + (l >> 4) * 4 + r;
            float rd = rowDivp ? 1.f / rowDivp[(long)bz * M + bm * 128 + rowl] : 1.f;
#pragma unroll
            for (int n = 0; n < 4; ++n) {
              int col = bn * 128 + wc * 64 + n * 16 + lr;
              float v = acc[m][n][r];
              if (biasp) v += biasp[col];
              v *= rd;
              if (relu) v = fmaxf(v, 0.f);
              Ts[n * 16 + lr][rowl] = f2bf(v);
            }
          }
        }
      }
      __syncthreads();
      int trow = tid >> 2, tc = (tid & 3) * 32;
      int colg = bn * 128 + ch * 64 + trow;
      int rowg = bm * 128 + tc;
      unsigned short* dp = CTp + (long)(rowg >> 8) * sCT + (long)colg * 256 + (rowg & 255);
#pragma unroll
      for (int j = 0; j < 4; ++j)
        *(us8*)(dp + j * 8) = *(const us8*)&Ts[trow][tc + j * 8];
    }
  }
}

// ---------------- fused MFMA attention (dual f32 + bf16 adj_s) ----------------
__global__ __launch_bounds__(256) void attn_mfma(const unsigned short* __restrict__ qbf,
                                                 const unsigned short* __restrict__ kbf,
                                                 const float* __restrict__ srcm,
                                                 float* __restrict__ adj_s,
                                                 unsigned short* __restrict__ adjsbf) {
  int blk = blockIdx.x;
  int b = blk >> 4, l0 = (blk & 15) << 4;
  int t = threadIdx.x;
  int w = t >> 6, l = t & 63;
  int lr = l & 15, kg = (l >> 4) * 8;
  int rbase = (l >> 4) * 4;
  __shared__ float redmx[4][16];
  __shared__ float redsm[4][16];
  float acc[4][4] = {};
  float cmv[4];
#pragma unroll
  for (int ct = 0; ct < 4; ++ct) cmv[ct] = srcm[b * L_ + w * 64 + ct * 16 + lr];

  for (int h = 0; h < H_; ++h) {
    const unsigned short* ap = qbf + ((long)b * L_ + l0 + lr) * D_ + h * 64 + kg;
    bfrag8 af0 = *(const bfrag8*)ap;
    bfrag8 af1 = *(const bfrag8*)(ap + 32);
    float sv[4][4];
#pragma unroll
    for (int ct = 0; ct < 4; ++ct) {
      const unsigned short* bp =
          kbf + ((long)b * L_ + w * 64 + ct * 16 + lr) * D_ + h * 64 + kg;
      bfrag8 bf0 = *(const bfrag8*)bp;
      bfrag8 bf1 = *(const bfrag8*)(bp + 32);
      f32x4 c = {};
      c = __builtin_amdgcn_mfma_f32_16x16x32_bf16(af0, bf0, c, 0, 0, 0);
      c = __builtin_amdgcn_mfma_f32_16x16x32_bf16(af1, bf1, c, 0, 0, 0);
#pragma unroll
      for (int r = 0; r < 4; ++r)
        sv[ct][r] = (cmv[ct] == 0.f) ? -1e9f : c[r] * 0.125f;
    }
#pragma unroll
    for (int r = 0; r < 4; ++r) {
      float mx = fmaxf(fmaxf(sv[0][r], sv[1][r]), fmaxf(sv[2][r], sv[3][r]));
#pragma unroll
      for (int o = 1; o < 16; o <<= 1) mx = fmaxf(mx, __shfl_xor(mx, o, 64));
      if (lr == 0) redmx[w][rbase + r] = mx;
    }
    __syncthreads();
#pragma unroll
    for (int r = 0; r < 4; ++r) {
      float mx = fmaxf(fmaxf(redmx[0][rbase + r], redmx[1][rbase + r]),
                       fmaxf(redmx[2][rbase + r], redmx[3][rbase + r]));
      float s = 0.f;
#pragma unroll
      for (int ct = 0; ct < 4; ++ct) {
        float e = __expf(sv[ct][r] - mx);
        sv[ct][r] = e;
        s += e;
      }
#pragma unroll
      for (int o = 1; o < 16; o <<= 1) s += __shfl_xor(s, o, 64);
      if (lr == 0) redsm[w][rbase + r] = s;
    }
    __syncthreads();
#pragma unroll
    for (int r = 0; r < 4; ++r) {
      float tot = redsm[0][rbase + r] + redsm[1][rbase + r] +
                  redsm[2][rbase + r] + redsm[3][rbase + r];
      float inv = 1.f / tot;
#pragma unroll
      for (int ct = 0; ct < 4; ++ct) acc[ct][r] += sv[ct][r] * inv;
    }
  }

#pragma unroll
  for (int r = 0; r < 4; ++r) {
    int row = l0 + rbase + r;
    float rm = srcm[b * L_ + row];
#pragma unroll
    for (int ct = 0; ct < 4; ++ct) {
      int col = w * 64 + ct * 16 + lr;
      float v = acc[ct][r] * (1.f / H_);
      if (col == row) v = 1.f;
      v *= rm;
      long idx = ((long)b * L_ + row) * L_ + col;
      adj_s[idx] = v;
      adjsbf[idx] = f2bf(v);
    }
  }
}

// ---------------- fused S-GEMM + row softmax, direct-global frags ------------
__global__ __launch_bounds__(256) void gemm_sfmx(
    const unsigned short* __restrict__ u1, const unsigned short* __restrict__ g1,
    unsigned short* __restrict__ P1,
    const unsigned short* __restrict__ u2, const unsigned short* __restrict__ g2,
    unsigned short* __restrict__ P2) {
  int bm = blockIdx.x;
  int bz = blockIdx.y;
  const unsigned short* Aq; const unsigned short* Bq; unsigned short* Pp;
  if (bz < 32) {
    Aq = u1 + (long)bz * L_ * MEM_; Bq = g1 + (long)bz * L_ * MEM_;
    Pp = P1 + (long)bz * L_ * L_;
  } else {
    int z = bz - 32;
    Aq = u2 + (long)z * L_ * MEM_; Bq = g2 + (long)z * L_ * MEM_;
    Pp = P2 + (long)z * L_ * L_;
  }
  __shared__ float redm[2][64];
  __shared__ float reds[2][64];
  const int t = threadIdx.x;
  const int l = t & 63, w = t >> 6;
  const int wr = w >> 1, wc = w & 1;
  const int lr = l & 15, kg = (l >> 4) * 8;
  f32x4 acc[2][8] = {};

  const unsigned short* ap[2];
  const unsigned short* bp[8];
#pragma unroll
  for (int m = 0; m < 2; ++m)
    ap[m] = Aq + (long)(bm * 64 + wr * 32 + m * 16 + lr) * MEM_ + kg;
#pragma unroll
  for (int n = 0; n < 8; ++n)
    bp[n] = Bq + (long)(wc * 128 + n * 16 + lr) * MEM_ + kg;

#pragma unroll 4
  for (int k0 = 0; k0 < MEM_; k0 += 32) {
    bfrag8 af[2], bf[8];
#pragma unroll
    for (int m = 0; m < 2; ++m) af[m] = *(const bfrag8*)(ap[m] + k0);
#pragma unroll
    for (int n = 0; n < 8; ++n) bf[n] = *(const bfrag8*)(bp[n] + k0);
#pragma unroll
    for (int m = 0; m < 2; ++m)
#pragma unroll
      for (int n = 0; n < 8; ++n)
        acc[m][n] = __builtin_amdgcn_mfma_f32_16x16x32_bf16(af[m], bf[n], acc[m][n], 0, 0, 0);
  }

#pragma unroll
  for (int m = 0; m < 2; ++m) {
#pragma unroll
    for (int r = 0; r < 4; ++r) {
      int lrow = wr * 32 + m * 16 + (l >> 4) * 4 + r;
      float mx = -1e30f;
#pragma unroll
      for (int n = 0; n < 8; ++n) mx = fmaxf(mx, acc[m][n][r]);
#pragma unroll
      for (int o = 1; o < 16; o <<= 1) mx = fmaxf(mx, __shfl_xor(mx, o, 64));
      if (lr == 0) redm[wc][lrow] = mx;
    }
  }
  __syncthreads();
#pragma unroll
  for (int m = 0; m < 2; ++m) {
#pragma unroll
    for (int r = 0; r < 4; ++r) {
      int lrow = wr * 32 + m * 16 + (l >> 4) * 4 + r;
      float mx = fmaxf(redm[0][lrow], redm[1][lrow]);
      float s = 0.f;
#pragma unroll
      for (int n = 0; n < 8; ++n) {
        float e = __expf(acc[m][n][r] - mx);
        acc[m][n][r] = e;
        s += e;
      }
#pragma unroll
      for (int o = 1; o < 16; o <<= 1) s += __shfl_xor(s, o, 64);
      if (lr == 0) reds[wc][lrow] = s;
    }
  }
  __syncthreads();
#pragma unroll
  for (int m = 0; m < 2; ++m) {
#pragma unroll
    for (int r = 0; r < 4; ++r) {
      int lrow = wr * 32 + m * 16 + (l >> 4) * 4 + r;
      float inv = 1.f / (reds[0][lrow] + reds[1][lrow]);
      int row = bm * 64 + lrow;
#pragma unroll
      for (int n = 0; n < 8; ++n) {
        int col = wc * 128 + n * 16 + lr;
        Pp[(long)row * L_ + col] = f2bf(acc[m][n][r] * inv);
      }
    }
  }
}

// ---------------- asps_mean via MFMA ----------------
__global__ __launch_bounds__(256) void asps_mean_v2(
    const unsigned short* __restrict__ tmpA,
    const unsigned short* __restrict__ kbf,
    const float* __restrict__ bias_m,
    float* __restrict__ asps_mean) {
  int blk = blockIdx.x;
  int b = blk >> 4, l0 = (blk & 15) << 4;
  int t = threadIdx.x;
  int w = t >> 6, l = t & 63;
  int lr = l & 15, kg = (l >> 4) * 8;
  float bm = bias_m[0];
  float accg[4][4] = {};
  for (int h = 0; h < H_; ++h) {
    const unsigned short* ap = tmpA + (((long)b * H_ + h) * L_ + l0 + lr) * 64 + kg;
    bfrag8 af0 = *(const bfrag8*)ap;
    bfrag8 af1 = *(const bfrag8*)(ap + 32);
#pragma unroll
    for (int ct = 0; ct < 4; ++ct) {
      const unsigned short* bp =
          kbf + ((long)b * L_ + w * 64 + ct * 16 + lr) * D_ + h * 64 + kg;
      bfrag8 bf0 = *(const bfrag8*)bp;
      bfrag8 bf1 = *(const bfrag8*)(bp + 32);
      f32x4 accl = {};
      accl = __builtin_amdgcn_mfma_f32_16x16x32_bf16(af0, bf0, accl, 0, 0, 0);
      accl = __builtin_amdgcn_mfma_f32_16x16x32_bf16(af1, bf1, accl, 0, 0, 0);
#pragma unroll
      for (int r = 0; r < 4; ++r) accg[ct][r] += tanh_fast(accl[r] + bm);
    }
  }
#pragma unroll
  for (int ct = 0; ct < 4; ++ct) {
    int col = w * 64 + ct * 16 + lr;
#pragma unroll
    for (int r = 0; r < 4; ++r) {
      int row = l0 + (l >> 4) * 4 + r;
      asps_mean[((long)b * L_ + row) * L_ + col] = accg[ct][r] * (1.f / H_);
    }
  }
}

// ---------------- avgH (1024 threads: 4-way l-split) ----------------
__global__ __launch_bounds__(1024) void avgh_kernel(const float* __restrict__ asps_mean,
                                                    float* __restrict__ avgH) {
  int b = blockIdx.x;
  int m = threadIdx.x & 255, q = threadIdx.x >> 8;
  __shared__ float part[4][256];
  float s = 0.f;
  for (int l = q * 64; l < q * 64 + 64; ++l)
    s += asps_mean[((long)b * L_ + l) * L_ + m];
  part[q][m] = s;
  __syncthreads();
  if (q == 0)
    avgH[b * L_ + m] = (part[0][m] + part[1][m] + part[2][m] + part[3][m]) * (1.f / L_);
}

// ---------------- adj_ag (dual f32 + bf16) ----------------
__global__ __launch_bounds__(256) void adjag_kernel(const float* __restrict__ asps_mean,
                                                    const float* __restrict__ avgH,
                                                    const float* __restrict__ amask,
                                                    const float* __restrict__ adjr,
                                                    float* __restrict__ adj_ag,
                                                    unsigned short* __restrict__ adjagbf) {
  long idx = (long)blockIdx.x * 256 + threadIdx.x;
  int m = idx & 255;
  long bl = idx >> 8;
  int l = (int)(bl & 255);
  int b = (int)(bl >> 8);
  bool rowa = amask[b * L_ + l] > 0.f;
  bool cola = amask[b * L_ + m] > 0.f;
  float asa;
  if (rowa && cola) asa = (l >= m) ? avgH[b * L_ + m] : avgH[b * L_ + l];
  else if (rowa)    asa = avgH[b * L_ + m];
  else if (cola)    asa = avgH[b * L_ + l];
  else              asa = asps_mean[idx];
  float r = (asa > 0.25f) ? 1.f : expf(adjr[idx]);
  float v = r * asa;
  adj_ag[idx] = v;
  adjagbf[idx] = f2bf(v);
}

// ---------------- KL partials + row denominators ----------------
__global__ __launch_bounds__(256) void kl_denom(const float* __restrict__ adj_s,
                                                const float* __restrict__ adj_ag,
                                                float* __restrict__ klpart,
                                                float* __restrict__ den_s,
                                                float* __restrict__ den_ag) {
  long row = blockIdx.x;
  int m = threadIdx.x;
  __shared__ float red[4];
  float s = adj_s[row * L_ + m];
  float a = adj_ag[row * L_ + m];
  float sum_s = blkRedSum(s, red);
  float sum_a = blkRedSum(a, red);
  float mx_s = blkRedMax(s, red);
  float mx_a = blkRedMax(a, red);
  float es = expf(s - mx_s), ea = expf(a - mx_a);
  float ses = blkRedSum(es, red);
  float sea = blkRedSum(ea, red);
  float logq = (s - mx_s) - logf(ses);
  float logp = (a - mx_a) - logf(sea);
  float term = (es / ses) * (logq - logp);
  float kp = blkRedSum(term, red);
  if (m == 0) {
    klpart[row] = kp;
    den_s[row] = sum_s + 1.f;
    den_ag[row] = sum_a + 1.f;
  }
}

__global__ __launch_bounds__(256) void kl_final(const float* __restrict__ klpart,
                                                float* __restrict__ dout) {
  __shared__ float red[4];
  float s = 0.f;
  for (int i = threadIdx.x; i < B_ * L_; i += 256) s += klpart[i];
  s = blkRedSum(s, red);
  if (threadIdx.x == 0) dout[96] = expf(-s * 0.1f);
}

// ---------------- classifier head (bf16 o inputs) ----------------
__global__ __launch_bounds__(256) void final_kernel(const unsigned short* __restrict__ o_ag,
                                                    const unsigned short* __restrict__ o_s,
                                                    const float* __restrict__ pooled,
                                                    const float* __restrict__ amask,
                                                    const float* __restrict__ wc,
                                                    const float* __restrict__ bc,
                                                    float* __restrict__ dout) {
  int b = blockIdx.x, t = threadIdx.x;
  __shared__ float cS[1536];
  __shared__ float maskS[256];
  __shared__ float red[4];
  maskS[t] = amask[b * L_ + t];
  float wn = blkRedSum(maskS[t], red);
  for (int e = t; e < MEM_; e += 256) {
    float s1 = 0.f, s2 = 0.f;
    for (int l = 0; l < L_; ++l) {
      float mk = maskS[l];
      if (mk != 0.f) {
        s1 += mk * bf2f(o_ag[((long)b * L_ + l) * MEM_ + e]);
        s2 += mk * bf2f(o_s[((long)b * L_ + l) * MEM_ + e]);
      }
    }
    cS[e] = s1 / wn;
    cS[MEM_ + e] = s2 / wn;
  }
  for (int j = t; j < D_; j += 256) cS[2 * MEM_ + j] = pooled[b * D_ + j];
  __syncthreads();
  float p0 = 0.f, p1 = 0.f, p2 = 0.f;
  for (int j = t; j < 1536; j += 256) {
    float v = cS[j];
    p0 += v * wc[j * 3 + 0];
    p1 += v * wc[j * 3 + 1];
    p2 += v * wc[j * 3 + 2];
  }
  p0 = blkRedSum(p0, red);
  p1 = blkRedSum(p1, red);
  p2 = blkRedSum(p2, red);
  if (t == 0) {
    dout[b * 3 + 0] = p0 + bc[0];
    dout[b * 3 + 1] = p1 + bc[1];
    dout[b * 3 + 2] = p2 + bc[2];
  }
}

extern "C" void kernel_launch(void* const* d_in, const int* in_sizes, int n_in,
                              void* d_out, int out_size, void* d_ws, size_t ws_size,
                              hipStream_t stream) {
  const float* seq    = (const float*)d_in[0];
  const float* pooled = (const float*)d_in[1];
  const float* adjr   = (const float*)d_in[2];
  const float* srcm   = (const float*)d_in[3];
  const float* amask  = (const float*)d_in[4];
  const float* ln_g   = (const float*)d_in[5];
  const float* ln_b   = (const float*)d_in[6];
  const float* wq     = (const float*)d_in[7];
  const float* bq     = (const float*)d_in[8];
  const float* wk     = (const float*)d_in[9];
  const float* bk     = (const float*)d_in[10];
  const float* wd     = (const float*)d_in[11];
  const float* bd     = (const float*)d_in[12];
  const float* wm     = (const float*)d_in[13];
  const float* bm     = (const float*)d_in[14];
  const float* wa0    = (const float*)d_in[15];
  const float* ba0    = (const float*)d_in[16];
  const float* wa1    = (const float*)d_in[17];
  const float* ba1    = (const float*)d_in[18];
  const float* ws0    = (const float*)d_in[19];
  const float* bs0    = (const float*)d_in[20];
  const float* ws1    = (const float*)d_in[21];
  const float* bs1    = (const float*)d_in[22];
  const float* aff1   = (const float*)d_in[23];
  const float* aff2   = (const float*)d_in[24];
  const float* wc     = (const float*)d_in[25];
  const float* bc     = (const float*)d_in[26];

  float* ws = (float*)d_ws;
  // ---- workspace layout (float units) ----
  float* S0 = ws;                        // 6291456: x f32 -> {o_agbf|o_sbf|gTag|gTs}
  float* S1 = S0 + 6291456;              // 3145728: xbf
  float* S2 = S1 + 3145728;              // 3145728: qbf -> tmpA -> {g_agbf|g_sbf}
  float* S3 = S2 + 3145728;              // 3145728: kbf -> {tTag|tTs} -> {u1bf|u2bf}
  float* S4 = S3 + 3145728;              // 524288 : aspbf + wdT + wmT (shorts)
  float* S5 = S4 + 524288;               // 2097152: asps f32 -> {P1bf|P2bf}
  float* adj_s  = S5 + 2097152;          // 2097152
  float* adj_ag = adj_s + 2097152;       // 2097152
  unsigned short* adjsbf  = (unsigned short*)(adj_ag + 2097152);  // 2097152 sh
  unsigned short* adjagbf = adjsbf + 2097152;                     // 2097152 sh
  unsigned short* wT      = adjagbf + 2097152;                    // 2359296 sh
  unsigned short* wqT   = wT;
  unsigned short* wkT   = wT + 589824;
  unsigned short* wa0T  = wT + 1179648;
  unsigned short* ws0T  = wT + 1474560;
  unsigned short* wa1T  = wT + 1769472;
  unsigned short* ws1T  = wT + 1916928;
  unsigned short* aff1T = wT + 2064384;
  unsigned short* aff2T = wT + 2211840;
  float* tail   = (float*)(wT + 2359296);
  float* avgH   = tail;
  float* den_s  = avgH + 8192;
  float* den_ag = den_s + 8192;
  float* klp    = den_ag + 8192;

  float* x = S0;
  unsigned short* o_agbf = (unsigned short*)S0;
  unsigned short* o_sbf  = o_agbf + 3145728;
  unsigned short* gTag   = o_agbf + 6291456;
  unsigned short* gTs    = o_agbf + 9437184;
  unsigned short* xbf    = (unsigned short*)S1;
  unsigned short* qbf    = (unsigned short*)S2;
  unsigned short* tmpA   = (unsigned short*)S2;
  unsigned short* g_agbf = (unsigned short*)S2;
  unsigned short* g_sbf  = g_agbf + 3145728;
  unsigned short* kbf    = (unsigned short*)S3;
  unsigned short* tTag   = (unsigned short*)S3;
  unsigned short* tTs    = tTag + 3145728;
  unsigned short* u1bf   = (unsigned short*)S3;
  unsigned short* u2bf   = u1bf + 3145728;
  unsigned short* aspbf  = (unsigned short*)S4;      // 524288 shorts
  unsigned short* wdT    = aspbf + 524288;           // 49152 shorts
  unsigned short* wmT    = wdT + 49152;              // 49152 shorts
  float* asps = S5;
  unsigned short* P1bf = (unsigned short*)S5;
  unsigned short* P2bf = P1bf + 2097152;
  float* dout = (float*)d_out;

  const long sAdjSh = (long)L_ * L_;     // 65536 shorts per z
  const long sMemSh = (long)L_ * MEM_;   // 98304 shorts per z

  // ---- weight transpose/convert (once per call) ----
  tc_pair<<<dim3(12, 12, 2), 256, 0, stream>>>(wq, wqT, wk, wkT, 768, 768);
  tc_pair<<<dim3(6, 12, 2), 256, 0, stream>>>(wa0, wa0T, ws0, ws0T, 768, 384);
  tc_pair<<<dim3(6, 6, 2), 256, 0, stream>>>(wa1, wa1T, ws1, ws1T, 384, 384);
  tc_pair<<<dim3(6, 6, 2), 256, 0, stream>>>(aff1, aff1T, aff2, aff2T, 384, 384);
  tc_pair<<<dim3(1, 12, 1), 256, 0, stream>>>(wd, wdT, nullptr, nullptr, 768, 64);
  tc_wm<<<H_, 256, 0, stream>>>(wm, wmT);

  ln_kernel<<<B_ * L_, 256, 0, stream>>>(seq, ln_g, ln_b, x, xbf);
  // paired q/k projections (bf16 in/out)
  gemm_bb<<<dim3(6, 64, 2), 256, 0, stream>>>(
      xbf, wqT, nullptr, qbf, nullptr, 8192, 768, 768, 0, 0, 0, 0, bq, nullptr, 0,
      xbf, wkT, nullptr, kbf, nullptr, bk, nullptr, 1);
  attn_mfma<<<B_ * 16, 256, 0, stream>>>(qbf, kbf, srcm, adj_s, adjsbf);
  // asp chain (MFMA)
  asp_mfma<<<512, 256, 0, stream>>>(xbf, wdT, amask, bd, aspbf);
  asp_wm_v2<<<B_ * H_, 256, 0, stream>>>(aspbf, wmT, tmpA);  // after attn (tmpA aliases qbf)
  asps_mean_v2<<<B_ * 16, 256, 0, stream>>>(tmpA, kbf, bm, asps);
  avgh_kernel<<<B_, 1024, 0, stream>>>(asps, avgH);
  adjag_kernel<<<B_ * L_ * L_ / 256, 256, 0, stream>>>(asps, avgH, amask, adjr,
                                                       adj_ag, adjagbf);
  kl_denom<<<B_ * L_, 256, 0, stream>>>(adj_s, adj_ag, klp, den_s, den_ag);
  kl_final<<<1, 256, 0, stream>>>(klp, dout);

  for (int li = 0; li < 2; ++li) {
    int Kd = li ? MEM_ : D_;
    const unsigned short* inag = li ? o_agbf : xbf;
    const unsigned short* ins  = li ? o_sbf : xbf;
    const unsigned short* wAT = li ? wa1T : wa0T;
    const float* bA = li ? ba1 : ba0;
    const unsigned short* wST = li ? ws1T : ws0T;
    const float* bS = li ? bs1 : bs0;
    // paired t-GEMMs -> transposed bf16 tT
    gemm_bb<<<dim3(3, 64, 2), 256, 0, stream>>>(
        inag, wAT, nullptr, nullptr, tTag, 8192, MEM_, Kd, 0, 0, 0, sMemSh,
        nullptr, nullptr, 0,
        ins, wST, nullptr, nullptr, tTs, nullptr, nullptr, 1);
    // paired g-GEMMs: g = relu((adj@t + b)/den), outputs g bf16 + gT bf16
    gemm_bb<<<dim3(3, 2, 64), 256, 0, stream>>>(
        adjagbf, tTag, nullptr, g_agbf, gTag, L_, MEM_, L_, sAdjSh, sMemSh, sMemSh,
        sMemSh, bA, den_ag, 1,
        adjsbf, tTs, nullptr, g_sbf, gTs, bS, den_s, 32);
    // paired u-GEMMs
    gemm_bb<<<dim3(3, 64, 2), 256, 0, stream>>>(
        g_agbf, aff1T, nullptr, u1bf, nullptr, 8192, MEM_, MEM_, 0, 0, 0, 0,
        nullptr, nullptr, 0,
        g_sbf, aff2T, nullptr, u2bf, nullptr, nullptr, nullptr, 1);
    // paired fused S+softmax
    gemm_sfmx<<<dim3(4, 64), 256, 0, stream>>>(u1bf, g_sbf, P1bf, u2bf, g_agbf, P2bf);
    // paired PV: o_ag = P1@g_s (B = gTs), o_s = P2@g_ag (B = gTag)
    gemm_bb<<<dim3(3, 2, 64), 256, 0, stream>>>(
        P1bf, gTs, nullptr, o_agbf, nullptr, L_, MEM_, L_, sAdjSh, sMemSh, sMemSh, 0,
        nullptr, nullptr, 0,
        P2bf, gTag, nullptr, o_sbf, nullptr, nullptr, nullptr, 32);
  }

  final_kernel<<<B_, 256, 0, stream>>>(o_agbf, o_sbf, pooled, amask, wc, bc, dout);
}

// Round 9
// 497.830 us; speedup vs baseline: 1.2212x; 1.2212x over previous
//
#include <hip/hip_runtime.h>

#define B_ 32
#define L_ 256
#define D_ 768
#define H_ 12
#define DK_ 64
#define MEM_ 384

typedef __attribute__((ext_vector_type(8))) short bfrag8;    // 8 bf16 (4 VGPRs)
typedef __attribute__((ext_vector_type(8))) unsigned short us8;
typedef __attribute__((ext_vector_type(4))) float f32x4;

// f32 -> bf16 round-to-nearest-even (finite inputs only)
__device__ inline unsigned short f2bf(float f) {
  unsigned u = __float_as_uint(f);
  return (unsigned short)((u + 0x7fffu + ((u >> 16) & 1u)) >> 16);
}
__device__ inline float bf2f(unsigned short u) {
  return __uint_as_float(((unsigned)u) << 16);
}
__device__ inline float tanh_fast(float x) {
  x = fminf(fmaxf(x, -30.f), 30.f);
  float e = __expf(2.f * x);
  return (e - 1.f) * __builtin_amdgcn_rcpf(e + 1.f);
}
// async global->LDS, 16B per lane; LDS dest = wave-uniform base + lane*16
__device__ inline void gload_lds16(const unsigned short* g, unsigned short* l) {
  __builtin_amdgcn_global_load_lds(
      (__attribute__((address_space(1))) void*)(g),
      (__attribute__((address_space(3))) void*)(l), 16, 0, 0);
}

// ---------------- block reduce helpers (256 threads = 4 waves) ----------------
__device__ inline float waveRedSum(float v) {
#pragma unroll
  for (int o = 32; o; o >>= 1) v += __shfl_xor(v, o, 64);
  return v;
}
__device__ inline float waveRedMax(float v) {
#pragma unroll
  for (int o = 32; o; o >>= 1) v = fmaxf(v, __shfl_xor(v, o, 64));
  return v;
}
__device__ inline float blkRedSum(float v, float* red) {
  v = waveRedSum(v);
  int w = threadIdx.x >> 6;
  __syncthreads();
  if ((threadIdx.x & 63) == 0) red[w] = v;
  __syncthreads();
  return red[0] + red[1] + red[2] + red[3];
}
__device__ inline float blkRedMax(float v, float* red) {
  v = waveRedMax(v);
  int w = threadIdx.x >> 6;
  __syncthreads();
  if ((threadIdx.x & 63) == 0) red[w] = v;
  __syncthreads();
  return fmaxf(fmaxf(red[0], red[1]), fmaxf(red[2], red[3]));
}

// ---------------- LayerNorm (dual f32 + bf16 output) ----------------
__global__ __launch_bounds__(256) void ln_kernel(const float* __restrict__ in,
                                                 const float* __restrict__ g,
                                                 const float* __restrict__ bt,
                                                 float* __restrict__ out,
                                                 unsigned short* __restrict__ outbf) {
  long row = blockIdx.x;
  const float* p = in + row * D_;
  float v[3];
#pragma unroll
  for (int i = 0; i < 3; ++i) v[i] = p[threadIdx.x + i * 256];
  __shared__ float red[4];
  float s = v[0] + v[1] + v[2];
  s = blkRedSum(s, red);
  float mu = s * (1.f / D_);
  float ss = 0.f;
#pragma unroll
  for (int i = 0; i < 3; ++i) { float d = v[i] - mu; ss += d * d; }
  ss = blkRedSum(ss, red);
  float sd = sqrtf(ss * (1.f / (D_ - 1)));
  float inv = 1.f / (sd + 1e-6f);
#pragma unroll
  for (int i = 0; i < 3; ++i) {
    int c = threadIdx.x + i * 256;
    float o = g[c] * (v[i] - mu) * inv + bt[c];
    out[row * D_ + c] = o;
    outbf[row * D_ + c] = f2bf(o);
  }
}

// ---------------- transpose + convert: dst[C][R] bf16 = src[R][C] f32 ----------------
__global__ __launch_bounds__(256) void tc_pair(const float* __restrict__ s1,
                                               unsigned short* __restrict__ d1,
                                               const float* __restrict__ s2,
                                               unsigned short* __restrict__ d2,
                                               int R, int C) {
  const float* src = blockIdx.z ? s2 : s1;
  unsigned short* dst = blockIdx.z ? d2 : d1;
  __shared__ float tile[64][65];
  int c0 = blockIdx.x * 64, r0 = blockIdx.y * 64;
  int tx = threadIdx.x & 63, ty = threadIdx.x >> 6;
#pragma unroll
  for (int i = 0; i < 16; ++i)
    tile[ty + i * 4][tx] = src[(long)(r0 + ty + i * 4) * C + c0 + tx];
  __syncthreads();
#pragma unroll
  for (int i = 0; i < 16; ++i)
    dst[(long)(c0 + ty + i * 4) * R + r0 + tx] = f2bf(tile[tx][ty + i * 4]);
}

// ---------------- per-head transpose: wmT[h][e][d] = wm[h][d][e], bf16 ----------------
__global__ __launch_bounds__(256) void tc_wm(const float* __restrict__ wm,
                                             unsigned short* __restrict__ wmT) {
  int h = blockIdx.x;
  __shared__ float tile[64][65];
  int tx = threadIdx.x & 63, ty = threadIdx.x >> 6;
#pragma unroll
  for (int i = 0; i < 16; ++i)
    tile[ty + i * 4][tx] = wm[h * 4096 + (ty + i * 4) * 64 + tx];
  __syncthreads();
#pragma unroll
  for (int i = 0; i < 16; ++i)
    wmT[h * 4096 + (ty + i * 4) * 64 + tx] = f2bf(tile[tx][ty + i * 4]);
}

// ---------------- asp = bf16(mask_row * (x @ wd) + bd), MFMA, no LDS ----------------
__global__ __launch_bounds__(256) void asp_mfma(const unsigned short* __restrict__ xbf,
                                                const unsigned short* __restrict__ wdT,
                                                const float* __restrict__ amask,
                                                const float* __restrict__ bd,
                                                unsigned short* __restrict__ aspbf) {
  int l0 = blockIdx.x << 4;
  int t = threadIdx.x;
  int w = t >> 6, l = t & 63;
  int lr = l & 15, kg = (l >> 4) * 8;
  const unsigned short* ap = xbf + (long)(l0 + lr) * D_ + kg;
  const unsigned short* bp = wdT + (long)(w * 16 + lr) * D_ + kg;
  f32x4 acc = {};
#pragma unroll
  for (int k0 = 0; k0 < D_; k0 += 32) {
    bfrag8 af = *(const bfrag8*)(ap + k0);
    bfrag8 bf = *(const bfrag8*)(bp + k0);
    acc = __builtin_amdgcn_mfma_f32_16x16x32_bf16(af, bf, acc, 0, 0, 0);
  }
  int col = w * 16 + lr;
#pragma unroll
  for (int r = 0; r < 4; ++r) {
    int row = l0 + (l >> 4) * 4 + r;
    float v = acc[r] * amask[row] + bd[col];
    aspbf[(long)row * DK_ + col] = f2bf(v);
  }
}

// ---------------- tmpA[b,h] = aspbf[b] @ Wm[h], MFMA, no LDS ----------------
__global__ __launch_bounds__(256) void asp_wm_v2(const unsigned short* __restrict__ aspbf,
                                                 const unsigned short* __restrict__ wmT,
                                                 unsigned short* __restrict__ tmpA) {
  int bh = blockIdx.x;
  int b = bh / H_, h = bh % H_;
  int t = threadIdx.x;
  int w = t >> 6, l = t & 63;
  int lr = l & 15, kg = (l >> 4) * 8;
  const unsigned short* wp = wmT + h * 4096;
  f32x4 acc[4][4] = {};
#pragma unroll
  for (int ks = 0; ks < 2; ++ks) {
    int k0 = ks * 32;
    bfrag8 af[4], bf[4];
#pragma unroll
    for (int m = 0; m < 4; ++m)
      af[m] = *(const bfrag8*)(aspbf + (long)(b * L_ + w * 64 + m * 16 + lr) * DK_ + k0 + kg);
#pragma unroll
    for (int n = 0; n < 4; ++n)
      bf[n] = *(const bfrag8*)(wp + (n * 16 + lr) * 64 + k0 + kg);
#pragma unroll
    for (int m = 0; m < 4; ++m)
#pragma unroll
      for (int n = 0; n < 4; ++n)
        acc[m][n] = __builtin_amdgcn_mfma_f32_16x16x32_bf16(af[m], bf[n], acc[m][n], 0, 0, 0);
  }
#pragma unroll
  for (int m = 0; m < 4; ++m)
#pragma unroll
    for (int n = 0; n < 4; ++n)
#pragma unroll
      for (int r = 0; r < 4; ++r) {
        int row = w * 64 + m * 16 + (l >> 4) * 4 + r;
        int col = n * 16 + lr;
        tmpA[(((long)b * H_ + h) * L_ + row) * DK_ + col] = f2bf(acc[m][n][r]);
      }
}

// ---------------- all-bf16 MFMA GEMM, global_load_lds staging + swizzled reads -------
// A bf16 [m][k]; Bt bf16 [n][k]. 128x128 tile, BK=32, 4 waves (2x2), 4x4 frags.
// Staging: DMA 16B/lane into linear [128][32] tiles; global source slot pre-swizzled
// by (row&3) so LDS reads (slot sg^(lr&3)) are ~2-way conflict-free.
// Outputs: C f32, Cbf row-major bf16, CT bf16 transposed-per-256-row-group.
// Second operand set (z >= zsplit) pairs two independent same-shape GEMMs.
__global__ __launch_bounds__(256) void gemm_bb(
    const unsigned short* __restrict__ A, const unsigned short* __restrict__ Bt,
    float* __restrict__ C, unsigned short* __restrict__ Cbf,
    unsigned short* __restrict__ CT,
    int M, int N, int K, long sA, long sB, long sC, long sCT,
    const float* __restrict__ bias, const float* __restrict__ rowDiv, int relu,
    const unsigned short* __restrict__ A2, const unsigned short* __restrict__ Bt2,
    float* __restrict__ C2, unsigned short* __restrict__ Cbf2,
    unsigned short* __restrict__ CT2,
    const float* __restrict__ bias2, const float* __restrict__ rowDiv2, int zsplit) {
  __shared__ alignas(16) unsigned short smem[8704];  // As[0:4096) Bs[4096:8192); Ts aliases
  unsigned short* AsS = smem;
  unsigned short* BsS = smem + 4096;
  const int tid = threadIdx.x;
  const int bn = blockIdx.x, bm = blockIdx.y;
  int bz = blockIdx.z;
  const unsigned short* Ap = A; const unsigned short* Btp = Bt;
  float* Cp = C; unsigned short* Cbp = Cbf; unsigned short* CTp = CT;
  const float* biasp = bias; const float* rowDivp = rowDiv;
  if (zsplit > 0 && bz >= zsplit) {
    bz -= zsplit;
    Ap = A2; Btp = Bt2; Cp = C2; Cbp = Cbf2; CTp = CT2; biasp = bias2; rowDivp = rowDiv2;
  }
  Ap += (long)bz * sA; Btp += (long)bz * sB;
  if (Cp) Cp += (long)bz * sC;
  if (Cbp) Cbp += (long)bz * sC;
  if (CTp) CTp += (long)bz * sCT;

  f32x4 acc[4][4] = {};
  const int l = tid & 63, w = tid >> 6;
  const int wr = w >> 1, wc = w & 1;
  const int lr = l & 15, sg = l >> 4;

  // staging source coords: chunk = w (+4); row = chunk*16 + (l>>2); slot pre-swizzled
  const int rc = l >> 2;
  const int sslot = (l & 3) ^ (rc & 3);
  const unsigned short* gA0 = Ap + (long)(bm * 128 + w * 16 + rc) * K + sslot * 8;
  const unsigned short* gA1 = Ap + (long)(bm * 128 + (w + 4) * 16 + rc) * K + sslot * 8;
  const unsigned short* gB0 = Btp + (long)(bn * 128 + w * 16 + rc) * K + sslot * 8;
  const unsigned short* gB1 = Btp + (long)(bn * 128 + (w + 4) * 16 + rc) * K + sslot * 8;
  unsigned short* lA0 = AsS + w * 512;
  unsigned short* lA1 = AsS + (w + 4) * 512;
  unsigned short* lB0 = BsS + w * 512;
  unsigned short* lB1 = BsS + (w + 4) * 512;

  // loop-invariant LDS fragment pointers (swizzled slot)
  const unsigned short* arp[4];
  const unsigned short* brp[4];
#pragma unroll
  for (int m = 0; m < 4; ++m)
    arp[m] = AsS + (wr * 64 + m * 16 + lr) * 32 + ((sg ^ (lr & 3)) * 8);
#pragma unroll
  for (int n = 0; n < 4; ++n)
    brp[n] = BsS + (wc * 64 + n * 16 + lr) * 32 + ((sg ^ (lr & 3)) * 8);

  for (int k0 = 0; k0 < K; k0 += 32) {
    gload_lds16(gA0 + k0, lA0);
    gload_lds16(gA1 + k0, lA1);
    gload_lds16(gB0 + k0, lB0);
    gload_lds16(gB1 + k0, lB1);
    __syncthreads();
    bfrag8 af[4], bf[4];
#pragma unroll
    for (int m = 0; m < 4; ++m) af[m] = *(const bfrag8*)arp[m];
#pragma unroll
    for (int n = 0; n < 4; ++n) bf[n] = *(const bfrag8*)brp[n];
#pragma unroll
    for (int m = 0; m < 4; ++m)
#pragma unroll
      for (int n = 0; n < 4; ++n)
        acc[m][n] = __builtin_amdgcn_mfma_f32_16x16x32_bf16(af[m], bf[n], acc[m][n], 0, 0, 0);
    __syncthreads();
  }

  if (Cp || Cbp) {
#pragma unroll
    for (int m = 0; m < 4; ++m) {
#pragma unroll
      for (int r = 0; r < 4; ++r) {
        int row = bm * 128 + wr * 64 + m * 16 + (l >> 4) * 4 + r;
        float rd = rowDivp ? 1.f / rowDivp[(long)bz * M + row] : 1.f;
#pragma unroll
        for (int n = 0; n < 4; ++n) {
          int col = bn * 128 + wc * 64 + n * 16 + lr;
          float v = acc[m][n][r];
          if (biasp) v += biasp[col];
          v *= rd;
          if (relu) v = fmaxf(v, 0.f);
          if (Cp) Cp[(long)row * N + col] = v;
          if (Cbp) Cbp[(long)row * N + col] = f2bf(v);
        }
      }
    }
  }
  if (CT) {
    auto Ts = (unsigned short(*)[136])smem;  // aliases As/Bs; guarded by barriers
#pragma unroll
    for (int ch = 0; ch < 2; ++ch) {
      __syncthreads();
      if (wc == ch) {
#pragma unroll
        for (int m = 0; m < 4; ++m) {
#pragma unroll
          for (int r = 0; r < 4; ++r) {
            int rowl = wr * 64 + m * 16 + (l >> 4) * 4 + r;
            float rd = rowDivp ? 1.f / rowDivp[(long)bz * M + bm * 128 + rowl] : 1.f;
#pragma unroll
            for (int n = 0; n < 4; ++n) {
              int col = bn * 128 + wc * 64 + n * 16 + lr;
              float v = acc[m][n][r];
              if (biasp) v += biasp[col];
              v *= rd;
              if (relu) v = fmaxf(v, 0.f);
              Ts[n * 16 + lr][rowl] = f2bf(v);
            }
          }
        }
      }
      __syncthreads();
      int trow = tid >> 2, tc = (tid & 3) * 32;
      int colg = bn * 128 + ch * 64 + trow;
      int rowg = bm * 128 + tc;
      unsigned short* dp = CTp + (long)(rowg >> 8) * sCT + (long)colg * 256 + (rowg & 255);
#pragma unroll
      for (int j = 0; j < 4; ++j)
        *(us8*)(dp + j * 8) = *(const us8*)&Ts[trow][tc + j * 8];
    }
  }
}

// ---------------- fused MFMA attention (dual f32 + bf16 adj_s) ----------------
__global__ __launch_bounds__(256) void attn_mfma(const unsigned short* __restrict__ qbf,
                                                 const unsigned short* __restrict__ kbf,
                                                 const float* __restrict__ srcm,
                                                 float* __restrict__ adj_s,
                                                 unsigned short* __restrict__ adjsbf) {
  int blk = blockIdx.x;
  int b = blk >> 4, l0 = (blk & 15) << 4;
  int t = threadIdx.x;
  int w = t >> 6, l = t & 63;
  int lr = l & 15, kg = (l >> 4) * 8;
  int rbase = (l >> 4) * 4;
  __shared__ float redmx[4][16];
  __shared__ float redsm[4][16];
  float acc[4][4] = {};
  float cmv[4];
#pragma unroll
  for (int ct = 0; ct < 4; ++ct) cmv[ct] = srcm[b * L_ + w * 64 + ct * 16 + lr];

  for (int h = 0; h < H_; ++h) {
    const unsigned short* ap = qbf + ((long)b * L_ + l0 + lr) * D_ + h * 64 + kg;
    bfrag8 af0 = *(const bfrag8*)ap;
    bfrag8 af1 = *(const bfrag8*)(ap + 32);
    float sv[4][4];
#pragma unroll
    for (int ct = 0; ct < 4; ++ct) {
      const unsigned short* bp =
          kbf + ((long)b * L_ + w * 64 + ct * 16 + lr) * D_ + h * 64 + kg;
      bfrag8 bf0 = *(const bfrag8*)bp;
      bfrag8 bf1 = *(const bfrag8*)(bp + 32);
      f32x4 c = {};
      c = __builtin_amdgcn_mfma_f32_16x16x32_bf16(af0, bf0, c, 0, 0, 0);
      c = __builtin_amdgcn_mfma_f32_16x16x32_bf16(af1, bf1, c, 0, 0, 0);
#pragma unroll
      for (int r = 0; r < 4; ++r)
        sv[ct][r] = (cmv[ct] == 0.f) ? -1e9f : c[r] * 0.125f;
    }
#pragma unroll
    for (int r = 0; r < 4; ++r) {
      float mx = fmaxf(fmaxf(sv[0][r], sv[1][r]), fmaxf(sv[2][r], sv[3][r]));
#pragma unroll
      for (int o = 1; o < 16; o <<= 1) mx = fmaxf(mx, __shfl_xor(mx, o, 64));
      if (lr == 0) redmx[w][rbase + r] = mx;
    }
    __syncthreads();
#pragma unroll
    for (int r = 0; r < 4; ++r) {
      float mx = fmaxf(fmaxf(redmx[0][rbase + r], redmx[1][rbase + r]),
                       fmaxf(redmx[2][rbase + r], redmx[3][rbase + r]));
      float s = 0.f;
#pragma unroll
      for (int ct = 0; ct < 4; ++ct) {
        float e = __expf(sv[ct][r] - mx);
        sv[ct][r] = e;
        s += e;
      }
#pragma unroll
      for (int o = 1; o < 16; o <<= 1) s += __shfl_xor(s, o, 64);
      if (lr == 0) redsm[w][rbase + r] = s;
    }
    __syncthreads();
#pragma unroll
    for (int r = 0; r < 4; ++r) {
      float tot = redsm[0][rbase + r] + redsm[1][rbase + r] +
                  redsm[2][rbase + r] + redsm[3][rbase + r];
      float inv = 1.f / tot;
#pragma unroll
      for (int ct = 0; ct < 4; ++ct) acc[ct][r] += sv[ct][r] * inv;
    }
  }

#pragma unroll
  for (int r = 0; r < 4; ++r) {
    int row = l0 + rbase + r;
    float rm = srcm[b * L_ + row];
#pragma unroll
    for (int ct = 0; ct < 4; ++ct) {
      int col = w * 64 + ct * 16 + lr;
      float v = acc[ct][r] * (1.f / H_);
      if (col == row) v = 1.f;
      v *= rm;
      long idx = ((long)b * L_ + row) * L_ + col;
      adj_s[idx] = v;
      adjsbf[idx] = f2bf(v);
    }
  }
}

// ---------------- fused S-GEMM + row softmax (LDS-staged bf16): P = softmax(u @ g^T) ---
__global__ __launch_bounds__(256) void gemm_sfmx(
    const unsigned short* __restrict__ u1, const unsigned short* __restrict__ g1,
    unsigned short* __restrict__ P1,
    const unsigned short* __restrict__ u2, const unsigned short* __restrict__ g2,
    unsigned short* __restrict__ P2) {
  int bm = blockIdx.x;
  int bz = blockIdx.y;
  const unsigned short* Ap; const unsigned short* Bp; unsigned short* Pp;
  if (bz < 32) {
    Ap = u1 + (long)bz * L_ * MEM_; Bp = g1 + (long)bz * L_ * MEM_;
    Pp = P1 + (long)bz * L_ * L_;
  } else {
    int z = bz - 32;
    Ap = u2 + (long)z * L_ * MEM_; Bp = g2 + (long)z * L_ * MEM_;
    Pp = P2 + (long)z * L_ * L_;
  }
  __shared__ unsigned short As[64][40];
  __shared__ unsigned short Bs[256][40];
  __shared__ float redm[2][64];
  __shared__ float reds[2][64];
  const int t = threadIdx.x;
  const int l = t & 63, w = t >> 6;
  const int wr = w >> 1, wc = w & 1;
  const int lr = l & 15, kg = (l >> 4) * 8;
  f32x4 acc[2][8] = {};
  const int arA = t >> 2, akA = (t & 3) * 8;

  for (int k0 = 0; k0 < MEM_; k0 += 32) {
    *(us8*)&As[arA][akA] = *(const us8*)(Ap + (long)(bm * 64 + arA) * MEM_ + k0 + akA);
#pragma unroll
    for (int j = 0; j < 4; ++j)
      *(us8*)&Bs[t][j * 8] = *(const us8*)(Bp + (long)t * MEM_ + k0 + j * 8);
    __syncthreads();
    bfrag8 af[2], bf[8];
#pragma unroll
    for (int m = 0; m < 2; ++m) af[m] = *(const bfrag8*)&As[wr * 32 + m * 16 + lr][kg];
#pragma unroll
    for (int n = 0; n < 8; ++n) bf[n] = *(const bfrag8*)&Bs[wc * 128 + n * 16 + lr][kg];
#pragma unroll
    for (int m = 0; m < 2; ++m)
#pragma unroll
      for (int n = 0; n < 8; ++n)
        acc[m][n] = __builtin_amdgcn_mfma_f32_16x16x32_bf16(af[m], bf[n], acc[m][n], 0, 0, 0);
    __syncthreads();
  }

#pragma unroll
  for (int m = 0; m < 2; ++m) {
#pragma unroll
    for (int r = 0; r < 4; ++r) {
      int lrow = wr * 32 + m * 16 + (l >> 4) * 4 + r;
      float mx = -1e30f;
#pragma unroll
      for (int n = 0; n < 8; ++n) mx = fmaxf(mx, acc[m][n][r]);
#pragma unroll
      for (int o = 1; o < 16; o <<= 1) mx = fmaxf(mx, __shfl_xor(mx, o, 64));
      if (lr == 0) redm[wc][lrow] = mx;
    }
  }
  __syncthreads();
#pragma unroll
  for (int m = 0; m < 2; ++m) {
#pragma unroll
    for (int r = 0; r < 4; ++r) {
      int lrow = wr * 32 + m * 16 + (l >> 4) * 4 + r;
      float mx = fmaxf(redm[0][lrow], redm[1][lrow]);
      float s = 0.f;
#pragma unroll
      for (int n = 0; n < 8; ++n) {
        float e = __expf(acc[m][n][r] - mx);
        acc[m][n][r] = e;
        s += e;
      }
#pragma unroll
      for (int o = 1; o < 16; o <<= 1) s += __shfl_xor(s, o, 64);
      if (lr == 0) reds[wc][lrow] = s;
    }
  }
  __syncthreads();
#pragma unroll
  for (int m = 0; m < 2; ++m) {
#pragma unroll
    for (int r = 0; r < 4; ++r) {
      int lrow = wr * 32 + m * 16 + (l >> 4) * 4 + r;
      float inv = 1.f / (reds[0][lrow] + reds[1][lrow]);
      int row = bm * 64 + lrow;
#pragma unroll
      for (int n = 0; n < 8; ++n) {
        int col = wc * 128 + n * 16 + lr;
        Pp[(long)row * L_ + col] = f2bf(acc[m][n][r] * inv);
      }
    }
  }
}

// ---------------- asps_mean via MFMA ----------------
__global__ __launch_bounds__(256) void asps_mean_v2(
    const unsigned short* __restrict__ tmpA,
    const unsigned short* __restrict__ kbf,
    const float* __restrict__ bias_m,
    float* __restrict__ asps_mean) {
  int blk = blockIdx.x;
  int b = blk >> 4, l0 = (blk & 15) << 4;
  int t = threadIdx.x;
  int w = t >> 6, l = t & 63;
  int lr = l & 15, kg = (l >> 4) * 8;
  float bm = bias_m[0];
  float accg[4][4] = {};
  for (int h = 0; h < H_; ++h) {
    const unsigned short* ap = tmpA + (((long)b * H_ + h) * L_ + l0 + lr) * 64 + kg;
    bfrag8 af0 = *(const bfrag8*)ap;
    bfrag8 af1 = *(const bfrag8*)(ap + 32);
#pragma unroll
    for (int ct = 0; ct < 4; ++ct) {
      const unsigned short* bp =
          kbf + ((long)b * L_ + w * 64 + ct * 16 + lr) * D_ + h * 64 + kg;
      bfrag8 bf0 = *(const bfrag8*)bp;
      bfrag8 bf1 = *(const bfrag8*)(bp + 32);
      f32x4 accl = {};
      accl = __builtin_amdgcn_mfma_f32_16x16x32_bf16(af0, bf0, accl, 0, 0, 0);
      accl = __builtin_amdgcn_mfma_f32_16x16x32_bf16(af1, bf1, accl, 0, 0, 0);
#pragma unroll
      for (int r = 0; r < 4; ++r) accg[ct][r] += tanh_fast(accl[r] + bm);
    }
  }
#pragma unroll
  for (int ct = 0; ct < 4; ++ct) {
    int col = w * 64 + ct * 16 + lr;
#pragma unroll
    for (int r = 0; r < 4; ++r) {
      int row = l0 + (l >> 4) * 4 + r;
      asps_mean[((long)b * L_ + row) * L_ + col] = accg[ct][r] * (1.f / H_);
    }
  }
}

// ---------------- avgH (1024 threads: 4-way l-split) ----------------
__global__ __launch_bounds__(1024) void avgh_kernel(const float* __restrict__ asps_mean,
                                                    float* __restrict__ avgH) {
  int b = blockIdx.x;
  int m = threadIdx.x & 255, q = threadIdx.x >> 8;
  __shared__ float part[4][256];
  float s = 0.f;
  for (int l = q * 64; l < q * 64 + 64; ++l)
    s += asps_mean[((long)b * L_ + l) * L_ + m];
  part[q][m] = s;
  __syncthreads();
  if (q == 0)
    avgH[b * L_ + m] = (part[0][m] + part[1][m] + part[2][m] + part[3][m]) * (1.f / L_);
}

// ---------------- adj_ag (dual f32 + bf16) ----------------
__global__ __launch_bounds__(256) void adjag_kernel(const float* __restrict__ asps_mean,
                                                    const float* __restrict__ avgH,
                                                    const float* __restrict__ amask,
                                                    const float* __restrict__ adjr,
                                                    float* __restrict__ adj_ag,
                                                    unsigned short* __restrict__ adjagbf) {
  long idx = (long)blockIdx.x * 256 + threadIdx.x;
  int m = idx & 255;
  long bl = idx >> 8;
  int l = (int)(bl & 255);
  int b = (int)(bl >> 8);
  bool rowa = amask[b * L_ + l] > 0.f;
  bool cola = amask[b * L_ + m] > 0.f;
  float asa;
  if (rowa && cola) asa = (l >= m) ? avgH[b * L_ + m] : avgH[b * L_ + l];
  else if (rowa)    asa = avgH[b * L_ + m];
  else if (cola)    asa = avgH[b * L_ + l];
  else              asa = asps_mean[idx];
  float r = (asa > 0.25f) ? 1.f : expf(adjr[idx]);
  float v = r * asa;
  adj_ag[idx] = v;
  adjagbf[idx] = f2bf(v);
}

// ---------------- KL partials + row denominators ----------------
__global__ __launch_bounds__(256) void kl_denom(const float* __restrict__ adj_s,
                                                const float* __restrict__ adj_ag,
                                                float* __restrict__ klpart,
                                                float* __restrict__ den_s,
                                                float* __restrict__ den_ag) {
  long row = blockIdx.x;
  int m = threadIdx.x;
  __shared__ float red[4];
  float s = adj_s[row * L_ + m];
  float a = adj_ag[row * L_ + m];
  float sum_s = blkRedSum(s, red);
  float sum_a = blkRedSum(a, red);
  float mx_s = blkRedMax(s, red);
  float mx_a = blkRedMax(a, red);
  float es = expf(s - mx_s), ea = expf(a - mx_a);
  float ses = blkRedSum(es, red);
  float sea = blkRedSum(ea, red);
  float logq = (s - mx_s) - logf(ses);
  float logp = (a - mx_a) - logf(sea);
  float term = (es / ses) * (logq - logp);
  float kp = blkRedSum(term, red);
  if (m == 0) {
    klpart[row] = kp;
    den_s[row] = sum_s + 1.f;
    den_ag[row] = sum_a + 1.f;
  }
}

__global__ __launch_bounds__(256) void kl_final(const float* __restrict__ klpart,
                                                float* __restrict__ dout) {
  __shared__ float red[4];
  float s = 0.f;
  for (int i = threadIdx.x; i < B_ * L_; i += 256) s += klpart[i];
  s = blkRedSum(s, red);
  if (threadIdx.x == 0) dout[96] = expf(-s * 0.1f);
}

// ---------------- classifier head (bf16 o inputs) ----------------
__global__ __launch_bounds__(256) void final_kernel(const unsigned short* __restrict__ o_ag,
                                                    const unsigned short* __restrict__ o_s,
                                                    const float* __restrict__ pooled,
                                                    const float* __restrict__ amask,
                                                    const float* __restrict__ wc,
                                                    const float* __restrict__ bc,
                                                    float* __restrict__ dout) {
  int b = blockIdx.x, t = threadIdx.x;
  __shared__ float cS[1536];
  __shared__ float maskS[256];
  __shared__ float red[4];
  maskS[t] = amask[b * L_ + t];
  float wn = blkRedSum(maskS[t], red);
  for (int e = t; e < MEM_; e += 256) {
    float s1 = 0.f, s2 = 0.f;
    for (int l = 0; l < L_; ++l) {
      float mk = maskS[l];
      if (mk != 0.f) {
        s1 += mk * bf2f(o_ag[((long)b * L_ + l) * MEM_ + e]);
        s2 += mk * bf2f(o_s[((long)b * L_ + l) * MEM_ + e]);
      }
    }
    cS[e] = s1 / wn;
    cS[MEM_ + e] = s2 / wn;
  }
  for (int j = t; j < D_; j += 256) cS[2 * MEM_ + j] = pooled[b * D_ + j];
  __syncthreads();
  float p0 = 0.f, p1 = 0.f, p2 = 0.f;
  for (int j = t; j < 1536; j += 256) {
    float v = cS[j];
    p0 += v * wc[j * 3 + 0];
    p1 += v * wc[j * 3 + 1];
    p2 += v * wc[j * 3 + 2];
  }
  p0 = blkRedSum(p0, red);
  p1 = blkRedSum(p1, red);
  p2 = blkRedSum(p2, red);
  if (t == 0) {
    dout[b * 3 + 0] = p0 + bc[0];
    dout[b * 3 + 1] = p1 + bc[1];
    dout[b * 3 + 2] = p2 + bc[2];
  }
}

extern "C" void kernel_launch(void* const* d_in, const int* in_sizes, int n_in,
                              void* d_out, int out_size, void* d_ws, size_t ws_size,
                              hipStream_t stream) {
  const float* seq    = (const float*)d_in[0];
  const float* pooled = (const float*)d_in[1];
  const float* adjr   = (const float*)d_in[2];
  const float* srcm   = (const float*)d_in[3];
  const float* amask  = (const float*)d_in[4];
  const float* ln_g   = (const float*)d_in[5];
  const float* ln_b   = (const float*)d_in[6];
  const float* wq     = (const float*)d_in[7];
  const float* bq     = (const float*)d_in[8];
  const float* wk     = (const float*)d_in[9];
  const float* bk     = (const float*)d_in[10];
  const float* wd     = (const float*)d_in[11];
  const float* bd     = (const float*)d_in[12];
  const float* wm     = (const float*)d_in[13];
  const float* bm     = (const float*)d_in[14];
  const float* wa0    = (const float*)d_in[15];
  const float* ba0    = (const float*)d_in[16];
  const float* wa1    = (const float*)d_in[17];
  const float* ba1    = (const float*)d_in[18];
  const float* ws0    = (const float*)d_in[19];
  const float* bs0    = (const float*)d_in[20];
  const float* ws1    = (const float*)d_in[21];
  const float* bs1    = (const float*)d_in[22];
  const float* aff1   = (const float*)d_in[23];
  const float* aff2   = (const float*)d_in[24];
  const float* wc     = (const float*)d_in[25];
  const float* bc     = (const float*)d_in[26];

  float* ws = (float*)d_ws;
  // ---- workspace layout (float units) ----
  float* S0 = ws;                        // 6291456: x f32 -> {o_agbf|o_sbf|gTag|gTs}
  float* S1 = S0 + 6291456;              // 3145728: xbf
  float* S2 = S1 + 3145728;              // 3145728: qbf -> tmpA -> {g_agbf|g_sbf}
  float* S3 = S2 + 3145728;              // 3145728: kbf -> {tTag|tTs} -> {u1bf|u2bf}
  float* S4 = S3 + 3145728;              // 524288 : aspbf + wdT + wmT (shorts)
  float* S5 = S4 + 524288;               // 2097152: asps f32 -> {P1bf|P2bf}
  float* adj_s  = S5 + 2097152;          // 2097152
  float* adj_ag = adj_s + 2097152;       // 2097152
  unsigned short* adjsbf  = (unsigned short*)(adj_ag + 2097152);  // 2097152 sh
  unsigned short* adjagbf = adjsbf + 2097152;                     // 2097152 sh
  unsigned short* wT      = adjagbf + 2097152;                    // 2359296 sh
  unsigned short* wqT   = wT;
  unsigned short* wkT   = wT + 589824;
  unsigned short* wa0T  = wT + 1179648;
  unsigned short* ws0T  = wT + 1474560;
  unsigned short* wa1T  = wT + 1769472;
  unsigned short* ws1T  = wT + 1916928;
  unsigned short* aff1T = wT + 2064384;
  unsigned short* aff2T = wT + 2211840;
  float* tail   = (float*)(wT + 2359296);
  float* avgH   = tail;
  float* den_s  = avgH + 8192;
  float* den_ag = den_s + 8192;
  float* klp    = den_ag + 8192;

  float* x = S0;
  unsigned short* o_agbf = (unsigned short*)S0;
  unsigned short* o_sbf  = o_agbf + 3145728;
  unsigned short* gTag   = o_agbf + 6291456;
  unsigned short* gTs    = o_agbf + 9437184;
  unsigned short* xbf    = (unsigned short*)S1;
  unsigned short* qbf    = (unsigned short*)S2;
  unsigned short* tmpA   = (unsigned short*)S2;
  unsigned short* g_agbf = (unsigned short*)S2;
  unsigned short* g_sbf  = g_agbf + 3145728;
  unsigned short* kbf    = (unsigned short*)S3;
  unsigned short* tTag   = (unsigned short*)S3;
  unsigned short* tTs    = tTag + 3145728;
  unsigned short* u1bf   = (unsigned short*)S3;
  unsigned short* u2bf   = u1bf + 3145728;
  unsigned short* aspbf  = (unsigned short*)S4;      // 524288 shorts
  unsigned short* wdT    = aspbf + 524288;           // 49152 shorts
  unsigned short* wmT    = wdT + 49152;              // 49152 shorts
  float* asps = S5;
  unsigned short* P1bf = (unsigned short*)S5;
  unsigned short* P2bf = P1bf + 2097152;
  float* dout = (float*)d_out;

  const long sAdjSh = (long)L_ * L_;     // 65536 shorts per z
  const long sMemSh = (long)L_ * MEM_;   // 98304 shorts per z

  // ---- weight transpose/convert (once per call) ----
  tc_pair<<<dim3(12, 12, 2), 256, 0, stream>>>(wq, wqT, wk, wkT, 768, 768);
  tc_pair<<<dim3(6, 12, 2), 256, 0, stream>>>(wa0, wa0T, ws0, ws0T, 768, 384);
  tc_pair<<<dim3(6, 6, 2), 256, 0, stream>>>(wa1, wa1T, ws1, ws1T, 384, 384);
  tc_pair<<<dim3(6, 6, 2), 256, 0, stream>>>(aff1, aff1T, aff2, aff2T, 384, 384);
  tc_pair<<<dim3(1, 12, 1), 256, 0, stream>>>(wd, wdT, nullptr, nullptr, 768, 64);
  tc_wm<<<H_, 256, 0, stream>>>(wm, wmT);

  ln_kernel<<<B_ * L_, 256, 0, stream>>>(seq, ln_g, ln_b, x, xbf);
  // paired q/k projections (bf16 in/out)
  gemm_bb<<<dim3(6, 64, 2), 256, 0, stream>>>(
      xbf, wqT, nullptr, qbf, nullptr, 8192, 768, 768, 0, 0, 0, 0, bq, nullptr, 0,
      xbf, wkT, nullptr, kbf, nullptr, bk, nullptr, 1);
  attn_mfma<<<B_ * 16, 256, 0, stream>>>(qbf, kbf, srcm, adj_s, adjsbf);
  // asp chain (MFMA)
  asp_mfma<<<512, 256, 0, stream>>>(xbf, wdT, amask, bd, aspbf);
  asp_wm_v2<<<B_ * H_, 256, 0, stream>>>(aspbf, wmT, tmpA);  // after attn (tmpA aliases qbf)
  asps_mean_v2<<<B_ * 16, 256, 0, stream>>>(tmpA, kbf, bm, asps);
  avgh_kernel<<<B_, 1024, 0, stream>>>(asps, avgH);
  adjag_kernel<<<B_ * L_ * L_ / 256, 256, 0, stream>>>(asps, avgH, amask, adjr,
                                                       adj_ag, adjagbf);
  kl_denom<<<B_ * L_, 256, 0, stream>>>(adj_s, adj_ag, klp, den_s, den_ag);
  kl_final<<<1, 256, 0, stream>>>(klp, dout);

  for (int li = 0; li < 2; ++li) {
    int Kd = li ? MEM_ : D_;
    const unsigned short* inag = li ? o_agbf : xbf;
    const unsigned short* ins  = li ? o_sbf : xbf;
    const unsigned short* wAT = li ? wa1T : wa0T;
    const float* bA = li ? ba1 : ba0;
    const unsigned short* wST = li ? ws1T : ws0T;
    const float* bS = li ? bs1 : bs0;
    // paired t-GEMMs -> transposed bf16 tT
    gemm_bb<<<dim3(3, 64, 2), 256, 0, stream>>>(
        inag, wAT, nullptr, nullptr, tTag, 8192, MEM_, Kd, 0, 0, 0, sMemSh,
        nullptr, nullptr, 0,
        ins, wST, nullptr, nullptr, tTs, nullptr, nullptr, 1);
    // paired g-GEMMs: g = relu((adj@t + b)/den), outputs g bf16 + gT bf16
    gemm_bb<<<dim3(3, 2, 64), 256, 0, stream>>>(
        adjagbf, tTag, nullptr, g_agbf, gTag, L_, MEM_, L_, sAdjSh, sMemSh, sMemSh,
        sMemSh, bA, den_ag, 1,
        adjsbf, tTs, nullptr, g_sbf, gTs, bS, den_s, 32);
    // paired u-GEMMs
    gemm_bb<<<dim3(3, 64, 2), 256, 0, stream>>>(
        g_agbf, aff1T, nullptr, u1bf, nullptr, 8192, MEM_, MEM_, 0, 0, 0, 0,
        nullptr, nullptr, 0,
        g_sbf, aff2T, nullptr, u2bf, nullptr, nullptr, nullptr, 1);
    // paired fused S+softmax
    gemm_sfmx<<<dim3(4, 64), 256, 0, stream>>>(u1bf, g_sbf, P1bf, u2bf, g_agbf, P2bf);
    // paired PV: o_ag = P1@g_s (B = gTs), o_s = P2@g_ag (B = gTag)
    gemm_bb<<<dim3(3, 2, 64), 256, 0, stream>>>(
        P1bf, gTs, nullptr, o_agbf, nullptr, L_, MEM_, L_, sAdjSh, sMemSh, sMemSh, 0,
        nullptr, nullptr, 0,
        P2bf, gTag, nullptr, o_sbf, nullptr, nullptr, nullptr, 32);
  }

  final_kernel<<<B_, 256, 0, stream>>>(o_agbf, o_sbf, pooled, amask, wc, bc, dout);
}

// Round 10
// 488.501 us; speedup vs baseline: 1.2446x; 1.0191x over previous
//
#include <hip/hip_runtime.h>

#define B_ 32
#define L_ 256
#define D_ 768
#define H_ 12
#define DK_ 64
#define MEM_ 384

typedef __attribute__((ext_vector_type(8))) short bfrag8;    // 8 bf16 (4 VGPRs)
typedef __attribute__((ext_vector_type(8))) unsigned short us8;
typedef __attribute__((ext_vector_type(4))) float f32x4;

// f32 -> bf16 round-to-nearest-even (finite inputs only)
__device__ inline unsigned short f2bf(float f) {
  unsigned u = __float_as_uint(f);
  return (unsigned short)((u + 0x7fffu + ((u >> 16) & 1u)) >> 16);
}
__device__ inline float bf2f(unsigned short u) {
  return __uint_as_float(((unsigned)u) << 16);
}
__device__ inline float tanh_fast(float x) {
  x = fminf(fmaxf(x, -30.f), 30.f);
  float e = __expf(2.f * x);
  return (e - 1.f) * __builtin_amdgcn_rcpf(e + 1.f);
}
// async global->LDS, 16B per lane; LDS dest = wave-uniform base + lane*16
__device__ inline void gload_lds16(const unsigned short* g, unsigned short* l) {
  __builtin_amdgcn_global_load_lds(
      (__attribute__((address_space(1))) void*)(g),
      (__attribute__((address_space(3))) void*)(l), 16, 0, 0);
}

// ---------------- block reduce helpers (256 threads = 4 waves) ----------------
__device__ inline float waveRedSum(float v) {
#pragma unroll
  for (int o = 32; o; o >>= 1) v += __shfl_xor(v, o, 64);
  return v;
}
__device__ inline float waveRedMax(float v) {
#pragma unroll
  for (int o = 32; o; o >>= 1) v = fmaxf(v, __shfl_xor(v, o, 64));
  return v;
}
__device__ inline float blkRedSum(float v, float* red) {
  v = waveRedSum(v);
  int w = threadIdx.x >> 6;
  __syncthreads();
  if ((threadIdx.x & 63) == 0) red[w] = v;
  __syncthreads();
  return red[0] + red[1] + red[2] + red[3];
}
__device__ inline float blkRedMax(float v, float* red) {
  v = waveRedMax(v);
  int w = threadIdx.x >> 6;
  __syncthreads();
  if ((threadIdx.x & 63) == 0) red[w] = v;
  __syncthreads();
  return fmaxf(fmaxf(red[0], red[1]), fmaxf(red[2], red[3]));
}

// ---------------- LayerNorm (dual f32 + bf16 output) ----------------
__global__ __launch_bounds__(256) void ln_kernel(const float* __restrict__ in,
                                                 const float* __restrict__ g,
                                                 const float* __restrict__ bt,
                                                 float* __restrict__ out,
                                                 unsigned short* __restrict__ outbf) {
  long row = blockIdx.x;
  const float* p = in + row * D_;
  float v[3];
#pragma unroll
  for (int i = 0; i < 3; ++i) v[i] = p[threadIdx.x + i * 256];
  __shared__ float red[4];
  float s = v[0] + v[1] + v[2];
  s = blkRedSum(s, red);
  float mu = s * (1.f / D_);
  float ss = 0.f;
#pragma unroll
  for (int i = 0; i < 3; ++i) { float d = v[i] - mu; ss += d * d; }
  ss = blkRedSum(ss, red);
  float sd = sqrtf(ss * (1.f / (D_ - 1)));
  float inv = 1.f / (sd + 1e-6f);
#pragma unroll
  for (int i = 0; i < 3; ++i) {
    int c = threadIdx.x + i * 256;
    float o = g[c] * (v[i] - mu) * inv + bt[c];
    out[row * D_ + c] = o;
    outbf[row * D_ + c] = f2bf(o);
  }
}

// ---------------- transpose + convert: dst[C][R] bf16 = src[R][C] f32 ----------------
__global__ __launch_bounds__(256) void tc_pair(const float* __restrict__ s1,
                                               unsigned short* __restrict__ d1,
                                               const float* __restrict__ s2,
                                               unsigned short* __restrict__ d2,
                                               int R, int C) {
  const float* src = blockIdx.z ? s2 : s1;
  unsigned short* dst = blockIdx.z ? d2 : d1;
  __shared__ float tile[64][65];
  int c0 = blockIdx.x * 64, r0 = blockIdx.y * 64;
  int tx = threadIdx.x & 63, ty = threadIdx.x >> 6;
#pragma unroll
  for (int i = 0; i < 16; ++i)
    tile[ty + i * 4][tx] = src[(long)(r0 + ty + i * 4) * C + c0 + tx];
  __syncthreads();
#pragma unroll
  for (int i = 0; i < 16; ++i)
    dst[(long)(c0 + ty + i * 4) * R + r0 + tx] = f2bf(tile[tx][ty + i * 4]);
}

// ---------------- per-head transpose: wmT[h][e][d] = wm[h][d][e], bf16 ----------------
__global__ __launch_bounds__(256) void tc_wm(const float* __restrict__ wm,
                                             unsigned short* __restrict__ wmT) {
  int h = blockIdx.x;
  __shared__ float tile[64][65];
  int tx = threadIdx.x & 63, ty = threadIdx.x >> 6;
#pragma unroll
  for (int i = 0; i < 16; ++i)
    tile[ty + i * 4][tx] = wm[h * 4096 + (ty + i * 4) * 64 + tx];
  __syncthreads();
#pragma unroll
  for (int i = 0; i < 16; ++i)
    wmT[h * 4096 + (ty + i * 4) * 64 + tx] = f2bf(tile[tx][ty + i * 4]);
}

// ---------------- asp = bf16(mask_row * (x @ wd) + bd), MFMA, no LDS ----------------
__global__ __launch_bounds__(256) void asp_mfma(const unsigned short* __restrict__ xbf,
                                                const unsigned short* __restrict__ wdT,
                                                const float* __restrict__ amask,
                                                const float* __restrict__ bd,
                                                unsigned short* __restrict__ aspbf) {
  int l0 = blockIdx.x << 4;
  int t = threadIdx.x;
  int w = t >> 6, l = t & 63;
  int lr = l & 15, kg = (l >> 4) * 8;
  const unsigned short* ap = xbf + (long)(l0 + lr) * D_ + kg;
  const unsigned short* bp = wdT + (long)(w * 16 + lr) * D_ + kg;
  f32x4 acc = {};
#pragma unroll
  for (int k0 = 0; k0 < D_; k0 += 32) {
    bfrag8 af = *(const bfrag8*)(ap + k0);
    bfrag8 bf = *(const bfrag8*)(bp + k0);
    acc = __builtin_amdgcn_mfma_f32_16x16x32_bf16(af, bf, acc, 0, 0, 0);
  }
  int col = w * 16 + lr;
#pragma unroll
  for (int r = 0; r < 4; ++r) {
    int row = l0 + (l >> 4) * 4 + r;
    float v = acc[r] * amask[row] + bd[col];
    aspbf[(long)row * DK_ + col] = f2bf(v);
  }
}

// ---------------- tmpA[b,h] = aspbf[b] @ Wm[h], MFMA, no LDS ----------------
__global__ __launch_bounds__(256) void asp_wm_v2(const unsigned short* __restrict__ aspbf,
                                                 const unsigned short* __restrict__ wmT,
                                                 unsigned short* __restrict__ tmpA) {
  int bh = blockIdx.x;
  int b = bh / H_, h = bh % H_;
  int t = threadIdx.x;
  int w = t >> 6, l = t & 63;
  int lr = l & 15, kg = (l >> 4) * 8;
  const unsigned short* wp = wmT + h * 4096;
  f32x4 acc[4][4] = {};
#pragma unroll
  for (int ks = 0; ks < 2; ++ks) {
    int k0 = ks * 32;
    bfrag8 af[4], bf[4];
#pragma unroll
    for (int m = 0; m < 4; ++m)
      af[m] = *(const bfrag8*)(aspbf + (long)(b * L_ + w * 64 + m * 16 + lr) * DK_ + k0 + kg);
#pragma unroll
    for (int n = 0; n < 4; ++n)
      bf[n] = *(const bfrag8*)(wp + (n * 16 + lr) * 64 + k0 + kg);
#pragma unroll
    for (int m = 0; m < 4; ++m)
#pragma unroll
      for (int n = 0; n < 4; ++n)
        acc[m][n] = __builtin_amdgcn_mfma_f32_16x16x32_bf16(af[m], bf[n], acc[m][n], 0, 0, 0);
  }
#pragma unroll
  for (int m = 0; m < 4; ++m)
#pragma unroll
    for (int n = 0; n < 4; ++n)
#pragma unroll
      for (int r = 0; r < 4; ++r) {
        int row = w * 64 + m * 16 + (l >> 4) * 4 + r;
        int col = n * 16 + lr;
        tmpA[(((long)b * H_ + h) * L_ + row) * DK_ + col] = f2bf(acc[m][n][r]);
      }
}

// ---------------- all-bf16 MFMA GEMM, global_load_lds staging, BK=64 ------------------
// A bf16 [m][k]; Bt bf16 [n][k]. 128x128 tile, BK=64, 4 waves (2x2), 4x4 frags.
// LDS [128][64] per operand; DMA chunks = 8 rows x 64k; source slot pre-swizzled
// (l&7)^(l>>3); reads use phys slot (kk*4+sg)^(lr&7)  -> ~2-way conflicts.
__global__ __launch_bounds__(256) void gemm_bb(
    const unsigned short* __restrict__ A, const unsigned short* __restrict__ Bt,
    float* __restrict__ C, unsigned short* __restrict__ Cbf,
    unsigned short* __restrict__ CT,
    int M, int N, int K, long sA, long sB, long sC, long sCT,
    const float* __restrict__ bias, const float* __restrict__ rowDiv, int relu,
    const unsigned short* __restrict__ A2, const unsigned short* __restrict__ Bt2,
    float* __restrict__ C2, unsigned short* __restrict__ Cbf2,
    unsigned short* __restrict__ CT2,
    const float* __restrict__ bias2, const float* __restrict__ rowDiv2, int zsplit) {
  __shared__ alignas(16) unsigned short smem[16384];  // As[0:8192) Bs[8192:16384)
  unsigned short* AsS = smem;
  unsigned short* BsS = smem + 8192;
  const int tid = threadIdx.x;
  const int bn = blockIdx.x, bm = blockIdx.y;
  int bz = blockIdx.z;
  const unsigned short* Ap = A; const unsigned short* Btp = Bt;
  float* Cp = C; unsigned short* Cbp = Cbf; unsigned short* CTp = CT;
  const float* biasp = bias; const float* rowDivp = rowDiv;
  if (zsplit > 0 && bz >= zsplit) {
    bz -= zsplit;
    Ap = A2; Btp = Bt2; Cp = C2; Cbp = Cbf2; CTp = CT2; biasp = bias2; rowDivp = rowDiv2;
  }
  Ap += (long)bz * sA; Btp += (long)bz * sB;
  if (Cp) Cp += (long)bz * sC;
  if (Cbp) Cbp += (long)bz * sC;
  if (CTp) CTp += (long)bz * sCT;

  f32x4 acc[4][4] = {};
  const int l = tid & 63, w = tid >> 6;
  const int wr = w >> 1, wc = w & 1;
  const int lr = l & 15, sg = l >> 4;

  // staging: wave w stages chunks 4w..4w+3 per operand; chunk j: rows 32w+8j+(l>>3)
  const int rc = l >> 3;                    // row-in-chunk
  const int sslot = (l & 7) ^ rc;           // pre-swizzled source slot
  const unsigned short* gA[4];
  const unsigned short* gB[4];
  unsigned short* lA[4];
  unsigned short* lB[4];
#pragma unroll
  for (int j = 0; j < 4; ++j) {
    int rowj = w * 32 + j * 8 + rc;
    gA[j] = Ap + (long)(bm * 128 + rowj) * K + sslot * 8;
    gB[j] = Btp + (long)(bn * 128 + rowj) * K + sslot * 8;
    lA[j] = AsS + (w * 4 + j) * 512;
    lB[j] = BsS + (w * 4 + j) * 512;
  }

  // read pointers: row base + swizzled slot offsets for the two k-halves
  const unsigned short* rowA[4];
  const unsigned short* rowB[4];
#pragma unroll
  for (int m = 0; m < 4; ++m) rowA[m] = AsS + (wr * 64 + m * 16 + lr) * 64;
#pragma unroll
  for (int n = 0; n < 4; ++n) rowB[n] = BsS + (wc * 64 + n * 16 + lr) * 64;
  const int off0 = ((sg) ^ (lr & 7)) * 8;
  const int off1 = ((4 + sg) ^ (lr & 7)) * 8;

  for (int k0 = 0; k0 < K; k0 += 64) {
#pragma unroll
    for (int j = 0; j < 4; ++j) {
      gload_lds16(gA[j] + k0, lA[j]);
      gload_lds16(gB[j] + k0, lB[j]);
    }
    __syncthreads();
#pragma unroll
    for (int kk = 0; kk < 2; ++kk) {
      const int off = kk ? off1 : off0;
      bfrag8 af[4], bf[4];
#pragma unroll
      for (int m = 0; m < 4; ++m) af[m] = *(const bfrag8*)(rowA[m] + off);
#pragma unroll
      for (int n = 0; n < 4; ++n) bf[n] = *(const bfrag8*)(rowB[n] + off);
#pragma unroll
      for (int m = 0; m < 4; ++m)
#pragma unroll
        for (int n = 0; n < 4; ++n)
          acc[m][n] = __builtin_amdgcn_mfma_f32_16x16x32_bf16(af[m], bf[n], acc[m][n], 0, 0, 0);
    }
    __syncthreads();
  }

  if (Cp || Cbp) {
#pragma unroll
    for (int m = 0; m < 4; ++m) {
#pragma unroll
      for (int r = 0; r < 4; ++r) {
        int row = bm * 128 + wr * 64 + m * 16 + (l >> 4) * 4 + r;
        float rd = rowDivp ? 1.f / rowDivp[(long)bz * M + row] : 1.f;
#pragma unroll
        for (int n = 0; n < 4; ++n) {
          int col = bn * 128 + wc * 64 + n * 16 + lr;
          float v = acc[m][n][r];
          if (biasp) v += biasp[col];
          v *= rd;
          if (relu) v = fmaxf(v, 0.f);
          if (Cp) Cp[(long)row * N + col] = v;
          if (Cbp) Cbp[(long)row * N + col] = f2bf(v);
        }
      }
    }
  }
  if (CT) {
    auto Ts = (unsigned short(*)[136])smem;  // aliases As/Bs; guarded by barriers
#pragma unroll
    for (int ch = 0; ch < 2; ++ch) {
      __syncthreads();
      if (wc == ch) {
#pragma unroll
        for (int m = 0; m < 4; ++m) {
#pragma unroll
          for (int r = 0; r < 4; ++r) {
            int rowl = wr * 64 + m * 16 + (l >> 4) * 4 + r;
            float rd = rowDivp ? 1.f / rowDivp[(long)bz * M + bm * 128 + rowl] : 1.f;
#pragma unroll
            for (int n = 0; n < 4; ++n) {
              int col = bn * 128 + wc * 64 + n * 16 + lr;
              float v = acc[m][n][r];
              if (biasp) v += biasp[col];
              v *= rd;
              if (relu) v = fmaxf(v, 0.f);
              Ts[n * 16 + lr][rowl] = f2bf(v);
            }
          }
        }
      }
      __syncthreads();
      int trow = tid >> 2, tc = (tid & 3) * 32;
      int colg = bn * 128 + ch * 64 + trow;
      int rowg = bm * 128 + tc;
      unsigned short* dp = CTp + (long)(rowg >> 8) * sCT + (long)colg * 256 + (rowg & 255);
#pragma unroll
      for (int j = 0; j < 4; ++j)
        *(us8*)(dp + j * 8) = *(const us8*)&Ts[trow][tc + j * 8];
    }
  }
}

// ---------------- fused MFMA attention v2: head-pairs + single-barrier combine --------
// block = (b, 16 rows); 4 waves each own 64 cols. Per head pair: local softmax pieces
// (in-reg + 16-lane shfl), write (mx,sum) per wave, ONE barrier, scaled-sum combine.
__global__ __launch_bounds__(256) void attn_mfma(const unsigned short* __restrict__ qbf,
                                                 const unsigned short* __restrict__ kbf,
                                                 const float* __restrict__ srcm,
                                                 float* __restrict__ adj_s,
                                                 unsigned short* __restrict__ adjsbf) {
  int blk = blockIdx.x;
  int b = blk >> 4, l0 = (blk & 15) << 4;
  int t = threadIdx.x;
  int w = t >> 6, l = t & 63;
  int lr = l & 15, kg = (l >> 4) * 8;
  int rbase = (l >> 4) * 4;
  __shared__ float red[6][2][16][8];  // [pair][head][row][0:4 mx | 4:8 sum]
  float acc[4][4] = {};
  float cmv[4];
#pragma unroll
  for (int ct = 0; ct < 4; ++ct) cmv[ct] = srcm[b * L_ + w * 64 + ct * 16 + lr];

#pragma unroll 1
  for (int hp = 0; hp < 6; ++hp) {
    const unsigned short* ap = qbf + ((long)b * L_ + l0 + lr) * D_ + hp * 128 + kg;
    bfrag8 a00 = *(const bfrag8*)ap;
    bfrag8 a01 = *(const bfrag8*)(ap + 32);
    bfrag8 a10 = *(const bfrag8*)(ap + 64);
    bfrag8 a11 = *(const bfrag8*)(ap + 96);
    float sv0[4][4], sv1[4][4];
#pragma unroll
    for (int ct = 0; ct < 4; ++ct) {
      const unsigned short* bp =
          kbf + ((long)b * L_ + w * 64 + ct * 16 + lr) * D_ + hp * 128 + kg;
      bfrag8 b00 = *(const bfrag8*)bp;
      bfrag8 b01 = *(const bfrag8*)(bp + 32);
      bfrag8 b10 = *(const bfrag8*)(bp + 64);
      bfrag8 b11 = *(const bfrag8*)(bp + 96);
      f32x4 c0 = {}, c1 = {};
      c0 = __builtin_amdgcn_mfma_f32_16x16x32_bf16(a00, b00, c0, 0, 0, 0);
      c0 = __builtin_amdgcn_mfma_f32_16x16x32_bf16(a01, b01, c0, 0, 0, 0);
      c1 = __builtin_amdgcn_mfma_f32_16x16x32_bf16(a10, b10, c1, 0, 0, 0);
      c1 = __builtin_amdgcn_mfma_f32_16x16x32_bf16(a11, b11, c1, 0, 0, 0);
      bool msk = (cmv[ct] == 0.f);
#pragma unroll
      for (int r = 0; r < 4; ++r) {
        sv0[ct][r] = msk ? -1e9f : c0[r] * 0.125f;
        sv1[ct][r] = msk ? -1e9f : c1[r] * 0.125f;
      }
    }
    float mx0a[4], mx1a[4];
#pragma unroll
    for (int r = 0; r < 4; ++r) {
      float m0 = fmaxf(fmaxf(sv0[0][r], sv0[1][r]), fmaxf(sv0[2][r], sv0[3][r]));
      float m1 = fmaxf(fmaxf(sv1[0][r], sv1[1][r]), fmaxf(sv1[2][r], sv1[3][r]));
#pragma unroll
      for (int o = 1; o < 16; o <<= 1) {
        m0 = fmaxf(m0, __shfl_xor(m0, o, 64));
        m1 = fmaxf(m1, __shfl_xor(m1, o, 64));
      }
      mx0a[r] = m0; mx1a[r] = m1;
      float s0 = 0.f, s1 = 0.f;
#pragma unroll
      for (int ct = 0; ct < 4; ++ct) {
        float e0 = __expf(sv0[ct][r] - m0);
        float e1 = __expf(sv1[ct][r] - m1);
        sv0[ct][r] = e0; sv1[ct][r] = e1;
        s0 += e0; s1 += e1;
      }
#pragma unroll
      for (int o = 1; o < 16; o <<= 1) {
        s0 += __shfl_xor(s0, o, 64);
        s1 += __shfl_xor(s1, o, 64);
      }
      if (lr == 0) {
        red[hp][0][rbase + r][w] = m0;
        red[hp][0][rbase + r][4 + w] = s0;
        red[hp][1][rbase + r][w] = m1;
        red[hp][1][rbase + r][4 + w] = s1;
      }
    }
    __syncthreads();
#pragma unroll
    for (int r = 0; r < 4; ++r) {
      f32x4 m4 = *(const f32x4*)&red[hp][0][rbase + r][0];
      f32x4 s4 = *(const f32x4*)&red[hp][0][rbase + r][4];
      float mt = fmaxf(fmaxf(m4[0], m4[1]), fmaxf(m4[2], m4[3]));
      float tot = s4[0] * __expf(m4[0] - mt) + s4[1] * __expf(m4[1] - mt) +
                  s4[2] * __expf(m4[2] - mt) + s4[3] * __expf(m4[3] - mt);
      float sc0 = __expf(mx0a[r] - mt) * __builtin_amdgcn_rcpf(tot);
      f32x4 n4 = *(const f32x4*)&red[hp][1][rbase + r][0];
      f32x4 t4 = *(const f32x4*)&red[hp][1][rbase + r][4];
      float nt = fmaxf(fmaxf(n4[0], n4[1]), fmaxf(n4[2], n4[3]));
      float tt = t4[0] * __expf(n4[0] - nt) + t4[1] * __expf(n4[1] - nt) +
                 t4[2] * __expf(n4[2] - nt) + t4[3] * __expf(n4[3] - nt);
      float sc1 = __expf(mx1a[r] - nt) * __builtin_amdgcn_rcpf(tt);
#pragma unroll
      for (int ct = 0; ct < 4; ++ct)
        acc[ct][r] += sv0[ct][r] * sc0 + sv1[ct][r] * sc1;
    }
    // no second barrier: next pair writes a different red[hp] buffer
  }

#pragma unroll
  for (int r = 0; r < 4; ++r) {
    int row = l0 + rbase + r;
    float rm = srcm[b * L_ + row];
#pragma unroll
    for (int ct = 0; ct < 4; ++ct) {
      int col = w * 64 + ct * 16 + lr;
      float v = acc[ct][r] * (1.f / H_);
      if (col == row) v = 1.f;
      v *= rm;
      long idx = ((long)b * L_ + row) * L_ + col;
      adj_s[idx] = v;
      adjsbf[idx] = f2bf(v);
    }
  }
}

// ---------------- fused S-GEMM + row softmax (LDS-staged bf16): P = softmax(u @ g^T) ---
__global__ __launch_bounds__(256) void gemm_sfmx(
    const unsigned short* __restrict__ u1, const unsigned short* __restrict__ g1,
    unsigned short* __restrict__ P1,
    const unsigned short* __restrict__ u2, const unsigned short* __restrict__ g2,
    unsigned short* __restrict__ P2) {
  int bm = blockIdx.x;
  int bz = blockIdx.y;
  const unsigned short* Ap; const unsigned short* Bp; unsigned short* Pp;
  if (bz < 32) {
    Ap = u1 + (long)bz * L_ * MEM_; Bp = g1 + (long)bz * L_ * MEM_;
    Pp = P1 + (long)bz * L_ * L_;
  } else {
    int z = bz - 32;
    Ap = u2 + (long)z * L_ * MEM_; Bp = g2 + (long)z * L_ * MEM_;
    Pp = P2 + (long)z * L_ * L_;
  }
  __shared__ unsigned short As[64][40];
  __shared__ unsigned short Bs[256][40];
  __shared__ float redm[2][64];
  __shared__ float reds[2][64];
  const int t = threadIdx.x;
  const int l = t & 63, w = t >> 6;
  const int wr = w >> 1, wc = w & 1;
  const int lr = l & 15, kg = (l >> 4) * 8;
  f32x4 acc[2][8] = {};
  const int arA = t >> 2, akA = (t & 3) * 8;

  for (int k0 = 0; k0 < MEM_; k0 += 32) {
    *(us8*)&As[arA][akA] = *(const us8*)(Ap + (long)(bm * 64 + arA) * MEM_ + k0 + akA);
#pragma unroll
    for (int j = 0; j < 4; ++j)
      *(us8*)&Bs[t][j * 8] = *(const us8*)(Bp + (long)t * MEM_ + k0 + j * 8);
    __syncthreads();
    bfrag8 af[2], bf[8];
#pragma unroll
    for (int m = 0; m < 2; ++m) af[m] = *(const bfrag8*)&As[wr * 32 + m * 16 + lr][kg];
#pragma unroll
    for (int n = 0; n < 8; ++n) bf[n] = *(const bfrag8*)&Bs[wc * 128 + n * 16 + lr][kg];
#pragma unroll
    for (int m = 0; m < 2; ++m)
#pragma unroll
      for (int n = 0; n < 8; ++n)
        acc[m][n] = __builtin_amdgcn_mfma_f32_16x16x32_bf16(af[m], bf[n], acc[m][n], 0, 0, 0);
    __syncthreads();
  }

#pragma unroll
  for (int m = 0; m < 2; ++m) {
#pragma unroll
    for (int r = 0; r < 4; ++r) {
      int lrow = wr * 32 + m * 16 + (l >> 4) * 4 + r;
      float mx = -1e30f;
#pragma unroll
      for (int n = 0; n < 8; ++n) mx = fmaxf(mx, acc[m][n][r]);
#pragma unroll
      for (int o = 1; o < 16; o <<= 1) mx = fmaxf(mx, __shfl_xor(mx, o, 64));
      if (lr == 0) redm[wc][lrow] = mx;
    }
  }
  __syncthreads();
#pragma unroll
  for (int m = 0; m < 2; ++m) {
#pragma unroll
    for (int r = 0; r < 4; ++r) {
      int lrow = wr * 32 + m * 16 + (l >> 4) * 4 + r;
      float mx = fmaxf(redm[0][lrow], redm[1][lrow]);
      float s = 0.f;
#pragma unroll
      for (int n = 0; n < 8; ++n) {
        float e = __expf(acc[m][n][r] - mx);
        acc[m][n][r] = e;
        s += e;
      }
#pragma unroll
      for (int o = 1; o < 16; o <<= 1) s += __shfl_xor(s, o, 64);
      if (lr == 0) reds[wc][lrow] = s;
    }
  }
  __syncthreads();
#pragma unroll
  for (int m = 0; m < 2; ++m) {
#pragma unroll
    for (int r = 0; r < 4; ++r) {
      int lrow = wr * 32 + m * 16 + (l >> 4) * 4 + r;
      float inv = 1.f / (reds[0][lrow] + reds[1][lrow]);
      int row = bm * 64 + lrow;
#pragma unroll
      for (int n = 0; n < 8; ++n) {
        int col = wc * 128 + n * 16 + lr;
        Pp[(long)row * L_ + col] = f2bf(acc[m][n][r] * inv);
      }
    }
  }
}

// ---------------- asps_mean via MFMA ----------------
__global__ __launch_bounds__(256) void asps_mean_v2(
    const unsigned short* __restrict__ tmpA,
    const unsigned short* __restrict__ kbf,
    const float* __restrict__ bias_m,
    float* __restrict__ asps_mean) {
  int blk = blockIdx.x;
  int b = blk >> 4, l0 = (blk & 15) << 4;
  int t = threadIdx.x;
  int w = t >> 6, l = t & 63;
  int lr = l & 15, kg = (l >> 4) * 8;
  float bm = bias_m[0];
  float accg[4][4] = {};
  for (int h = 0; h < H_; ++h) {
    const unsigned short* ap = tmpA + (((long)b * H_ + h) * L_ + l0 + lr) * 64 + kg;
    bfrag8 af0 = *(const bfrag8*)ap;
    bfrag8 af1 = *(const bfrag8*)(ap + 32);
#pragma unroll
    for (int ct = 0; ct < 4; ++ct) {
      const unsigned short* bp =
          kbf + ((long)b * L_ + w * 64 + ct * 16 + lr) * D_ + h * 64 + kg;
      bfrag8 bf0 = *(const bfrag8*)bp;
      bfrag8 bf1 = *(const bfrag8*)(bp + 32);
      f32x4 accl = {};
      accl = __builtin_amdgcn_mfma_f32_16x16x32_bf16(af0, bf0, accl, 0, 0, 0);
      accl = __builtin_amdgcn_mfma_f32_16x16x32_bf16(af1, bf1, accl, 0, 0, 0);
#pragma unroll
      for (int r = 0; r < 4; ++r) accg[ct][r] += tanh_fast(accl[r] + bm);
    }
  }
#pragma unroll
  for (int ct = 0; ct < 4; ++ct) {
    int col = w * 64 + ct * 16 + lr;
#pragma unroll
    for (int r = 0; r < 4; ++r) {
      int row = l0 + (l >> 4) * 4 + r;
      asps_mean[((long)b * L_ + row) * L_ + col] = accg[ct][r] * (1.f / H_);
    }
  }
}

// ---------------- avgH (1024 threads: 4-way l-split) ----------------
__global__ __launch_bounds__(1024) void avgh_kernel(const float* __restrict__ asps_mean,
                                                    float* __restrict__ avgH) {
  int b = blockIdx.x;
  int m = threadIdx.x & 255, q = threadIdx.x >> 8;
  __shared__ float part[4][256];
  float s = 0.f;
  for (int l = q * 64; l < q * 64 + 64; ++l)
    s += asps_mean[((long)b * L_ + l) * L_ + m];
  part[q][m] = s;
  __syncthreads();
  if (q == 0)
    avgH[b * L_ + m] = (part[0][m] + part[1][m] + part[2][m] + part[3][m]) * (1.f / L_);
}

// ---------------- adj_ag (dual f32 + bf16) ----------------
__global__ __launch_bounds__(256) void adjag_kernel(const float* __restrict__ asps_mean,
                                                    const float* __restrict__ avgH,
                                                    const float* __restrict__ amask,
                                                    const float* __restrict__ adjr,
                                                    float* __restrict__ adj_ag,
                                                    unsigned short* __restrict__ adjagbf) {
  long idx = (long)blockIdx.x * 256 + threadIdx.x;
  int m = idx & 255;
  long bl = idx >> 8;
  int l = (int)(bl & 255);
  int b = (int)(bl >> 8);
  bool rowa = amask[b * L_ + l] > 0.f;
  bool cola = amask[b * L_ + m] > 0.f;
  float asa;
  if (rowa && cola) asa = (l >= m) ? avgH[b * L_ + m] : avgH[b * L_ + l];
  else if (rowa)    asa = avgH[b * L_ + m];
  else if (cola)    asa = avgH[b * L_ + l];
  else              asa = asps_mean[idx];
  float r = (asa > 0.25f) ? 1.f : expf(adjr[idx]);
  float v = r * asa;
  adj_ag[idx] = v;
  adjagbf[idx] = f2bf(v);
}

// ---------------- KL partials + row denominators ----------------
__global__ __launch_bounds__(256) void kl_denom(const float* __restrict__ adj_s,
                                                const float* __restrict__ adj_ag,
                                                float* __restrict__ klpart,
                                                float* __restrict__ den_s,
                                                float* __restrict__ den_ag) {
  long row = blockIdx.x;
  int m = threadIdx.x;
  __shared__ float red[4];
  float s = adj_s[row * L_ + m];
  float a = adj_ag[row * L_ + m];
  float sum_s = blkRedSum(s, red);
  float sum_a = blkRedSum(a, red);
  float mx_s = blkRedMax(s, red);
  float mx_a = blkRedMax(a, red);
  float es = expf(s - mx_s), ea = expf(a - mx_a);
  float ses = blkRedSum(es, red);
  float sea = blkRedSum(ea, red);
  float logq = (s - mx_s) - logf(ses);
  float logp = (a - mx_a) - logf(sea);
  float term = (es / ses) * (logq - logp);
  float kp = blkRedSum(term, red);
  if (m == 0) {
    klpart[row] = kp;
    den_s[row] = sum_s + 1.f;
    den_ag[row] = sum_a + 1.f;
  }
}

__global__ __launch_bounds__(256) void kl_final(const float* __restrict__ klpart,
                                                float* __restrict__ dout) {
  __shared__ float red[4];
  float s = 0.f;
  for (int i = threadIdx.x; i < B_ * L_; i += 256) s += klpart[i];
  s = blkRedSum(s, red);
  if (threadIdx.x == 0) dout[96] = expf(-s * 0.1f);
}

// ---------------- classifier head (bf16 o inputs) ----------------
__global__ __launch_bounds__(256) void final_kernel(const unsigned short* __restrict__ o_ag,
                                                    const unsigned short* __restrict__ o_s,
                                                    const float* __restrict__ pooled,
                                                    const float* __restrict__ amask,
                                                    const float* __restrict__ wc,
                                                    const float* __restrict__ bc,
                                                    float* __restrict__ dout) {
  int b = blockIdx.x, t = threadIdx.x;
  __shared__ float cS[1536];
  __shared__ float maskS[256];
  __shared__ float red[4];
  maskS[t] = amask[b * L_ + t];
  float wn = blkRedSum(maskS[t], red);
  for (int e = t; e < MEM_; e += 256) {
    float s1 = 0.f, s2 = 0.f;
    for (int l = 0; l < L_; ++l) {
      float mk = maskS[l];
      if (mk != 0.f) {
        s1 += mk * bf2f(o_ag[((long)b * L_ + l) * MEM_ + e]);
        s2 += mk * bf2f(o_s[((long)b * L_ + l) * MEM_ + e]);
      }
    }
    cS[e] = s1 / wn;
    cS[MEM_ + e] = s2 / wn;
  }
  for (int j = t; j < D_; j += 256) cS[2 * MEM_ + j] = pooled[b * D_ + j];
  __syncthreads();
  float p0 = 0.f, p1 = 0.f, p2 = 0.f;
  for (int j = t; j < 1536; j += 256) {
    float v = cS[j];
    p0 += v * wc[j * 3 + 0];
    p1 += v * wc[j * 3 + 1];
    p2 += v * wc[j * 3 + 2];
  }
  p0 = blkRedSum(p0, red);
  p1 = blkRedSum(p1, red);
  p2 = blkRedSum(p2, red);
  if (t == 0) {
    dout[b * 3 + 0] = p0 + bc[0];
    dout[b * 3 + 1] = p1 + bc[1];
    dout[b * 3 + 2] = p2 + bc[2];
  }
}

extern "C" void kernel_launch(void* const* d_in, const int* in_sizes, int n_in,
                              void* d_out, int out_size, void* d_ws, size_t ws_size,
                              hipStream_t stream) {
  const float* seq    = (const float*)d_in[0];
  const float* pooled = (const float*)d_in[1];
  const float* adjr   = (const float*)d_in[2];
  const float* srcm   = (const float*)d_in[3];
  const float* amask  = (const float*)d_in[4];
  const float* ln_g   = (const float*)d_in[5];
  const float* ln_b   = (const float*)d_in[6];
  const float* wq     = (const float*)d_in[7];
  const float* bq     = (const float*)d_in[8];
  const float* wk     = (const float*)d_in[9];
  const float* bk     = (const float*)d_in[10];
  const float* wd     = (const float*)d_in[11];
  const float* bd     = (const float*)d_in[12];
  const float* wm     = (const float*)d_in[13];
  const float* bm     = (const float*)d_in[14];
  const float* wa0    = (const float*)d_in[15];
  const float* ba0    = (const float*)d_in[16];
  const float* wa1    = (const float*)d_in[17];
  const float* ba1    = (const float*)d_in[18];
  const float* ws0    = (const float*)d_in[19];
  const float* bs0    = (const float*)d_in[20];
  const float* ws1    = (const float*)d_in[21];
  const float* bs1    = (const float*)d_in[22];
  const float* aff1   = (const float*)d_in[23];
  const float* aff2   = (const float*)d_in[24];
  const float* wc     = (const float*)d_in[25];
  const float* bc     = (const float*)d_in[26];

  float* ws = (float*)d_ws;
  // ---- workspace layout (float units) ----
  float* S0 = ws;                        // 6291456: x f32 -> {o_agbf|o_sbf|gTag|gTs}
  float* S1 = S0 + 6291456;              // 3145728: xbf
  float* S2 = S1 + 3145728;              // 3145728: qbf -> tmpA -> {g_agbf|g_sbf}
  float* S3 = S2 + 3145728;              // 3145728: kbf -> {tTag|tTs} -> {u1bf|u2bf}
  float* S4 = S3 + 3145728;              // 524288 : aspbf + wdT + wmT (shorts)
  float* S5 = S4 + 524288;               // 2097152: asps f32 -> {P1bf|P2bf}
  float* adj_s  = S5 + 2097152;          // 2097152
  float* adj_ag = adj_s + 2097152;       // 2097152
  unsigned short* adjsbf  = (unsigned short*)(adj_ag + 2097152);  // 2097152 sh
  unsigned short* adjagbf = adjsbf + 2097152;                     // 2097152 sh
  unsigned short* wT      = adjagbf + 2097152;                    // 2359296 sh
  unsigned short* wqT   = wT;
  unsigned short* wkT   = wT + 589824;
  unsigned short* wa0T  = wT + 1179648;
  unsigned short* ws0T  = wT + 1474560;
  unsigned short* wa1T  = wT + 1769472;
  unsigned short* ws1T  = wT + 1916928;
  unsigned short* aff1T = wT + 2064384;
  unsigned short* aff2T = wT + 2211840;
  float* tail   = (float*)(wT + 2359296);
  float* avgH   = tail;
  float* den_s  = avgH + 8192;
  float* den_ag = den_s + 8192;
  float* klp    = den_ag + 8192;

  float* x = S0;
  unsigned short* o_agbf = (unsigned short*)S0;
  unsigned short* o_sbf  = o_agbf + 3145728;
  unsigned short* gTag   = o_agbf + 6291456;
  unsigned short* gTs    = o_agbf + 9437184;
  unsigned short* xbf    = (unsigned short*)S1;
  unsigned short* qbf    = (unsigned short*)S2;
  unsigned short* tmpA   = (unsigned short*)S2;
  unsigned short* g_agbf = (unsigned short*)S2;
  unsigned short* g_sbf  = g_agbf + 3145728;
  unsigned short* kbf    = (unsigned short*)S3;
  unsigned short* tTag   = (unsigned short*)S3;
  unsigned short* tTs    = tTag + 3145728;
  unsigned short* u1bf   = (unsigned short*)S3;
  unsigned short* u2bf   = u1bf + 3145728;
  unsigned short* aspbf  = (unsigned short*)S4;      // 524288 shorts
  unsigned short* wdT    = aspbf + 524288;           // 49152 shorts
  unsigned short* wmT    = wdT + 49152;              // 49152 shorts
  float* asps = S5;
  unsigned short* P1bf = (unsigned short*)S5;
  unsigned short* P2bf = P1bf + 2097152;
  float* dout = (float*)d_out;

  const long sAdjSh = (long)L_ * L_;     // 65536 shorts per z
  const long sMemSh = (long)L_ * MEM_;   // 98304 shorts per z

  // ---- weight transpose/convert (once per call) ----
  tc_pair<<<dim3(12, 12, 2), 256, 0, stream>>>(wq, wqT, wk, wkT, 768, 768);
  tc_pair<<<dim3(6, 12, 2), 256, 0, stream>>>(wa0, wa0T, ws0, ws0T, 768, 384);
  tc_pair<<<dim3(6, 6, 2), 256, 0, stream>>>(wa1, wa1T, ws1, ws1T, 384, 384);
  tc_pair<<<dim3(6, 6, 2), 256, 0, stream>>>(aff1, aff1T, aff2, aff2T, 384, 384);
  tc_pair<<<dim3(1, 12, 1), 256, 0, stream>>>(wd, wdT, nullptr, nullptr, 768, 64);
  tc_wm<<<H_, 256, 0, stream>>>(wm, wmT);

  ln_kernel<<<B_ * L_, 256, 0, stream>>>(seq, ln_g, ln_b, x, xbf);
  // paired q/k projections (bf16 in/out)
  gemm_bb<<<dim3(6, 64, 2), 256, 0, stream>>>(
      xbf, wqT, nullptr, qbf, nullptr, 8192, 768, 768, 0, 0, 0, 0, bq, nullptr, 0,
      xbf, wkT, nullptr, kbf, nullptr, bk, nullptr, 1);
  attn_mfma<<<B_ * 16, 256, 0, stream>>>(qbf, kbf, srcm, adj_s, adjsbf);
  // asp chain (MFMA)
  asp_mfma<<<512, 256, 0, stream>>>(xbf, wdT, amask, bd, aspbf);
  asp_wm_v2<<<B_ * H_, 256, 0, stream>>>(aspbf, wmT, tmpA);  // after attn (tmpA aliases qbf)
  asps_mean_v2<<<B_ * 16, 256, 0, stream>>>(tmpA, kbf, bm, asps);
  avgh_kernel<<<B_, 1024, 0, stream>>>(asps, avgH);
  adjag_kernel<<<B_ * L_ * L_ / 256, 256, 0, stream>>>(asps, avgH, amask, adjr,
                                                       adj_ag, adjagbf);
  kl_denom<<<B_ * L_, 256, 0, stream>>>(adj_s, adj_ag, klp, den_s, den_ag);
  kl_final<<<1, 256, 0, stream>>>(klp, dout);

  for (int li = 0; li < 2; ++li) {
    int Kd = li ? MEM_ : D_;
    const unsigned short* inag = li ? o_agbf : xbf;
    const unsigned short* ins  = li ? o_sbf : xbf;
    const unsigned short* wAT = li ? wa1T : wa0T;
    const float* bA = li ? ba1 : ba0;
    const unsigned short* wST = li ? ws1T : ws0T;
    const float* bS = li ? bs1 : bs0;
    // paired t-GEMMs -> transposed bf16 tT
    gemm_bb<<<dim3(3, 64, 2), 256, 0, stream>>>(
        inag, wAT, nullptr, nullptr, tTag, 8192, MEM_, Kd, 0, 0, 0, sMemSh,
        nullptr, nullptr, 0,
        ins, wST, nullptr, nullptr, tTs, nullptr, nullptr, 1);
    // paired g-GEMMs: g = relu((adj@t + b)/den), outputs g bf16 + gT bf16
    gemm_bb<<<dim3(3, 2, 64), 256, 0, stream>>>(
        adjagbf, tTag, nullptr, g_agbf, gTag, L_, MEM_, L_, sAdjSh, sMemSh, sMemSh,
        sMemSh, bA, den_ag, 1,
        adjsbf, tTs, nullptr, g_sbf, gTs, bS, den_s, 32);
    // paired u-GEMMs
    gemm_bb<<<dim3(3, 64, 2), 256, 0, stream>>>(
        g_agbf, aff1T, nullptr, u1bf, nullptr, 8192, MEM_, MEM_, 0, 0, 0, 0,
        nullptr, nullptr, 0,
        g_sbf, aff2T, nullptr, u2bf, nullptr, nullptr, nullptr, 1);
    // paired fused S+softmax
    gemm_sfmx<<<dim3(4, 64), 256, 0, stream>>>(u1bf, g_sbf, P1bf, u2bf, g_agbf, P2bf);
    // paired PV: o_ag = P1@g_s (B = gTs), o_s = P2@g_ag (B = gTag)
    gemm_bb<<<dim3(3, 2, 64), 256, 0, stream>>>(
        P1bf, gTs, nullptr, o_agbf, nullptr, L_, MEM_, L_, sAdjSh, sMemSh, sMemSh, 0,
        nullptr, nullptr, 0,
        P2bf, gTag, nullptr, o_sbf, nullptr, nullptr, nullptr, 32);
  }

  final_kernel<<<B_, 256, 0, stream>>>(o_agbf, o_sbf, pooled, amask, wc, bc, dout);
}

// Round 11
// 432.713 us; speedup vs baseline: 1.4050x; 1.1289x over previous
//
#include <hip/hip_runtime.h>

#define B_ 32
#define L_ 256
#define D_ 768
#define H_ 12
#define DK_ 64
#define MEM_ 384

typedef __attribute__((ext_vector_type(8))) short bfrag8;    // 8 bf16 (4 VGPRs)
typedef __attribute__((ext_vector_type(8))) unsigned short us8;
typedef __attribute__((ext_vector_type(4))) float f32x4;

__device__ inline unsigned short f2bf(float f) {
  unsigned u = __float_as_uint(f);
  return (unsigned short)((u + 0x7fffu + ((u >> 16) & 1u)) >> 16);
}
__device__ inline float bf2f(unsigned short u) {
  return __uint_as_float(((unsigned)u) << 16);
}
__device__ inline float tanh_fast(float x) {
  x = fminf(fmaxf(x, -30.f), 30.f);
  float e = __expf(2.f * x);
  return (e - 1.f) * __builtin_amdgcn_rcpf(e + 1.f);
}
__device__ inline void gload_lds16(const unsigned short* g, unsigned short* l) {
  __builtin_amdgcn_global_load_lds(
      (__attribute__((address_space(1))) void*)(g),
      (__attribute__((address_space(3))) void*)(l), 16, 0, 0);
}

// ---------------- block reduce helpers ----------------
__device__ inline float waveRedSum(float v) {
#pragma unroll
  for (int o = 32; o; o >>= 1) v += __shfl_xor(v, o, 64);
  return v;
}
__device__ inline float waveRedMax(float v) {
#pragma unroll
  for (int o = 32; o; o >>= 1) v = fmaxf(v, __shfl_xor(v, o, 64));
  return v;
}
__device__ inline float blkRedSum(float v, float* red) {
  v = waveRedSum(v);
  int w = threadIdx.x >> 6;
  __syncthreads();
  if ((threadIdx.x & 63) == 0) red[w] = v;
  __syncthreads();
  return red[0] + red[1] + red[2] + red[3];
}
__device__ inline float blkRedMax(float v, float* red) {
  v = waveRedMax(v);
  int w = threadIdx.x >> 6;
  __syncthreads();
  if ((threadIdx.x & 63) == 0) red[w] = v;
  __syncthreads();
  return fmaxf(fmaxf(red[0], red[1]), fmaxf(red[2], red[3]));
}

// ---------------- prep: all weight transposes (blocks 0..599) + LayerNorm (600+) -----
__global__ __launch_bounds__(256) void prep_kernel(
    const float* __restrict__ seq, const float* __restrict__ lng,
    const float* __restrict__ lnb, float* __restrict__ xout,
    unsigned short* __restrict__ xbf,
    const float* __restrict__ wq, unsigned short* __restrict__ wqT,
    const float* __restrict__ wk, unsigned short* __restrict__ wkT,
    const float* __restrict__ wa0, unsigned short* __restrict__ wa0T,
    const float* __restrict__ ws0, unsigned short* __restrict__ ws0T,
    const float* __restrict__ wa1, unsigned short* __restrict__ wa1T,
    const float* __restrict__ ws1, unsigned short* __restrict__ ws1T,
    const float* __restrict__ aff1, unsigned short* __restrict__ aff1T,
    const float* __restrict__ aff2, unsigned short* __restrict__ aff2T,
    const float* __restrict__ wd, unsigned short* __restrict__ wdT,
    const float* __restrict__ wm, unsigned short* __restrict__ wmT) {
  int bid = blockIdx.x;
  if (bid >= 600) {  // ---- LayerNorm row ----
    long row = bid - 600;
    const float* p = seq + row * D_;
    float v[3];
#pragma unroll
    for (int i = 0; i < 3; ++i) v[i] = p[threadIdx.x + i * 256];
    __shared__ float red[4];
    float s = v[0] + v[1] + v[2];
    s = blkRedSum(s, red);
    float mu = s * (1.f / D_);
    float ss = 0.f;
#pragma unroll
    for (int i = 0; i < 3; ++i) { float d = v[i] - mu; ss += d * d; }
    ss = blkRedSum(ss, red);
    float sd = sqrtf(ss * (1.f / (D_ - 1)));
    float inv = 1.f / (sd + 1e-6f);
#pragma unroll
    for (int i = 0; i < 3; ++i) {
      int c = threadIdx.x + i * 256;
      float o = lng[c] * (v[i] - mu) * inv + lnb[c];
      xout[row * D_ + c] = o;
      xbf[row * D_ + c] = f2bf(o);
    }
    return;
  }
  // ---- weight transpose tile ----
  const float* src; unsigned short* dst; int Rr, Cc, tIdx;
  if (bid < 144)      { src = wq;   dst = wqT;   Rr = 768; Cc = 768; tIdx = bid; }
  else if (bid < 288) { src = wk;   dst = wkT;   Rr = 768; Cc = 768; tIdx = bid - 144; }
  else if (bid < 360) { src = wa0;  dst = wa0T;  Rr = 768; Cc = 384; tIdx = bid - 288; }
  else if (bid < 432) { src = ws0;  dst = ws0T;  Rr = 768; Cc = 384; tIdx = bid - 360; }
  else if (bid < 468) { src = wa1;  dst = wa1T;  Rr = 384; Cc = 384; tIdx = bid - 432; }
  else if (bid < 504) { src = ws1;  dst = ws1T;  Rr = 384; Cc = 384; tIdx = bid - 468; }
  else if (bid < 540) { src = aff1; dst = aff1T; Rr = 384; Cc = 384; tIdx = bid - 504; }
  else if (bid < 576) { src = aff2; dst = aff2T; Rr = 384; Cc = 384; tIdx = bid - 540; }
  else if (bid < 588) { src = wd;   dst = wdT;   Rr = 768; Cc = 64;  tIdx = bid - 576; }
  else { int h = bid - 588; src = wm + h * 4096; dst = wmT + h * 4096; Rr = 64; Cc = 64; tIdx = 0; }
  __shared__ float tile[64][65];
  int nx = Cc >> 6;
  int c0 = (tIdx % nx) * 64, r0 = (tIdx / nx) * 64;
  int tx = threadIdx.x & 63, ty = threadIdx.x >> 6;
#pragma unroll
  for (int i = 0; i < 16; ++i)
    tile[ty + i * 4][tx] = src[(long)(r0 + ty + i * 4) * Cc + c0 + tx];
  __syncthreads();
#pragma unroll
  for (int i = 0; i < 16; ++i)
    dst[(long)(c0 + ty + i * 4) * Rr + r0 + tx] = f2bf(tile[tx][ty + i * 4]);
}

// ---------------- all-bf16 MFMA GEMM, DMA staging, BK=32, MR x 128 tile --------------
// MR=128: 4 waves 2x2, 4x4 frags. MR=64: 4 waves 2x2 (wave 32 rows x 64 cols), 2x4.
// Swizzle: phys slot = logical ^ ((row>>1)&3)  (2 lanes/bank, free).
template <int MR>
__global__ __launch_bounds__(256) void gemm_bb(
    const unsigned short* __restrict__ A, const unsigned short* __restrict__ Bt,
    float* __restrict__ C, unsigned short* __restrict__ Cbf,
    unsigned short* __restrict__ CT,
    int M, int N, int K, long sA, long sB, long sC, long sCT,
    const float* __restrict__ bias, const float* __restrict__ rowDiv, int relu,
    const unsigned short* __restrict__ A2, const unsigned short* __restrict__ Bt2,
    float* __restrict__ C2, unsigned short* __restrict__ Cbf2,
    unsigned short* __restrict__ CT2,
    const float* __restrict__ bias2, const float* __restrict__ rowDiv2, int zsplit) {
  constexpr int MFRAG = MR / 32;   // m-frags per wave
  constexpr int RW = MR / 2;       // rows per wave
  constexpr int ASH = MR * 32;     // A tile shorts
  constexpr int TSH = 64 * (MR + 8);
  constexpr int SMN = (ASH + 4096 > TSH) ? (ASH + 4096) : TSH;
  __shared__ alignas(16) unsigned short smem[SMN];
  unsigned short* AsS = smem;
  unsigned short* BsS = smem + ASH;
  const int tid = threadIdx.x;
  const int bn = blockIdx.x, bm = blockIdx.y;
  int bz = blockIdx.z;
  const unsigned short* Ap = A; const unsigned short* Btp = Bt;
  float* Cp = C; unsigned short* Cbp = Cbf; unsigned short* CTp = CT;
  const float* biasp = bias; const float* rowDivp = rowDiv;
  if (zsplit > 0 && bz >= zsplit) {
    bz -= zsplit;
    Ap = A2; Btp = Bt2; Cp = C2; Cbp = Cbf2; CTp = CT2; biasp = bias2; rowDivp = rowDiv2;
  }
  Ap += (long)bz * sA; Btp += (long)bz * sB;
  if (Cp) Cp += (long)bz * sC;
  if (Cbp) Cbp += (long)bz * sC;
  if (CTp) CTp += (long)bz * sCT;

  f32x4 acc[MFRAG][4] = {};
  const int l = tid & 63, w = tid >> 6;
  const int wr = w >> 1, wc = w & 1;
  const int lr = l & 15, sg = l >> 4;

  // staging: chunk = 16 rows; lane l: row-in-chunk rc = l>>2, source slot pre-swizzled
  const int rc = l >> 2;
  const int sslot = (l & 3) ^ ((rc >> 1) & 3);
  const unsigned short* gA0 = Ap + (long)(bm * MR + w * 16 + rc) * K + sslot * 8;
  const unsigned short* gA1 = (MR == 128)
      ? Ap + (long)(bm * MR + (w + 4) * 16 + rc) * K + sslot * 8 : nullptr;
  const unsigned short* gB0 = Btp + (long)(bn * 128 + w * 16 + rc) * K + sslot * 8;
  const unsigned short* gB1 = Btp + (long)(bn * 128 + (w + 4) * 16 + rc) * K + sslot * 8;
  unsigned short* lA0 = AsS + w * 512;
  unsigned short* lA1 = AsS + (w + 4) * 512;
  unsigned short* lB0 = BsS + w * 512;
  unsigned short* lB1 = BsS + (w + 4) * 512;

  const int off = (sg ^ ((lr >> 1) & 3)) * 8;
  const unsigned short* arp[MFRAG];
  const unsigned short* brp[4];
#pragma unroll
  for (int m = 0; m < MFRAG; ++m)
    arp[m] = AsS + (wr * RW + m * 16 + lr) * 32 + off;
#pragma unroll
  for (int n = 0; n < 4; ++n)
    brp[n] = BsS + (wc * 64 + n * 16 + lr) * 32 + off;

  for (int k0 = 0; k0 < K; k0 += 32) {
    gload_lds16(gA0 + k0, lA0);
    if (MR == 128) gload_lds16(gA1 + k0, lA1);
    gload_lds16(gB0 + k0, lB0);
    gload_lds16(gB1 + k0, lB1);
    __syncthreads();
    bfrag8 af[MFRAG], bf[4];
#pragma unroll
    for (int m = 0; m < MFRAG; ++m) af[m] = *(const bfrag8*)(arp[m] + 0);
#pragma unroll
    for (int n = 0; n < 4; ++n) bf[n] = *(const bfrag8*)(brp[n] + 0);
#pragma unroll
    for (int m = 0; m < MFRAG; ++m)
#pragma unroll
      for (int n = 0; n < 4; ++n)
        acc[m][n] = __builtin_amdgcn_mfma_f32_16x16x32_bf16(af[m], bf[n], acc[m][n], 0, 0, 0);
    __syncthreads();
  }

  if (Cp || Cbp) {
#pragma unroll
    for (int m = 0; m < MFRAG; ++m) {
#pragma unroll
      for (int r = 0; r < 4; ++r) {
        int row = bm * MR + wr * RW + m * 16 + (l >> 4) * 4 + r;
        float rd = rowDivp ? 1.f / rowDivp[(long)bz * M + row] : 1.f;
#pragma unroll
        for (int n = 0; n < 4; ++n) {
          int col = bn * 128 + wc * 64 + n * 16 + lr;
          float v = acc[m][n][r];
          if (biasp) v += biasp[col];
          v *= rd;
          if (relu) v = fmaxf(v, 0.f);
          if (Cp) Cp[(long)row * N + col] = v;
          if (Cbp) Cbp[(long)row * N + col] = f2bf(v);
        }
      }
    }
  }
  if (CT) {
    auto Ts = (unsigned short(*)[MR + 8])smem;  // aliases As/Bs; guarded by barriers
#pragma unroll
    for (int ch = 0; ch < 2; ++ch) {
      __syncthreads();
      if (wc == ch) {
#pragma unroll
        for (int m = 0; m < MFRAG; ++m) {
#pragma unroll
          for (int r = 0; r < 4; ++r) {
            int rowl = wr * RW + m * 16 + (l >> 4) * 4 + r;
            float rd = rowDivp ? 1.f / rowDivp[(long)bz * M + bm * MR + rowl] : 1.f;
#pragma unroll
            for (int n = 0; n < 4; ++n) {
              int col = bn * 128 + wc * 64 + n * 16 + lr;
              float v = acc[m][n][r];
              if (biasp) v += biasp[col];
              v *= rd;
              if (relu) v = fmaxf(v, 0.f);
              Ts[n * 16 + lr][rowl] = f2bf(v);
            }
          }
        }
      }
      __syncthreads();
      int trow = tid >> 2, tc = (tid & 3) * (MR / 4);
      int colg = bn * 128 + ch * 64 + trow;
      int rowg = bm * MR + tc;
      unsigned short* dp = CTp + (long)(rowg >> 8) * sCT + (long)colg * 256 + (rowg & 255);
#pragma unroll
      for (int j = 0; j < MR / 32; ++j)
        *(us8*)(dp + j * 8) = *(const us8*)&Ts[trow][tc + j * 8];
    }
  }
}

// ---------------- fused attention (blocks 0..511) + asp projection (512..1023) --------
__global__ __launch_bounds__(256) void attn_asp(
    const unsigned short* __restrict__ qbf, const unsigned short* __restrict__ kbf,
    const float* __restrict__ srcm, float* __restrict__ adj_s,
    unsigned short* __restrict__ adjsbf,
    const unsigned short* __restrict__ xbf, const unsigned short* __restrict__ wdT,
    const float* __restrict__ amask, const float* __restrict__ bd,
    unsigned short* __restrict__ aspbf) {
  int t = threadIdx.x;
  int w = t >> 6, l = t & 63;
  int lr = l & 15, kg = (l >> 4) * 8;
  if (blockIdx.x >= 512) {  // ---- asp = bf16(mask_row*(x@wd)+bd), MFMA, no LDS ----
    int l0 = (blockIdx.x - 512) << 4;
    const unsigned short* ap = xbf + (long)(l0 + lr) * D_ + kg;
    const unsigned short* bp = wdT + (long)(w * 16 + lr) * D_ + kg;
    f32x4 acc = {};
#pragma unroll
    for (int k0 = 0; k0 < D_; k0 += 32) {
      bfrag8 af = *(const bfrag8*)(ap + k0);
      bfrag8 bf = *(const bfrag8*)(bp + k0);
      acc = __builtin_amdgcn_mfma_f32_16x16x32_bf16(af, bf, acc, 0, 0, 0);
    }
    int col = w * 16 + lr;
#pragma unroll
    for (int r = 0; r < 4; ++r) {
      int row = l0 + (l >> 4) * 4 + r;
      float v = acc[r] * amask[row] + bd[col];
      aspbf[(long)row * DK_ + col] = f2bf(v);
    }
    return;
  }
  // ---- attention: head-pairs + single-barrier scaled-sum combine ----
  int blk = blockIdx.x;
  int b = blk >> 4, l0 = (blk & 15) << 4;
  int rbase = (l >> 4) * 4;
  __shared__ float red[6][2][16][8];
  float acc[4][4] = {};
  float cmv[4];
#pragma unroll
  for (int ct = 0; ct < 4; ++ct) cmv[ct] = srcm[b * L_ + w * 64 + ct * 16 + lr];

#pragma unroll 1
  for (int hp = 0; hp < 6; ++hp) {
    const unsigned short* ap = qbf + ((long)b * L_ + l0 + lr) * D_ + hp * 128 + kg;
    bfrag8 a00 = *(const bfrag8*)ap;
    bfrag8 a01 = *(const bfrag8*)(ap + 32);
    bfrag8 a10 = *(const bfrag8*)(ap + 64);
    bfrag8 a11 = *(const bfrag8*)(ap + 96);
    float sv0[4][4], sv1[4][4];
#pragma unroll
    for (int ct = 0; ct < 4; ++ct) {
      const unsigned short* bp =
          kbf + ((long)b * L_ + w * 64 + ct * 16 + lr) * D_ + hp * 128 + kg;
      bfrag8 b00 = *(const bfrag8*)bp;
      bfrag8 b01 = *(const bfrag8*)(bp + 32);
      bfrag8 b10 = *(const bfrag8*)(bp + 64);
      bfrag8 b11 = *(const bfrag8*)(bp + 96);
      f32x4 c0 = {}, c1 = {};
      c0 = __builtin_amdgcn_mfma_f32_16x16x32_bf16(a00, b00, c0, 0, 0, 0);
      c0 = __builtin_amdgcn_mfma_f32_16x16x32_bf16(a01, b01, c0, 0, 0, 0);
      c1 = __builtin_amdgcn_mfma_f32_16x16x32_bf16(a10, b10, c1, 0, 0, 0);
      c1 = __builtin_amdgcn_mfma_f32_16x16x32_bf16(a11, b11, c1, 0, 0, 0);
      bool msk = (cmv[ct] == 0.f);
#pragma unroll
      for (int r = 0; r < 4; ++r) {
        sv0[ct][r] = msk ? -1e9f : c0[r] * 0.125f;
        sv1[ct][r] = msk ? -1e9f : c1[r] * 0.125f;
      }
    }
    float mx0a[4], mx1a[4];
#pragma unroll
    for (int r = 0; r < 4; ++r) {
      float m0 = fmaxf(fmaxf(sv0[0][r], sv0[1][r]), fmaxf(sv0[2][r], sv0[3][r]));
      float m1 = fmaxf(fmaxf(sv1[0][r], sv1[1][r]), fmaxf(sv1[2][r], sv1[3][r]));
#pragma unroll
      for (int o = 1; o < 16; o <<= 1) {
        m0 = fmaxf(m0, __shfl_xor(m0, o, 64));
        m1 = fmaxf(m1, __shfl_xor(m1, o, 64));
      }
      mx0a[r] = m0; mx1a[r] = m1;
      float s0 = 0.f, s1 = 0.f;
#pragma unroll
      for (int ct = 0; ct < 4; ++ct) {
        float e0 = __expf(sv0[ct][r] - m0);
        float e1 = __expf(sv1[ct][r] - m1);
        sv0[ct][r] = e0; sv1[ct][r] = e1;
        s0 += e0; s1 += e1;
      }
#pragma unroll
      for (int o = 1; o < 16; o <<= 1) {
        s0 += __shfl_xor(s0, o, 64);
        s1 += __shfl_xor(s1, o, 64);
      }
      if (lr == 0) {
        red[hp][0][rbase + r][w] = m0;
        red[hp][0][rbase + r][4 + w] = s0;
        red[hp][1][rbase + r][w] = m1;
        red[hp][1][rbase + r][4 + w] = s1;
      }
    }
    __syncthreads();
#pragma unroll
    for (int r = 0; r < 4; ++r) {
      f32x4 m4 = *(const f32x4*)&red[hp][0][rbase + r][0];
      f32x4 s4 = *(const f32x4*)&red[hp][0][rbase + r][4];
      float mt = fmaxf(fmaxf(m4[0], m4[1]), fmaxf(m4[2], m4[3]));
      float tot = s4[0] * __expf(m4[0] - mt) + s4[1] * __expf(m4[1] - mt) +
                  s4[2] * __expf(m4[2] - mt) + s4[3] * __expf(m4[3] - mt);
      float sc0 = __expf(mx0a[r] - mt) * __builtin_amdgcn_rcpf(tot);
      f32x4 n4 = *(const f32x4*)&red[hp][1][rbase + r][0];
      f32x4 t4 = *(const f32x4*)&red[hp][1][rbase + r][4];
      float nt = fmaxf(fmaxf(n4[0], n4[1]), fmaxf(n4[2], n4[3]));
      float tt = t4[0] * __expf(n4[0] - nt) + t4[1] * __expf(n4[1] - nt) +
                 t4[2] * __expf(n4[2] - nt) + t4[3] * __expf(n4[3] - nt);
      float sc1 = __expf(mx1a[r] - nt) * __builtin_amdgcn_rcpf(tt);
#pragma unroll
      for (int ct = 0; ct < 4; ++ct)
        acc[ct][r] += sv0[ct][r] * sc0 + sv1[ct][r] * sc1;
    }
  }

#pragma unroll
  for (int r = 0; r < 4; ++r) {
    int row = l0 + rbase + r;
    float rm = srcm[b * L_ + row];
#pragma unroll
    for (int ct = 0; ct < 4; ++ct) {
      int col = w * 64 + ct * 16 + lr;
      float v = acc[ct][r] * (1.f / H_);
      if (col == row) v = 1.f;
      v *= rm;
      long idx = ((long)b * L_ + row) * L_ + col;
      adj_s[idx] = v;
      adjsbf[idx] = f2bf(v);
    }
  }
}

// ---------------- tmpA[b,h] = aspbf[b] @ Wm[h], MFMA, no LDS ----------------
__global__ __launch_bounds__(256) void asp_wm_v2(const unsigned short* __restrict__ aspbf,
                                                 const unsigned short* __restrict__ wmT,
                                                 unsigned short* __restrict__ tmpA) {
  int bh = blockIdx.x;
  int b = bh / H_, h = bh % H_;
  int t = threadIdx.x;
  int w = t >> 6, l = t & 63;
  int lr = l & 15, kg = (l >> 4) * 8;
  const unsigned short* wp = wmT + h * 4096;
  f32x4 acc[4][4] = {};
#pragma unroll
  for (int ks = 0; ks < 2; ++ks) {
    int k0 = ks * 32;
    bfrag8 af[4], bf[4];
#pragma unroll
    for (int m = 0; m < 4; ++m)
      af[m] = *(const bfrag8*)(aspbf + (long)(b * L_ + w * 64 + m * 16 + lr) * DK_ + k0 + kg);
#pragma unroll
    for (int n = 0; n < 4; ++n)
      bf[n] = *(const bfrag8*)(wp + (n * 16 + lr) * 64 + k0 + kg);
#pragma unroll
    for (int m = 0; m < 4; ++m)
#pragma unroll
      for (int n = 0; n < 4; ++n)
        acc[m][n] = __builtin_amdgcn_mfma_f32_16x16x32_bf16(af[m], bf[n], acc[m][n], 0, 0, 0);
  }
#pragma unroll
  for (int m = 0; m < 4; ++m)
#pragma unroll
    for (int n = 0; n < 4; ++n)
#pragma unroll
      for (int r = 0; r < 4; ++r) {
        int row = w * 64 + m * 16 + (l >> 4) * 4 + r;
        int col = n * 16 + lr;
        tmpA[(((long)b * H_ + h) * L_ + row) * DK_ + col] = f2bf(acc[m][n][r]);
      }
}

// ---------------- fused S-GEMM + row softmax (LDS-staged bf16) ----------------
__global__ __launch_bounds__(256) void gemm_sfmx(
    const unsigned short* __restrict__ u1, const unsigned short* __restrict__ g1,
    unsigned short* __restrict__ P1,
    const unsigned short* __restrict__ u2, const unsigned short* __restrict__ g2,
    unsigned short* __restrict__ P2) {
  int bm = blockIdx.x;
  int bz = blockIdx.y;
  const unsigned short* Ap; const unsigned short* Bp; unsigned short* Pp;
  if (bz < 32) {
    Ap = u1 + (long)bz * L_ * MEM_; Bp = g1 + (long)bz * L_ * MEM_;
    Pp = P1 + (long)bz * L_ * L_;
  } else {
    int z = bz - 32;
    Ap = u2 + (long)z * L_ * MEM_; Bp = g2 + (long)z * L_ * MEM_;
    Pp = P2 + (long)z * L_ * L_;
  }
  __shared__ unsigned short As[64][40];
  __shared__ unsigned short Bs[256][40];
  __shared__ float redm[2][64];
  __shared__ float reds[2][64];
  const int t = threadIdx.x;
  const int l = t & 63, w = t >> 6;
  const int wr = w >> 1, wc = w & 1;
  const int lr = l & 15, kg = (l >> 4) * 8;
  f32x4 acc[2][8] = {};
  const int arA = t >> 2, akA = (t & 3) * 8;

  for (int k0 = 0; k0 < MEM_; k0 += 32) {
    *(us8*)&As[arA][akA] = *(const us8*)(Ap + (long)(bm * 64 + arA) * MEM_ + k0 + akA);
#pragma unroll
    for (int j = 0; j < 4; ++j)
      *(us8*)&Bs[t][j * 8] = *(const us8*)(Bp + (long)t * MEM_ + k0 + j * 8);
    __syncthreads();
    bfrag8 af[2], bf[8];
#pragma unroll
    for (int m = 0; m < 2; ++m) af[m] = *(const bfrag8*)&As[wr * 32 + m * 16 + lr][kg];
#pragma unroll
    for (int n = 0; n < 8; ++n) bf[n] = *(const bfrag8*)&Bs[wc * 128 + n * 16 + lr][kg];
#pragma unroll
    for (int m = 0; m < 2; ++m)
#pragma unroll
      for (int n = 0; n < 8; ++n)
        acc[m][n] = __builtin_amdgcn_mfma_f32_16x16x32_bf16(af[m], bf[n], acc[m][n], 0, 0, 0);
    __syncthreads();
  }

#pragma unroll
  for (int m = 0; m < 2; ++m) {
#pragma unroll
    for (int r = 0; r < 4; ++r) {
      int lrow = wr * 32 + m * 16 + (l >> 4) * 4 + r;
      float mx = -1e30f;
#pragma unroll
      for (int n = 0; n < 8; ++n) mx = fmaxf(mx, acc[m][n][r]);
#pragma unroll
      for (int o = 1; o < 16; o <<= 1) mx = fmaxf(mx, __shfl_xor(mx, o, 64));
      if (lr == 0) redm[wc][lrow] = mx;
    }
  }
  __syncthreads();
#pragma unroll
  for (int m = 0; m < 2; ++m) {
#pragma unroll
    for (int r = 0; r < 4; ++r) {
      int lrow = wr * 32 + m * 16 + (l >> 4) * 4 + r;
      float mx = fmaxf(redm[0][lrow], redm[1][lrow]);
      float s = 0.f;
#pragma unroll
      for (int n = 0; n < 8; ++n) {
        float e = __expf(acc[m][n][r] - mx);
        acc[m][n][r] = e;
        s += e;
      }
#pragma unroll
      for (int o = 1; o < 16; o <<= 1) s += __shfl_xor(s, o, 64);
      if (lr == 0) reds[wc][lrow] = s;
    }
  }
  __syncthreads();
#pragma unroll
  for (int m = 0; m < 2; ++m) {
#pragma unroll
    for (int r = 0; r < 4; ++r) {
      int lrow = wr * 32 + m * 16 + (l >> 4) * 4 + r;
      float inv = 1.f / (reds[0][lrow] + reds[1][lrow]);
      int row = bm * 64 + lrow;
#pragma unroll
      for (int n = 0; n < 8; ++n) {
        int col = wc * 128 + n * 16 + lr;
        Pp[(long)row * L_ + col] = f2bf(acc[m][n][r] * inv);
      }
    }
  }
}

// ---------------- asps_mean via MFMA ----------------
__global__ __launch_bounds__(256) void asps_mean_v2(
    const unsigned short* __restrict__ tmpA,
    const unsigned short* __restrict__ kbf,
    const float* __restrict__ bias_m,
    float* __restrict__ asps_mean) {
  int blk = blockIdx.x;
  int b = blk >> 4, l0 = (blk & 15) << 4;
  int t = threadIdx.x;
  int w = t >> 6, l = t & 63;
  int lr = l & 15, kg = (l >> 4) * 8;
  float bm = bias_m[0];
  float accg[4][4] = {};
  for (int h = 0; h < H_; ++h) {
    const unsigned short* ap = tmpA + (((long)b * H_ + h) * L_ + l0 + lr) * 64 + kg;
    bfrag8 af0 = *(const bfrag8*)ap;
    bfrag8 af1 = *(const bfrag8*)(ap + 32);
#pragma unroll
    for (int ct = 0; ct < 4; ++ct) {
      const unsigned short* bp =
          kbf + ((long)b * L_ + w * 64 + ct * 16 + lr) * D_ + h * 64 + kg;
      bfrag8 bf0 = *(const bfrag8*)bp;
      bfrag8 bf1 = *(const bfrag8*)(bp + 32);
      f32x4 accl = {};
      accl = __builtin_amdgcn_mfma_f32_16x16x32_bf16(af0, bf0, accl, 0, 0, 0);
      accl = __builtin_amdgcn_mfma_f32_16x16x32_bf16(af1, bf1, accl, 0, 0, 0);
#pragma unroll
      for (int r = 0; r < 4; ++r) accg[ct][r] += tanh_fast(accl[r] + bm);
    }
  }
#pragma unroll
  for (int ct = 0; ct < 4; ++ct) {
    int col = w * 64 + ct * 16 + lr;
#pragma unroll
    for (int r = 0; r < 4; ++r) {
      int row = l0 + (l >> 4) * 4 + r;
      asps_mean[((long)b * L_ + row) * L_ + col] = accg[ct][r] * (1.f / H_);
    }
  }
}

// ---------------- avgH ----------------
__global__ __launch_bounds__(1024) void avgh_kernel(const float* __restrict__ asps_mean,
                                                    float* __restrict__ avgH) {
  int b = blockIdx.x;
  int m = threadIdx.x & 255, q = threadIdx.x >> 8;
  __shared__ float part[4][256];
  float s = 0.f;
  for (int l = q * 64; l < q * 64 + 64; ++l)
    s += asps_mean[((long)b * L_ + l) * L_ + m];
  part[q][m] = s;
  __syncthreads();
  if (q == 0)
    avgH[b * L_ + m] = (part[0][m] + part[1][m] + part[2][m] + part[3][m]) * (1.f / L_);
}

// ---------------- adj_ag (dual f32 + bf16) ----------------
__global__ __launch_bounds__(256) void adjag_kernel(const float* __restrict__ asps_mean,
                                                    const float* __restrict__ avgH,
                                                    const float* __restrict__ amask,
                                                    const float* __restrict__ adjr,
                                                    float* __restrict__ adj_ag,
                                                    unsigned short* __restrict__ adjagbf) {
  long idx = (long)blockIdx.x * 256 + threadIdx.x;
  int m = idx & 255;
  long bl = idx >> 8;
  int l = (int)(bl & 255);
  int b = (int)(bl >> 8);
  bool rowa = amask[b * L_ + l] > 0.f;
  bool cola = amask[b * L_ + m] > 0.f;
  float asa;
  if (rowa && cola) asa = (l >= m) ? avgH[b * L_ + m] : avgH[b * L_ + l];
  else if (rowa)    asa = avgH[b * L_ + m];
  else if (cola)    asa = avgH[b * L_ + l];
  else              asa = asps_mean[idx];
  float r = (asa > 0.25f) ? 1.f : expf(adjr[idx]);
  float v = r * asa;
  adj_ag[idx] = v;
  adjagbf[idx] = f2bf(v);
}

// ---------------- KL partials + row denominators ----------------
__global__ __launch_bounds__(256) void kl_denom(const float* __restrict__ adj_s,
                                                const float* __restrict__ adj_ag,
                                                float* __restrict__ klpart,
                                                float* __restrict__ den_s,
                                                float* __restrict__ den_ag) {
  long row = blockIdx.x;
  int m = threadIdx.x;
  __shared__ float red[4];
  float s = adj_s[row * L_ + m];
  float a = adj_ag[row * L_ + m];
  float sum_s = blkRedSum(s, red);
  float sum_a = blkRedSum(a, red);
  float mx_s = blkRedMax(s, red);
  float mx_a = blkRedMax(a, red);
  float es = expf(s - mx_s), ea = expf(a - mx_a);
  float ses = blkRedSum(es, red);
  float sea = blkRedSum(ea, red);
  float logq = (s - mx_s) - logf(ses);
  float logp = (a - mx_a) - logf(sea);
  float term = (es / ses) * (logq - logp);
  float kp = blkRedSum(term, red);
  if (m == 0) {
    klpart[row] = kp;
    den_s[row] = sum_s + 1.f;
    den_ag[row] = sum_a + 1.f;
  }
}

__global__ __launch_bounds__(256) void kl_final(const float* __restrict__ klpart,
                                                float* __restrict__ dout) {
  __shared__ float red[4];
  float s = 0.f;
  for (int i = threadIdx.x; i < B_ * L_; i += 256) s += klpart[i];
  s = blkRedSum(s, red);
  if (threadIdx.x == 0) dout[96] = expf(-s * 0.1f);
}

// ---------------- classifier head (bf16 o inputs) ----------------
__global__ __launch_bounds__(256) void final_kernel(const unsigned short* __restrict__ o_ag,
                                                    const unsigned short* __restrict__ o_s,
                                                    const float* __restrict__ pooled,
                                                    const float* __restrict__ amask,
                                                    const float* __restrict__ wc,
                                                    const float* __restrict__ bc,
                                                    float* __restrict__ dout) {
  int b = blockIdx.x, t = threadIdx.x;
  __shared__ float cS[1536];
  __shared__ float maskS[256];
  __shared__ float red[4];
  maskS[t] = amask[b * L_ + t];
  float wn = blkRedSum(maskS[t], red);
  for (int e = t; e < MEM_; e += 256) {
    float s1 = 0.f, s2 = 0.f;
    for (int l = 0; l < L_; ++l) {
      float mk = maskS[l];
      if (mk != 0.f) {
        s1 += mk * bf2f(o_ag[((long)b * L_ + l) * MEM_ + e]);
        s2 += mk * bf2f(o_s[((long)b * L_ + l) * MEM_ + e]);
      }
    }
    cS[e] = s1 / wn;
    cS[MEM_ + e] = s2 / wn;
  }
  for (int j = t; j < D_; j += 256) cS[2 * MEM_ + j] = pooled[b * D_ + j];
  __syncthreads();
  float p0 = 0.f, p1 = 0.f, p2 = 0.f;
  for (int j = t; j < 1536; j += 256) {
    float v = cS[j];
    p0 += v * wc[j * 3 + 0];
    p1 += v * wc[j * 3 + 1];
    p2 += v * wc[j * 3 + 2];
  }
  p0 = blkRedSum(p0, red);
  p1 = blkRedSum(p1, red);
  p2 = blkRedSum(p2, red);
  if (t == 0) {
    dout[b * 3 + 0] = p0 + bc[0];
    dout[b * 3 + 1] = p1 + bc[1];
    dout[b * 3 + 2] = p2 + bc[2];
  }
}

extern "C" void kernel_launch(void* const* d_in, const int* in_sizes, int n_in,
                              void* d_out, int out_size, void* d_ws, size_t ws_size,
                              hipStream_t stream) {
  const float* seq    = (const float*)d_in[0];
  const float* pooled = (const float*)d_in[1];
  const float* adjr   = (const float*)d_in[2];
  const float* srcm   = (const float*)d_in[3];
  const float* amask  = (const float*)d_in[4];
  const float* ln_g   = (const float*)d_in[5];
  const float* ln_b   = (const float*)d_in[6];
  const float* wq     = (const float*)d_in[7];
  const float* bq     = (const float*)d_in[8];
  const float* wk     = (const float*)d_in[9];
  const float* bk     = (const float*)d_in[10];
  const float* wd     = (const float*)d_in[11];
  const float* bd     = (const float*)d_in[12];
  const float* wm     = (const float*)d_in[13];
  const float* bm     = (const float*)d_in[14];
  const float* wa0    = (const float*)d_in[15];
  const float* ba0    = (const float*)d_in[16];
  const float* wa1    = (const float*)d_in[17];
  const float* ba1    = (const float*)d_in[18];
  const float* ws0    = (const float*)d_in[19];
  const float* bs0    = (const float*)d_in[20];
  const float* ws1    = (const float*)d_in[21];
  const float* bs1    = (const float*)d_in[22];
  const float* aff1   = (const float*)d_in[23];
  const float* aff2   = (const float*)d_in[24];
  const float* wc     = (const float*)d_in[25];
  const float* bc     = (const float*)d_in[26];

  float* ws = (float*)d_ws;
  float* S0 = ws;
  float* S1 = S0 + 6291456;
  float* S2 = S1 + 3145728;
  float* S3 = S2 + 3145728;
  float* S4 = S3 + 3145728;
  float* S5 = S4 + 524288;
  float* adj_s  = S5 + 2097152;
  float* adj_ag = adj_s + 2097152;
  unsigned short* adjsbf  = (unsigned short*)(adj_ag + 2097152);
  unsigned short* adjagbf = adjsbf + 2097152;
  unsigned short* wT      = adjagbf + 2097152;
  unsigned short* wqT   = wT;
  unsigned short* wkT   = wT + 589824;
  unsigned short* wa0T  = wT + 1179648;
  unsigned short* ws0T  = wT + 1474560;
  unsigned short* wa1T  = wT + 1769472;
  unsigned short* ws1T  = wT + 1916928;
  unsigned short* aff1T = wT + 2064384;
  unsigned short* aff2T = wT + 2211840;
  float* tail   = (float*)(wT + 2359296);
  float* avgH   = tail;
  float* den_s  = avgH + 8192;
  float* den_ag = den_s + 8192;
  float* klp    = den_ag + 8192;

  float* x = S0;
  unsigned short* o_agbf = (unsigned short*)S0;
  unsigned short* o_sbf  = o_agbf + 3145728;
  unsigned short* gTag   = o_agbf + 6291456;
  unsigned short* gTs    = o_agbf + 9437184;
  unsigned short* xbf    = (unsigned short*)S1;
  unsigned short* qbf    = (unsigned short*)S2;
  unsigned short* tmpA   = (unsigned short*)S2;
  unsigned short* g_agbf = (unsigned short*)S2;
  unsigned short* g_sbf  = g_agbf + 3145728;
  unsigned short* kbf    = (unsigned short*)S3;
  unsigned short* tTag   = (unsigned short*)S3;
  unsigned short* tTs    = tTag + 3145728;
  unsigned short* u1bf   = (unsigned short*)S3;
  unsigned short* u2bf   = u1bf + 3145728;
  unsigned short* aspbf  = (unsigned short*)S4;
  unsigned short* wdT    = aspbf + 524288;
  unsigned short* wmT    = wdT + 49152;
  float* asps = S5;
  unsigned short* P1bf = (unsigned short*)S5;
  unsigned short* P2bf = P1bf + 2097152;
  float* dout = (float*)d_out;

  const long sAdjSh = (long)L_ * L_;
  const long sMemSh = (long)L_ * MEM_;

  // prep: all weight transposes + LN in one dispatch
  prep_kernel<<<600 + B_ * L_, 256, 0, stream>>>(
      seq, ln_g, ln_b, x, xbf, wq, wqT, wk, wkT, wa0, wa0T, ws0, ws0T,
      wa1, wa1T, ws1, ws1T, aff1, aff1T, aff2, aff2T, wd, wdT, wm, wmT);
  // paired q/k projections
  gemm_bb<128><<<dim3(6, 64, 2), 256, 0, stream>>>(
      xbf, wqT, nullptr, qbf, nullptr, 8192, 768, 768, 0, 0, 0, 0, bq, nullptr, 0,
      xbf, wkT, nullptr, kbf, nullptr, bk, nullptr, 1);
  // attention + asp projection (independent) in one dispatch
  attn_asp<<<1024, 256, 0, stream>>>(qbf, kbf, srcm, adj_s, adjsbf,
                                     xbf, wdT, amask, bd, aspbf);
  asp_wm_v2<<<B_ * H_, 256, 0, stream>>>(aspbf, wmT, tmpA);  // after attn (tmpA aliases qbf)
  asps_mean_v2<<<B_ * 16, 256, 0, stream>>>(tmpA, kbf, bm, asps);
  avgh_kernel<<<B_, 1024, 0, stream>>>(asps, avgH);
  adjag_kernel<<<B_ * L_ * L_ / 256, 256, 0, stream>>>(asps, avgH, amask, adjr,
                                                       adj_ag, adjagbf);
  kl_denom<<<B_ * L_, 256, 0, stream>>>(adj_s, adj_ag, klp, den_s, den_ag);
  kl_final<<<1, 256, 0, stream>>>(klp, dout);

  for (int li = 0; li < 2; ++li) {
    int Kd = li ? MEM_ : D_;
    const unsigned short* inag = li ? o_agbf : xbf;
    const unsigned short* ins  = li ? o_sbf : xbf;
    const unsigned short* wAT = li ? wa1T : wa0T;
    const float* bA = li ? ba1 : ba0;
    const unsigned short* wST = li ? ws1T : ws0T;
    const float* bS = li ? bs1 : bs0;
    // paired t-GEMMs -> transposed bf16 tT (64-row tiles: 768 blocks)
    gemm_bb<64><<<dim3(3, 128, 2), 256, 0, stream>>>(
        inag, wAT, nullptr, nullptr, tTag, 8192, MEM_, Kd, 0, 0, 0, sMemSh,
        nullptr, nullptr, 0,
        ins, wST, nullptr, nullptr, tTs, nullptr, nullptr, 1);
    // paired g-GEMMs (64-row tiles: 768 blocks)
    gemm_bb<64><<<dim3(3, 4, 64), 256, 0, stream>>>(
        adjagbf, tTag, nullptr, g_agbf, gTag, L_, MEM_, L_, sAdjSh, sMemSh, sMemSh,
        sMemSh, bA, den_ag, 1,
        adjsbf, tTs, nullptr, g_sbf, gTs, bS, den_s, 32);
    // paired u-GEMMs
    gemm_bb<64><<<dim3(3, 128, 2), 256, 0, stream>>>(
        g_agbf, aff1T, nullptr, u1bf, nullptr, 8192, MEM_, MEM_, 0, 0, 0, 0,
        nullptr, nullptr, 0,
        g_sbf, aff2T, nullptr, u2bf, nullptr, nullptr, nullptr, 1);
    // paired fused S+softmax
    gemm_sfmx<<<dim3(4, 64), 256, 0, stream>>>(u1bf, g_sbf, P1bf, u2bf, g_agbf, P2bf);
    // paired PV
    gemm_bb<64><<<dim3(3, 4, 64), 256, 0, stream>>>(
        P1bf, gTs, nullptr, o_agbf, nullptr, L_, MEM_, L_, sAdjSh, sMemSh, sMemSh, 0,
        nullptr, nullptr, 0,
        P2bf, gTag, nullptr, o_sbf, nullptr, nullptr, nullptr, 32);
  }

  final_kernel<<<B_, 256, 0, stream>>>(o_agbf, o_sbf, pooled, amask, wc, bc, dout);
}

// Round 12
// 429.091 us; speedup vs baseline: 1.4169x; 1.0084x over previous
//
#include <hip/hip_runtime.h>

#define B_ 32
#define L_ 256
#define D_ 768
#define H_ 12
#define DK_ 64
#define MEM_ 384

typedef __attribute__((ext_vector_type(8))) short bfrag8;    // 8 bf16 (4 VGPRs)
typedef __attribute__((ext_vector_type(8))) unsigned short us8;
typedef __attribute__((ext_vector_type(4))) float f32x4;

__device__ inline unsigned short f2bf(float f) {
  unsigned u = __float_as_uint(f);
  return (unsigned short)((u + 0x7fffu + ((u >> 16) & 1u)) >> 16);
}
__device__ inline float bf2f(unsigned short u) {
  return __uint_as_float(((unsigned)u) << 16);
}
__device__ inline float tanh_fast(float x) {
  x = fminf(fmaxf(x, -30.f), 30.f);
  float e = __expf(2.f * x);
  return (e - 1.f) * __builtin_amdgcn_rcpf(e + 1.f);
}
__device__ inline void gload_lds16(const unsigned short* g, unsigned short* l) {
  __builtin_amdgcn_global_load_lds(
      (__attribute__((address_space(1))) void*)(g),
      (__attribute__((address_space(3))) void*)(l), 16, 0, 0);
}

// ---------------- block reduce helpers ----------------
__device__ inline float waveRedSum(float v) {
#pragma unroll
  for (int o = 32; o; o >>= 1) v += __shfl_xor(v, o, 64);
  return v;
}
__device__ inline float waveRedMax(float v) {
#pragma unroll
  for (int o = 32; o; o >>= 1) v = fmaxf(v, __shfl_xor(v, o, 64));
  return v;
}
__device__ inline float blkRedSum(float v, float* red) {
  v = waveRedSum(v);
  int w = threadIdx.x >> 6;
  __syncthreads();
  if ((threadIdx.x & 63) == 0) red[w] = v;
  __syncthreads();
  return red[0] + red[1] + red[2] + red[3];
}
__device__ inline float blkRedMax(float v, float* red) {
  v = waveRedMax(v);
  int w = threadIdx.x >> 6;
  __syncthreads();
  if ((threadIdx.x & 63) == 0) red[w] = v;
  __syncthreads();
  return fmaxf(fmaxf(red[0], red[1]), fmaxf(red[2], red[3]));
}

// ---------------- prep: all weight transposes (blocks 0..599) + LayerNorm (600+) -----
__global__ __launch_bounds__(256) void prep_kernel(
    const float* __restrict__ seq, const float* __restrict__ lng,
    const float* __restrict__ lnb, float* __restrict__ xout,
    unsigned short* __restrict__ xbf,
    const float* __restrict__ wq, unsigned short* __restrict__ wqT,
    const float* __restrict__ wk, unsigned short* __restrict__ wkT,
    const float* __restrict__ wa0, unsigned short* __restrict__ wa0T,
    const float* __restrict__ ws0, unsigned short* __restrict__ ws0T,
    const float* __restrict__ wa1, unsigned short* __restrict__ wa1T,
    const float* __restrict__ ws1, unsigned short* __restrict__ ws1T,
    const float* __restrict__ aff1, unsigned short* __restrict__ aff1T,
    const float* __restrict__ aff2, unsigned short* __restrict__ aff2T,
    const float* __restrict__ wd, unsigned short* __restrict__ wdT,
    const float* __restrict__ wm, unsigned short* __restrict__ wmT) {
  int bid = blockIdx.x;
  if (bid >= 600) {  // ---- LayerNorm row ----
    long row = bid - 600;
    const float* p = seq + row * D_;
    float v[3];
#pragma unroll
    for (int i = 0; i < 3; ++i) v[i] = p[threadIdx.x + i * 256];
    __shared__ float red[4];
    float s = v[0] + v[1] + v[2];
    s = blkRedSum(s, red);
    float mu = s * (1.f / D_);
    float ss = 0.f;
#pragma unroll
    for (int i = 0; i < 3; ++i) { float d = v[i] - mu; ss += d * d; }
    ss = blkRedSum(ss, red);
    float sd = sqrtf(ss * (1.f / (D_ - 1)));
    float inv = 1.f / (sd + 1e-6f);
#pragma unroll
    for (int i = 0; i < 3; ++i) {
      int c = threadIdx.x + i * 256;
      float o = lng[c] * (v[i] - mu) * inv + lnb[c];
      xout[row * D_ + c] = o;
      xbf[row * D_ + c] = f2bf(o);
    }
    return;
  }
  const float* src; unsigned short* dst; int Rr, Cc, tIdx;
  if (bid < 144)      { src = wq;   dst = wqT;   Rr = 768; Cc = 768; tIdx = bid; }
  else if (bid < 288) { src = wk;   dst = wkT;   Rr = 768; Cc = 768; tIdx = bid - 144; }
  else if (bid < 360) { src = wa0;  dst = wa0T;  Rr = 768; Cc = 384; tIdx = bid - 288; }
  else if (bid < 432) { src = ws0;  dst = ws0T;  Rr = 768; Cc = 384; tIdx = bid - 360; }
  else if (bid < 468) { src = wa1;  dst = wa1T;  Rr = 384; Cc = 384; tIdx = bid - 432; }
  else if (bid < 504) { src = ws1;  dst = ws1T;  Rr = 384; Cc = 384; tIdx = bid - 468; }
  else if (bid < 540) { src = aff1; dst = aff1T; Rr = 384; Cc = 384; tIdx = bid - 504; }
  else if (bid < 576) { src = aff2; dst = aff2T; Rr = 384; Cc = 384; tIdx = bid - 540; }
  else if (bid < 588) { src = wd;   dst = wdT;   Rr = 768; Cc = 64;  tIdx = bid - 576; }
  else { int h = bid - 588; src = wm + h * 4096; dst = wmT + h * 4096; Rr = 64; Cc = 64; tIdx = 0; }
  __shared__ float tile[64][65];
  int nx = Cc >> 6;
  int c0 = (tIdx % nx) * 64, r0 = (tIdx / nx) * 64;
  int tx = threadIdx.x & 63, ty = threadIdx.x >> 6;
#pragma unroll
  for (int i = 0; i < 16; ++i)
    tile[ty + i * 4][tx] = src[(long)(r0 + ty + i * 4) * Cc + c0 + tx];
  __syncthreads();
#pragma unroll
  for (int i = 0; i < 16; ++i)
    dst[(long)(c0 + ty + i * 4) * Rr + r0 + tx] = f2bf(tile[tx][ty + i * 4]);
}

// ---------------- all-bf16 MFMA GEMM, DMA staging, BK=32, MR x 128 tile --------------
template <int MR>
__global__ __launch_bounds__(256) void gemm_bb(
    const unsigned short* __restrict__ A, const unsigned short* __restrict__ Bt,
    float* __restrict__ C, unsigned short* __restrict__ Cbf,
    unsigned short* __restrict__ CT,
    int M, int N, int K, long sA, long sB, long sC, long sCT,
    const float* __restrict__ bias, const float* __restrict__ rowDiv, int relu,
    const unsigned short* __restrict__ A2, const unsigned short* __restrict__ Bt2,
    float* __restrict__ C2, unsigned short* __restrict__ Cbf2,
    unsigned short* __restrict__ CT2,
    const float* __restrict__ bias2, const float* __restrict__ rowDiv2, int zsplit) {
  constexpr int MFRAG = MR / 32;
  constexpr int RW = MR / 2;
  constexpr int ASH = MR * 32;
  constexpr int TSH = 64 * (MR + 8);
  constexpr int SMN = (ASH + 4096 > TSH) ? (ASH + 4096) : TSH;
  __shared__ alignas(16) unsigned short smem[SMN];
  unsigned short* AsS = smem;
  unsigned short* BsS = smem + ASH;
  const int tid = threadIdx.x;
  const int bn = blockIdx.x, bm = blockIdx.y;
  int bz = blockIdx.z;
  const unsigned short* Ap = A; const unsigned short* Btp = Bt;
  float* Cp = C; unsigned short* Cbp = Cbf; unsigned short* CTp = CT;
  const float* biasp = bias; const float* rowDivp = rowDiv;
  if (zsplit > 0 && bz >= zsplit) {
    bz -= zsplit;
    Ap = A2; Btp = Bt2; Cp = C2; Cbp = Cbf2; CTp = CT2; biasp = bias2; rowDivp = rowDiv2;
  }
  Ap += (long)bz * sA; Btp += (long)bz * sB;
  if (Cp) Cp += (long)bz * sC;
  if (Cbp) Cbp += (long)bz * sC;
  if (CTp) CTp += (long)bz * sCT;

  f32x4 acc[MFRAG][4] = {};
  const int l = tid & 63, w = tid >> 6;
  const int wr = w >> 1, wc = w & 1;
  const int lr = l & 15, sg = l >> 4;

  const int rc = l >> 2;
  const int sslot = (l & 3) ^ ((rc >> 1) & 3);
  const unsigned short* gA0 = Ap + (long)(bm * MR + w * 16 + rc) * K + sslot * 8;
  const unsigned short* gA1 = (MR == 128)
      ? Ap + (long)(bm * MR + (w + 4) * 16 + rc) * K + sslot * 8 : nullptr;
  const unsigned short* gB0 = Btp + (long)(bn * 128 + w * 16 + rc) * K + sslot * 8;
  const unsigned short* gB1 = Btp + (long)(bn * 128 + (w + 4) * 16 + rc) * K + sslot * 8;
  unsigned short* lA0 = AsS + w * 512;
  unsigned short* lA1 = AsS + (w + 4) * 512;
  unsigned short* lB0 = BsS + w * 512;
  unsigned short* lB1 = BsS + (w + 4) * 512;

  const int off = (sg ^ ((lr >> 1) & 3)) * 8;
  const unsigned short* arp[MFRAG];
  const unsigned short* brp[4];
#pragma unroll
  for (int m = 0; m < MFRAG; ++m)
    arp[m] = AsS + (wr * RW + m * 16 + lr) * 32 + off;
#pragma unroll
  for (int n = 0; n < 4; ++n)
    brp[n] = BsS + (wc * 64 + n * 16 + lr) * 32 + off;

  for (int k0 = 0; k0 < K; k0 += 32) {
    gload_lds16(gA0 + k0, lA0);
    if (MR == 128) gload_lds16(gA1 + k0, lA1);
    gload_lds16(gB0 + k0, lB0);
    gload_lds16(gB1 + k0, lB1);
    __syncthreads();
    bfrag8 af[MFRAG], bf[4];
#pragma unroll
    for (int m = 0; m < MFRAG; ++m) af[m] = *(const bfrag8*)(arp[m] + 0);
#pragma unroll
    for (int n = 0; n < 4; ++n) bf[n] = *(const bfrag8*)(brp[n] + 0);
#pragma unroll
    for (int m = 0; m < MFRAG; ++m)
#pragma unroll
      for (int n = 0; n < 4; ++n)
        acc[m][n] = __builtin_amdgcn_mfma_f32_16x16x32_bf16(af[m], bf[n], acc[m][n], 0, 0, 0);
    __syncthreads();
  }

  if (Cp || Cbp) {
#pragma unroll
    for (int m = 0; m < MFRAG; ++m) {
#pragma unroll
      for (int r = 0; r < 4; ++r) {
        int row = bm * MR + wr * RW + m * 16 + (l >> 4) * 4 + r;
        float rd = rowDivp ? 1.f / rowDivp[(long)bz * M + row] : 1.f;
#pragma unroll
        for (int n = 0; n < 4; ++n) {
          int col = bn * 128 + wc * 64 + n * 16 + lr;
          float v = acc[m][n][r];
          if (biasp) v += biasp[col];
          v *= rd;
          if (relu) v = fmaxf(v, 0.f);
          if (Cp) Cp[(long)row * N + col] = v;
          if (Cbp) Cbp[(long)row * N + col] = f2bf(v);
        }
      }
    }
  }
  if (CT) {
    auto Ts = (unsigned short(*)[MR + 8])smem;
#pragma unroll
    for (int ch = 0; ch < 2; ++ch) {
      __syncthreads();
      if (wc == ch) {
#pragma unroll
        for (int m = 0; m < MFRAG; ++m) {
#pragma unroll
          for (int r = 0; r < 4; ++r) {
            int rowl = wr * RW + m * 16 + (l >> 4) * 4 + r;
            float rd = rowDivp ? 1.f / rowDivp[(long)bz * M + bm * MR + rowl] : 1.f;
#pragma unroll
            for (int n = 0; n < 4; ++n) {
              int col = bn * 128 + wc * 64 + n * 16 + lr;
              float v = acc[m][n][r];
              if (biasp) v += biasp[col];
              v *= rd;
              if (relu) v = fmaxf(v, 0.f);
              Ts[n * 16 + lr][rowl] = f2bf(v);
            }
          }
        }
      }
      __syncthreads();
      int trow = tid >> 2, tc = (tid & 3) * (MR / 4);
      int colg = bn * 128 + ch * 64 + trow;
      int rowg = bm * MR + tc;
      unsigned short* dp = CTp + (long)(rowg >> 8) * sCT + (long)colg * 256 + (rowg & 255);
#pragma unroll
      for (int j = 0; j < MR / 32; ++j)
        *(us8*)(dp + j * 8) = *(const us8*)&Ts[trow][tc + j * 8];
    }
  }
}

// ---------------- fused attention (0..511, register-prefetched k) + asp (512..1023) ---
__global__ __launch_bounds__(256) void attn_asp(
    const unsigned short* __restrict__ qbf, const unsigned short* __restrict__ kbf,
    const float* __restrict__ srcm, float* __restrict__ adj_s,
    unsigned short* __restrict__ adjsbf,
    const unsigned short* __restrict__ xbf, const unsigned short* __restrict__ wdT,
    const float* __restrict__ amask, const float* __restrict__ bd,
    unsigned short* __restrict__ aspbf) {
  int t = threadIdx.x;
  int w = t >> 6, l = t & 63;
  int lr = l & 15, kg = (l >> 4) * 8;
  if (blockIdx.x >= 512) {  // ---- asp projection ----
    int l0 = (blockIdx.x - 512) << 4;
    const unsigned short* ap = xbf + (long)(l0 + lr) * D_ + kg;
    const unsigned short* bp = wdT + (long)(w * 16 + lr) * D_ + kg;
    f32x4 acc = {};
#pragma unroll
    for (int k0 = 0; k0 < D_; k0 += 32) {
      bfrag8 af = *(const bfrag8*)(ap + k0);
      bfrag8 bf = *(const bfrag8*)(bp + k0);
      acc = __builtin_amdgcn_mfma_f32_16x16x32_bf16(af, bf, acc, 0, 0, 0);
    }
    int col = w * 16 + lr;
#pragma unroll
    for (int r = 0; r < 4; ++r) {
      int row = l0 + (l >> 4) * 4 + r;
      float v = acc[r] * amask[row] + bd[col];
      aspbf[(long)row * DK_ + col] = f2bf(v);
    }
    return;
  }
  // ---- attention: head-pairs; ALL k frags register-prefetched before MFMAs ----
  int blk = blockIdx.x;
  int b = blk >> 4, l0 = (blk & 15) << 4;
  int rbase = (l >> 4) * 4;
  __shared__ float red[6][2][16][8];
  float acc[4][4] = {};
  float cmv[4];
#pragma unroll
  for (int ct = 0; ct < 4; ++ct) cmv[ct] = srcm[b * L_ + w * 64 + ct * 16 + lr];

#pragma unroll 1
  for (int hp = 0; hp < 6; ++hp) {
    const unsigned short* ap = qbf + ((long)b * L_ + l0 + lr) * D_ + hp * 128 + kg;
    bfrag8 a00 = *(const bfrag8*)ap;
    bfrag8 a01 = *(const bfrag8*)(ap + 32);
    bfrag8 a10 = *(const bfrag8*)(ap + 64);
    bfrag8 a11 = *(const bfrag8*)(ap + 96);
    // prefetch entire k tile for this head pair (16 loads in flight)
    bfrag8 kv[4][4];
#pragma unroll
    for (int ct = 0; ct < 4; ++ct) {
      const unsigned short* bp =
          kbf + ((long)b * L_ + w * 64 + ct * 16 + lr) * D_ + hp * 128 + kg;
      kv[ct][0] = *(const bfrag8*)bp;
      kv[ct][1] = *(const bfrag8*)(bp + 32);
      kv[ct][2] = *(const bfrag8*)(bp + 64);
      kv[ct][3] = *(const bfrag8*)(bp + 96);
    }
    float sv0[4][4], sv1[4][4];
#pragma unroll
    for (int ct = 0; ct < 4; ++ct) {
      f32x4 c0 = {}, c1 = {};
      c0 = __builtin_amdgcn_mfma_f32_16x16x32_bf16(a00, kv[ct][0], c0, 0, 0, 0);
      c0 = __builtin_amdgcn_mfma_f32_16x16x32_bf16(a01, kv[ct][1], c0, 0, 0, 0);
      c1 = __builtin_amdgcn_mfma_f32_16x16x32_bf16(a10, kv[ct][2], c1, 0, 0, 0);
      c1 = __builtin_amdgcn_mfma_f32_16x16x32_bf16(a11, kv[ct][3], c1, 0, 0, 0);
      bool msk = (cmv[ct] == 0.f);
#pragma unroll
      for (int r = 0; r < 4; ++r) {
        sv0[ct][r] = msk ? -1e9f : c0[r] * 0.125f;
        sv1[ct][r] = msk ? -1e9f : c1[r] * 0.125f;
      }
    }
    float mx0a[4], mx1a[4];
#pragma unroll
    for (int r = 0; r < 4; ++r) {
      float m0 = fmaxf(fmaxf(sv0[0][r], sv0[1][r]), fmaxf(sv0[2][r], sv0[3][r]));
      float m1 = fmaxf(fmaxf(sv1[0][r], sv1[1][r]), fmaxf(sv1[2][r], sv1[3][r]));
#pragma unroll
      for (int o = 1; o < 16; o <<= 1) {
        m0 = fmaxf(m0, __shfl_xor(m0, o, 64));
        m1 = fmaxf(m1, __shfl_xor(m1, o, 64));
      }
      mx0a[r] = m0; mx1a[r] = m1;
      float s0 = 0.f, s1 = 0.f;
#pragma unroll
      for (int ct = 0; ct < 4; ++ct) {
        float e0 = __expf(sv0[ct][r] - m0);
        float e1 = __expf(sv1[ct][r] - m1);
        sv0[ct][r] = e0; sv1[ct][r] = e1;
        s0 += e0; s1 += e1;
      }
#pragma unroll
      for (int o = 1; o < 16; o <<= 1) {
        s0 += __shfl_xor(s0, o, 64);
        s1 += __shfl_xor(s1, o, 64);
      }
      if (lr == 0) {
        red[hp][0][rbase + r][w] = m0;
        red[hp][0][rbase + r][4 + w] = s0;
        red[hp][1][rbase + r][w] = m1;
        red[hp][1][rbase + r][4 + w] = s1;
      }
    }
    __syncthreads();
#pragma unroll
    for (int r = 0; r < 4; ++r) {
      f32x4 m4 = *(const f32x4*)&red[hp][0][rbase + r][0];
      f32x4 s4 = *(const f32x4*)&red[hp][0][rbase + r][4];
      float mt = fmaxf(fmaxf(m4[0], m4[1]), fmaxf(m4[2], m4[3]));
      float tot = s4[0] * __expf(m4[0] - mt) + s4[1] * __expf(m4[1] - mt) +
                  s4[2] * __expf(m4[2] - mt) + s4[3] * __expf(m4[3] - mt);
      float sc0 = __expf(mx0a[r] - mt) * __builtin_amdgcn_rcpf(tot);
      f32x4 n4 = *(const f32x4*)&red[hp][1][rbase + r][0];
      f32x4 t4 = *(const f32x4*)&red[hp][1][rbase + r][4];
      float nt = fmaxf(fmaxf(n4[0], n4[1]), fmaxf(n4[2], n4[3]));
      float tt = t4[0] * __expf(n4[0] - nt) + t4[1] * __expf(n4[1] - nt) +
                 t4[2] * __expf(n4[2] - nt) + t4[3] * __expf(n4[3] - nt);
      float sc1 = __expf(mx1a[r] - nt) * __builtin_amdgcn_rcpf(tt);
#pragma unroll
      for (int ct = 0; ct < 4; ++ct)
        acc[ct][r] += sv0[ct][r] * sc0 + sv1[ct][r] * sc1;
    }
  }

#pragma unroll
  for (int r = 0; r < 4; ++r) {
    int row = l0 + rbase + r;
    float rm = srcm[b * L_ + row];
#pragma unroll
    for (int ct = 0; ct < 4; ++ct) {
      int col = w * 64 + ct * 16 + lr;
      float v = acc[ct][r] * (1.f / H_);
      if (col == row) v = 1.f;
      v *= rm;
      long idx = ((long)b * L_ + row) * L_ + col;
      adj_s[idx] = v;
      adjsbf[idx] = f2bf(v);
    }
  }
}

// ---------------- tmpA[b,h] = aspbf[b] @ Wm[h], MFMA, no LDS ----------------
__global__ __launch_bounds__(256) void asp_wm_v2(const unsigned short* __restrict__ aspbf,
                                                 const unsigned short* __restrict__ wmT,
                                                 unsigned short* __restrict__ tmpA) {
  int bh = blockIdx.x;
  int b = bh / H_, h = bh % H_;
  int t = threadIdx.x;
  int w = t >> 6, l = t & 63;
  int lr = l & 15, kg = (l >> 4) * 8;
  const unsigned short* wp = wmT + h * 4096;
  f32x4 acc[4][4] = {};
#pragma unroll
  for (int ks = 0; ks < 2; ++ks) {
    int k0 = ks * 32;
    bfrag8 af[4], bf[4];
#pragma unroll
    for (int m = 0; m < 4; ++m)
      af[m] = *(const bfrag8*)(aspbf + (long)(b * L_ + w * 64 + m * 16 + lr) * DK_ + k0 + kg);
#pragma unroll
    for (int n = 0; n < 4; ++n)
      bf[n] = *(const bfrag8*)(wp + (n * 16 + lr) * 64 + k0 + kg);
#pragma unroll
    for (int m = 0; m < 4; ++m)
#pragma unroll
      for (int n = 0; n < 4; ++n)
        acc[m][n] = __builtin_amdgcn_mfma_f32_16x16x32_bf16(af[m], bf[n], acc[m][n], 0, 0, 0);
  }
#pragma unroll
  for (int m = 0; m < 4; ++m)
#pragma unroll
    for (int n = 0; n < 4; ++n)
#pragma unroll
      for (int r = 0; r < 4; ++r) {
        int row = w * 64 + m * 16 + (l >> 4) * 4 + r;
        int col = n * 16 + lr;
        tmpA[(((long)b * H_ + h) * L_ + row) * DK_ + col] = f2bf(acc[m][n][r]);
      }
}

// ---------------- fused S-GEMM + row softmax (LDS-staged bf16) ----------------
__global__ __launch_bounds__(256) void gemm_sfmx(
    const unsigned short* __restrict__ u1, const unsigned short* __restrict__ g1,
    unsigned short* __restrict__ P1,
    const unsigned short* __restrict__ u2, const unsigned short* __restrict__ g2,
    unsigned short* __restrict__ P2) {
  int bm = blockIdx.x;
  int bz = blockIdx.y;
  const unsigned short* Ap; const unsigned short* Bp; unsigned short* Pp;
  if (bz < 32) {
    Ap = u1 + (long)bz * L_ * MEM_; Bp = g1 + (long)bz * L_ * MEM_;
    Pp = P1 + (long)bz * L_ * L_;
  } else {
    int z = bz - 32;
    Ap = u2 + (long)z * L_ * MEM_; Bp = g2 + (long)z * L_ * MEM_;
    Pp = P2 + (long)z * L_ * L_;
  }
  __shared__ unsigned short As[64][40];
  __shared__ unsigned short Bs[256][40];
  __shared__ float redm[2][64];
  __shared__ float reds[2][64];
  const int t = threadIdx.x;
  const int l = t & 63, w = t >> 6;
  const int wr = w >> 1, wc = w & 1;
  const int lr = l & 15, kg = (l >> 4) * 8;
  f32x4 acc[2][8] = {};
  const int arA = t >> 2, akA = (t & 3) * 8;

  for (int k0 = 0; k0 < MEM_; k0 += 32) {
    *(us8*)&As[arA][akA] = *(const us8*)(Ap + (long)(bm * 64 + arA) * MEM_ + k0 + akA);
#pragma unroll
    for (int j = 0; j < 4; ++j)
      *(us8*)&Bs[t][j * 8] = *(const us8*)(Bp + (long)t * MEM_ + k0 + j * 8);
    __syncthreads();
    bfrag8 af[2], bf[8];
#pragma unroll
    for (int m = 0; m < 2; ++m) af[m] = *(const bfrag8*)&As[wr * 32 + m * 16 + lr][kg];
#pragma unroll
    for (int n = 0; n < 8; ++n) bf[n] = *(const bfrag8*)&Bs[wc * 128 + n * 16 + lr][kg];
#pragma unroll
    for (int m = 0; m < 2; ++m)
#pragma unroll
      for (int n = 0; n < 8; ++n)
        acc[m][n] = __builtin_amdgcn_mfma_f32_16x16x32_bf16(af[m], bf[n], acc[m][n], 0, 0, 0);
    __syncthreads();
  }

#pragma unroll
  for (int m = 0; m < 2; ++m) {
#pragma unroll
    for (int r = 0; r < 4; ++r) {
      int lrow = wr * 32 + m * 16 + (l >> 4) * 4 + r;
      float mx = -1e30f;
#pragma unroll
      for (int n = 0; n < 8; ++n) mx = fmaxf(mx, acc[m][n][r]);
#pragma unroll
      for (int o = 1; o < 16; o <<= 1) mx = fmaxf(mx, __shfl_xor(mx, o, 64));
      if (lr == 0) redm[wc][lrow] = mx;
    }
  }
  __syncthreads();
#pragma unroll
  for (int m = 0; m < 2; ++m) {
#pragma unroll
    for (int r = 0; r < 4; ++r) {
      int lrow = wr * 32 + m * 16 + (l >> 4) * 4 + r;
      float mx = fmaxf(redm[0][lrow], redm[1][lrow]);
      float s = 0.f;
#pragma unroll
      for (int n = 0; n < 8; ++n) {
        float e = __expf(acc[m][n][r] - mx);
        acc[m][n][r] = e;
        s += e;
      }
#pragma unroll
      for (int o = 1; o < 16; o <<= 1) s += __shfl_xor(s, o, 64);
      if (lr == 0) reds[wc][lrow] = s;
    }
  }
  __syncthreads();
#pragma unroll
  for (int m = 0; m < 2; ++m) {
#pragma unroll
    for (int r = 0; r < 4; ++r) {
      int lrow = wr * 32 + m * 16 + (l >> 4) * 4 + r;
      float inv = 1.f / (reds[0][lrow] + reds[1][lrow]);
      int row = bm * 64 + lrow;
#pragma unroll
      for (int n = 0; n < 8; ++n) {
        int col = wc * 128 + n * 16 + lr;
        Pp[(long)row * L_ + col] = f2bf(acc[m][n][r] * inv);
      }
    }
  }
}

// ---------------- asps_mean via MFMA ----------------
__global__ __launch_bounds__(256) void asps_mean_v2(
    const unsigned short* __restrict__ tmpA,
    const unsigned short* __restrict__ kbf,
    const float* __restrict__ bias_m,
    float* __restrict__ asps_mean) {
  int blk = blockIdx.x;
  int b = blk >> 4, l0 = (blk & 15) << 4;
  int t = threadIdx.x;
  int w = t >> 6, l = t & 63;
  int lr = l & 15, kg = (l >> 4) * 8;
  float bm = bias_m[0];
  float accg[4][4] = {};
  for (int h = 0; h < H_; ++h) {
    const unsigned short* ap = tmpA + (((long)b * H_ + h) * L_ + l0 + lr) * 64 + kg;
    bfrag8 af0 = *(const bfrag8*)ap;
    bfrag8 af1 = *(const bfrag8*)(ap + 32);
#pragma unroll
    for (int ct = 0; ct < 4; ++ct) {
      const unsigned short* bp =
          kbf + ((long)b * L_ + w * 64 + ct * 16 + lr) * D_ + h * 64 + kg;
      bfrag8 bf0 = *(const bfrag8*)bp;
      bfrag8 bf1 = *(const bfrag8*)(bp + 32);
      f32x4 accl = {};
      accl = __builtin_amdgcn_mfma_f32_16x16x32_bf16(af0, bf0, accl, 0, 0, 0);
      accl = __builtin_amdgcn_mfma_f32_16x16x32_bf16(af1, bf1, accl, 0, 0, 0);
#pragma unroll
      for (int r = 0; r < 4; ++r) accg[ct][r] += tanh_fast(accl[r] + bm);
    }
  }
#pragma unroll
  for (int ct = 0; ct < 4; ++ct) {
    int col = w * 64 + ct * 16 + lr;
#pragma unroll
    for (int r = 0; r < 4; ++r) {
      int row = l0 + (l >> 4) * 4 + r;
      asps_mean[((long)b * L_ + row) * L_ + col] = accg[ct][r] * (1.f / H_);
    }
  }
}

// ---------------- avgH ----------------
__global__ __launch_bounds__(1024) void avgh_kernel(const float* __restrict__ asps_mean,
                                                    float* __restrict__ avgH) {
  int b = blockIdx.x;
  int m = threadIdx.x & 255, q = threadIdx.x >> 8;
  __shared__ float part[4][256];
  float s = 0.f;
  for (int l = q * 64; l < q * 64 + 64; ++l)
    s += asps_mean[((long)b * L_ + l) * L_ + m];
  part[q][m] = s;
  __syncthreads();
  if (q == 0)
    avgH[b * L_ + m] = (part[0][m] + part[1][m] + part[2][m] + part[3][m]) * (1.f / L_);
}

// ---------------- fused adj_ag + KL partials + row denominators (block = one row) -----
__global__ __launch_bounds__(256) void adjag_kl(const float* __restrict__ asps_mean,
                                                const float* __restrict__ avgH,
                                                const float* __restrict__ amask,
                                                const float* __restrict__ adjr,
                                                const float* __restrict__ adj_s,
                                                float* __restrict__ adj_ag,
                                                unsigned short* __restrict__ adjagbf,
                                                float* __restrict__ klpart,
                                                float* __restrict__ den_s,
                                                float* __restrict__ den_ag) {
  long row = blockIdx.x;               // b*L + l
  int m = threadIdx.x;
  int l = (int)(row & 255);
  int b = (int)(row >> 8);
  long idx = row * L_ + m;
  bool rowa = amask[b * L_ + l] > 0.f;
  bool cola = amask[b * L_ + m] > 0.f;
  float asa;
  if (rowa && cola) asa = (l >= m) ? avgH[b * L_ + m] : avgH[b * L_ + l];
  else if (rowa)    asa = avgH[b * L_ + m];
  else if (cola)    asa = avgH[b * L_ + l];
  else              asa = asps_mean[idx];
  float r = (asa > 0.25f) ? 1.f : expf(adjr[idx]);
  float a = r * asa;
  adj_ag[idx] = a;
  adjagbf[idx] = f2bf(a);

  __shared__ float red[4];
  float s = adj_s[idx];
  float sum_s = blkRedSum(s, red);
  float sum_a = blkRedSum(a, red);
  float mx_s = blkRedMax(s, red);
  float mx_a = blkRedMax(a, red);
  float es = expf(s - mx_s), ea = expf(a - mx_a);
  float ses = blkRedSum(es, red);
  float sea = blkRedSum(ea, red);
  float logq = (s - mx_s) - logf(ses);
  float logp = (a - mx_a) - logf(sea);
  float term = (es / ses) * (logq - logp);
  float kp = blkRedSum(term, red);
  if (m == 0) {
    klpart[row] = kp;
    den_s[row] = sum_s + 1.f;
    den_ag[row] = sum_a + 1.f;
  }
}

// ---------------- classifier head (+ KL finish at blockIdx == B_) ----------------
__global__ __launch_bounds__(256) void final_kernel(const unsigned short* __restrict__ o_ag,
                                                    const unsigned short* __restrict__ o_s,
                                                    const float* __restrict__ pooled,
                                                    const float* __restrict__ amask,
                                                    const float* __restrict__ wc,
                                                    const float* __restrict__ bc,
                                                    const float* __restrict__ klpart,
                                                    float* __restrict__ dout) {
  int b = blockIdx.x, t = threadIdx.x;
  __shared__ float red[4];
  if (b == B_) {  // KL finish
    float s = 0.f;
    for (int i = t; i < B_ * L_; i += 256) s += klpart[i];
    s = blkRedSum(s, red);
    if (t == 0) dout[96] = expf(-s * 0.1f);
    return;
  }
  __shared__ float cS[1536];
  __shared__ float maskS[256];
  maskS[t] = amask[b * L_ + t];
  float wn = blkRedSum(maskS[t], red);
  for (int e = t; e < MEM_; e += 256) {
    float s1 = 0.f, s2 = 0.f;
    for (int l = 0; l < L_; ++l) {
      float mk = maskS[l];
      if (mk != 0.f) {
        s1 += mk * bf2f(o_ag[((long)b * L_ + l) * MEM_ + e]);
        s2 += mk * bf2f(o_s[((long)b * L_ + l) * MEM_ + e]);
      }
    }
    cS[e] = s1 / wn;
    cS[MEM_ + e] = s2 / wn;
  }
  for (int j = t; j < D_; j += 256) cS[2 * MEM_ + j] = pooled[b * D_ + j];
  __syncthreads();
  float p0 = 0.f, p1 = 0.f, p2 = 0.f;
  for (int j = t; j < 1536; j += 256) {
    float v = cS[j];
    p0 += v * wc[j * 3 + 0];
    p1 += v * wc[j * 3 + 1];
    p2 += v * wc[j * 3 + 2];
  }
  p0 = blkRedSum(p0, red);
  p1 = blkRedSum(p1, red);
  p2 = blkRedSum(p2, red);
  if (t == 0) {
    dout[b * 3 + 0] = p0 + bc[0];
    dout[b * 3 + 1] = p1 + bc[1];
    dout[b * 3 + 2] = p2 + bc[2];
  }
}

extern "C" void kernel_launch(void* const* d_in, const int* in_sizes, int n_in,
                              void* d_out, int out_size, void* d_ws, size_t ws_size,
                              hipStream_t stream) {
  const float* seq    = (const float*)d_in[0];
  const float* pooled = (const float*)d_in[1];
  const float* adjr   = (const float*)d_in[2];
  const float* srcm   = (const float*)d_in[3];
  const float* amask  = (const float*)d_in[4];
  const float* ln_g   = (const float*)d_in[5];
  const float* ln_b   = (const float*)d_in[6];
  const float* wq     = (const float*)d_in[7];
  const float* bq     = (const float*)d_in[8];
  const float* wk     = (const float*)d_in[9];
  const float* bk     = (const float*)d_in[10];
  const float* wd     = (const float*)d_in[11];
  const float* bd     = (const float*)d_in[12];
  const float* wm     = (const float*)d_in[13];
  const float* bm     = (const float*)d_in[14];
  const float* wa0    = (const float*)d_in[15];
  const float* ba0    = (const float*)d_in[16];
  const float* wa1    = (const float*)d_in[17];
  const float* ba1    = (const float*)d_in[18];
  const float* ws0    = (const float*)d_in[19];
  const float* bs0    = (const float*)d_in[20];
  const float* ws1    = (const float*)d_in[21];
  const float* bs1    = (const float*)d_in[22];
  const float* aff1   = (const float*)d_in[23];
  const float* aff2   = (const float*)d_in[24];
  const float* wc     = (const float*)d_in[25];
  const float* bc     = (const float*)d_in[26];

  float* ws = (float*)d_ws;
  float* S0 = ws;
  float* S1 = S0 + 6291456;
  float* S2 = S1 + 3145728;
  float* S3 = S2 + 3145728;
  float* S4 = S3 + 3145728;
  float* S5 = S4 + 524288;
  float* adj_s  = S5 + 2097152;
  float* adj_ag = adj_s + 2097152;
  unsigned short* adjsbf  = (unsigned short*)(adj_ag + 2097152);
  unsigned short* adjagbf = adjsbf + 2097152;
  unsigned short* wT      = adjagbf + 2097152;
  unsigned short* wqT   = wT;
  unsigned short* wkT   = wT + 589824;
  unsigned short* wa0T  = wT + 1179648;
  unsigned short* ws0T  = wT + 1474560;
  unsigned short* wa1T  = wT + 1769472;
  unsigned short* ws1T  = wT + 1916928;
  unsigned short* aff1T = wT + 2064384;
  unsigned short* aff2T = wT + 2211840;
  float* tail   = (float*)(wT + 2359296);
  float* avgH   = tail;
  float* den_s  = avgH + 8192;
  float* den_ag = den_s + 8192;
  float* klp    = den_ag + 8192;

  float* x = S0;
  unsigned short* o_agbf = (unsigned short*)S0;
  unsigned short* o_sbf  = o_agbf + 3145728;
  unsigned short* gTag   = o_agbf + 6291456;
  unsigned short* gTs    = o_agbf + 9437184;
  unsigned short* xbf    = (unsigned short*)S1;
  unsigned short* qbf    = (unsigned short*)S2;
  unsigned short* tmpA   = (unsigned short*)S2;
  unsigned short* g_agbf = (unsigned short*)S2;
  unsigned short* g_sbf  = g_agbf + 3145728;
  unsigned short* kbf    = (unsigned short*)S3;
  unsigned short* tTag   = (unsigned short*)S3;
  unsigned short* tTs    = tTag + 3145728;
  unsigned short* u1bf   = (unsigned short*)S3;
  unsigned short* u2bf   = u1bf + 3145728;
  unsigned short* aspbf  = (unsigned short*)S4;
  unsigned short* wdT    = aspbf + 524288;
  unsigned short* wmT    = wdT + 49152;
  float* asps = S5;
  unsigned short* P1bf = (unsigned short*)S5;
  unsigned short* P2bf = P1bf + 2097152;
  float* dout = (float*)d_out;

  const long sAdjSh = (long)L_ * L_;
  const long sMemSh = (long)L_ * MEM_;

  prep_kernel<<<600 + B_ * L_, 256, 0, stream>>>(
      seq, ln_g, ln_b, x, xbf, wq, wqT, wk, wkT, wa0, wa0T, ws0, ws0T,
      wa1, wa1T, ws1, ws1T, aff1, aff1T, aff2, aff2T, wd, wdT, wm, wmT);
  // paired q/k projections (MR=64 for TLP)
  gemm_bb<64><<<dim3(6, 128, 2), 256, 0, stream>>>(
      xbf, wqT, nullptr, qbf, nullptr, 8192, 768, 768, 0, 0, 0, 0, bq, nullptr, 0,
      xbf, wkT, nullptr, kbf, nullptr, bk, nullptr, 1);
  attn_asp<<<1024, 256, 0, stream>>>(qbf, kbf, srcm, adj_s, adjsbf,
                                     xbf, wdT, amask, bd, aspbf);
  asp_wm_v2<<<B_ * H_, 256, 0, stream>>>(aspbf, wmT, tmpA);
  asps_mean_v2<<<B_ * 16, 256, 0, stream>>>(tmpA, kbf, bm, asps);
  avgh_kernel<<<B_, 1024, 0, stream>>>(asps, avgH);
  adjag_kl<<<B_ * L_, 256, 0, stream>>>(asps, avgH, amask, adjr, adj_s,
                                        adj_ag, adjagbf, klp, den_s, den_ag);

  for (int li = 0; li < 2; ++li) {
    int Kd = li ? MEM_ : D_;
    const unsigned short* inag = li ? o_agbf : xbf;
    const unsigned short* ins  = li ? o_sbf : xbf;
    const unsigned short* wAT = li ? wa1T : wa0T;
    const float* bA = li ? ba1 : ba0;
    const unsigned short* wST = li ? ws1T : ws0T;
    const float* bS = li ? bs1 : bs0;
    gemm_bb<64><<<dim3(3, 128, 2), 256, 0, stream>>>(
        inag, wAT, nullptr, nullptr, tTag, 8192, MEM_, Kd, 0, 0, 0, sMemSh,
        nullptr, nullptr, 0,
        ins, wST, nullptr, nullptr, tTs, nullptr, nullptr, 1);
    gemm_bb<64><<<dim3(3, 4, 64), 256, 0, stream>>>(
        adjagbf, tTag, nullptr, g_agbf, gTag, L_, MEM_, L_, sAdjSh, sMemSh, sMemSh,
        sMemSh, bA, den_ag, 1,
        adjsbf, tTs, nullptr, g_sbf, gTs, bS, den_s, 32);
    gemm_bb<64><<<dim3(3, 128, 2), 256, 0, stream>>>(
        g_agbf, aff1T, nullptr, u1bf, nullptr, 8192, MEM_, MEM_, 0, 0, 0, 0,
        nullptr, nullptr, 0,
        g_sbf, aff2T, nullptr, u2bf, nullptr, nullptr, nullptr, 1);
    gemm_sfmx<<<dim3(4, 64), 256, 0, stream>>>(u1bf, g_sbf, P1bf, u2bf, g_agbf, P2bf);
    gemm_bb<64><<<dim3(3, 4, 64), 256, 0, stream>>>(
        P1bf, gTs, nullptr, o_agbf, nullptr, L_, MEM_, L_, sAdjSh, sMemSh, sMemSh, 0,
        nullptr, nullptr, 0,
        P2bf, gTag, nullptr, o_sbf, nullptr, nullptr, nullptr, 32);
  }

  final_kernel<<<B_ + 1, 256, 0, stream>>>(o_agbf, o_sbf, pooled, amask, wc, bc,
                                           klp, dout);
}

// Round 13
// 408.026 us; speedup vs baseline: 1.4900x; 1.0516x over previous
//
#include <hip/hip_runtime.h>

#define B_ 32
#define L_ 256
#define D_ 768
#define H_ 12
#define DK_ 64
#define MEM_ 384

typedef __attribute__((ext_vector_type(8))) short bfrag8;    // 8 bf16 (4 VGPRs)
typedef __attribute__((ext_vector_type(8))) unsigned short us8;
typedef __attribute__((ext_vector_type(4))) float f32x4;

__device__ inline unsigned short f2bf(float f) {
  unsigned u = __float_as_uint(f);
  return (unsigned short)((u + 0x7fffu + ((u >> 16) & 1u)) >> 16);
}
__device__ inline float bf2f(unsigned short u) {
  return __uint_as_float(((unsigned)u) << 16);
}
__device__ inline float tanh_fast(float x) {
  x = fminf(fmaxf(x, -30.f), 30.f);
  float e = __expf(2.f * x);
  return (e - 1.f) * __builtin_amdgcn_rcpf(e + 1.f);
}
__device__ inline void gload_lds16(const unsigned short* g, unsigned short* l) {
  __builtin_amdgcn_global_load_lds(
      (__attribute__((address_space(1))) void*)(g),
      (__attribute__((address_space(3))) void*)(l), 16, 0, 0);
}

// ---------------- block reduce helpers ----------------
__device__ inline float waveRedSum(float v) {
#pragma unroll
  for (int o = 32; o; o >>= 1) v += __shfl_xor(v, o, 64);
  return v;
}
__device__ inline float waveRedMax(float v) {
#pragma unroll
  for (int o = 32; o; o >>= 1) v = fmaxf(v, __shfl_xor(v, o, 64));
  return v;
}
__device__ inline float blkRedSum(float v, float* red) {
  v = waveRedSum(v);
  int w = threadIdx.x >> 6;
  __syncthreads();
  if ((threadIdx.x & 63) == 0) red[w] = v;
  __syncthreads();
  return red[0] + red[1] + red[2] + red[3];
}
__device__ inline float blkRedMax(float v, float* red) {
  v = waveRedMax(v);
  int w = threadIdx.x >> 6;
  __syncthreads();
  if ((threadIdx.x & 63) == 0) red[w] = v;
  __syncthreads();
  return fmaxf(fmaxf(red[0], red[1]), fmaxf(red[2], red[3]));
}

// ---------------- prep: all weight transposes (blocks 0..599) + LayerNorm (600+) -----
__global__ __launch_bounds__(256) void prep_kernel(
    const float* __restrict__ seq, const float* __restrict__ lng,
    const float* __restrict__ lnb, float* __restrict__ xout,
    unsigned short* __restrict__ xbf,
    const float* __restrict__ wq, unsigned short* __restrict__ wqT,
    const float* __restrict__ wk, unsigned short* __restrict__ wkT,
    const float* __restrict__ wa0, unsigned short* __restrict__ wa0T,
    const float* __restrict__ ws0, unsigned short* __restrict__ ws0T,
    const float* __restrict__ wa1, unsigned short* __restrict__ wa1T,
    const float* __restrict__ ws1, unsigned short* __restrict__ ws1T,
    const float* __restrict__ aff1, unsigned short* __restrict__ aff1T,
    const float* __restrict__ aff2, unsigned short* __restrict__ aff2T,
    const float* __restrict__ wd, unsigned short* __restrict__ wdT,
    const float* __restrict__ wm, unsigned short* __restrict__ wmT) {
  int bid = blockIdx.x;
  if (bid >= 600) {  // ---- LayerNorm row ----
    long row = bid - 600;
    const float* p = seq + row * D_;
    float v[3];
#pragma unroll
    for (int i = 0; i < 3; ++i) v[i] = p[threadIdx.x + i * 256];
    __shared__ float red[4];
    float s = v[0] + v[1] + v[2];
    s = blkRedSum(s, red);
    float mu = s * (1.f / D_);
    float ss = 0.f;
#pragma unroll
    for (int i = 0; i < 3; ++i) { float d = v[i] - mu; ss += d * d; }
    ss = blkRedSum(ss, red);
    float sd = sqrtf(ss * (1.f / (D_ - 1)));
    float inv = 1.f / (sd + 1e-6f);
#pragma unroll
    for (int i = 0; i < 3; ++i) {
      int c = threadIdx.x + i * 256;
      float o = lng[c] * (v[i] - mu) * inv + lnb[c];
      xout[row * D_ + c] = o;
      xbf[row * D_ + c] = f2bf(o);
    }
    return;
  }
  const float* src; unsigned short* dst; int Rr, Cc, tIdx;
  if (bid < 144)      { src = wq;   dst = wqT;   Rr = 768; Cc = 768; tIdx = bid; }
  else if (bid < 288) { src = wk;   dst = wkT;   Rr = 768; Cc = 768; tIdx = bid - 144; }
  else if (bid < 360) { src = wa0;  dst = wa0T;  Rr = 768; Cc = 384; tIdx = bid - 288; }
  else if (bid < 432) { src = ws0;  dst = ws0T;  Rr = 768; Cc = 384; tIdx = bid - 360; }
  else if (bid < 468) { src = wa1;  dst = wa1T;  Rr = 384; Cc = 384; tIdx = bid - 432; }
  else if (bid < 504) { src = ws1;  dst = ws1T;  Rr = 384; Cc = 384; tIdx = bid - 468; }
  else if (bid < 540) { src = aff1; dst = aff1T; Rr = 384; Cc = 384; tIdx = bid - 504; }
  else if (bid < 576) { src = aff2; dst = aff2T; Rr = 384; Cc = 384; tIdx = bid - 540; }
  else if (bid < 588) { src = wd;   dst = wdT;   Rr = 768; Cc = 64;  tIdx = bid - 576; }
  else { int h = bid - 588; src = wm + h * 4096; dst = wmT + h * 4096; Rr = 64; Cc = 64; tIdx = 0; }
  __shared__ float tile[64][65];
  int nx = Cc >> 6;
  int c0 = (tIdx % nx) * 64, r0 = (tIdx / nx) * 64;
  int tx = threadIdx.x & 63, ty = threadIdx.x >> 6;
#pragma unroll
  for (int i = 0; i < 16; ++i)
    tile[ty + i * 4][tx] = src[(long)(r0 + ty + i * 4) * Cc + c0 + tx];
  __syncthreads();
#pragma unroll
  for (int i = 0; i < 16; ++i)
    dst[(long)(c0 + ty + i * 4) * Rr + r0 + tx] = f2bf(tile[tx][ty + i * 4]);
}

// ---------------- all-bf16 MFMA GEMM, DMA staging, BK=32, 2-phase double buffer ------
// MR x 128 tile. Stage for tile t+1 is issued BEFORE computing tile t; one
// __syncthreads per K-step (its vmcnt(0) drain lands after the MFMAs).
template <int MR>
__global__ __launch_bounds__(256) void gemm_bb(
    const unsigned short* __restrict__ A, const unsigned short* __restrict__ Bt,
    float* __restrict__ C, unsigned short* __restrict__ Cbf,
    unsigned short* __restrict__ CT,
    int M, int N, int K, long sA, long sB, long sC, long sCT,
    const float* __restrict__ bias, const float* __restrict__ rowDiv, int relu,
    const unsigned short* __restrict__ A2, const unsigned short* __restrict__ Bt2,
    float* __restrict__ C2, unsigned short* __restrict__ Cbf2,
    unsigned short* __restrict__ CT2,
    const float* __restrict__ bias2, const float* __restrict__ rowDiv2, int zsplit) {
  constexpr int MFRAG = MR / 32;
  constexpr int RW = MR / 2;
  constexpr int ASH = MR * 32;       // A tile shorts
  constexpr int BUFS = ASH + 4096;   // A+B shorts per buffer
  constexpr int TSH = 64 * (MR + 8);
  constexpr int SMN = (2 * BUFS > TSH) ? 2 * BUFS : TSH;
  __shared__ alignas(16) unsigned short smem[SMN];
  const int tid = threadIdx.x;
  const int bn = blockIdx.x, bm = blockIdx.y;
  int bz = blockIdx.z;
  const unsigned short* Ap = A; const unsigned short* Btp = Bt;
  float* Cp = C; unsigned short* Cbp = Cbf; unsigned short* CTp = CT;
  const float* biasp = bias; const float* rowDivp = rowDiv;
  if (zsplit > 0 && bz >= zsplit) {
    bz -= zsplit;
    Ap = A2; Btp = Bt2; Cp = C2; Cbp = Cbf2; CTp = CT2; biasp = bias2; rowDivp = rowDiv2;
  }
  Ap += (long)bz * sA; Btp += (long)bz * sB;
  if (Cp) Cp += (long)bz * sC;
  if (Cbp) Cbp += (long)bz * sC;
  if (CTp) CTp += (long)bz * sCT;

  f32x4 acc[MFRAG][4] = {};
  const int l = tid & 63, w = tid >> 6;
  const int wr = w >> 1, wc = w & 1;
  const int lr = l & 15, sg = l >> 4;

  // staging source coords (source slot pre-swizzled by (row>>1)&3)
  const int rc = l >> 2;
  const int sslot = (l & 3) ^ ((rc >> 1) & 3);
  const unsigned short* gA0 = Ap + (long)(bm * MR + w * 16 + rc) * K + sslot * 8;
  const unsigned short* gA1 = (MR == 128)
      ? Ap + (long)(bm * MR + (w + 4) * 16 + rc) * K + sslot * 8 : nullptr;
  const unsigned short* gB0 = Btp + (long)(bn * 128 + w * 16 + rc) * K + sslot * 8;
  const unsigned short* gB1 = Btp + (long)(bn * 128 + (w + 4) * 16 + rc) * K + sslot * 8;
  const int stA0 = w * 512, stA1 = (w + 4) * 512;
  const int stB0 = ASH + w * 512, stB1 = ASH + (w + 4) * 512;

  // read offsets (within buffer) with matching swizzle
  const int swz = (sg ^ ((lr >> 1) & 3)) * 8;
  int aoff[MFRAG], boff[4];
#pragma unroll
  for (int m = 0; m < MFRAG; ++m) aoff[m] = (wr * RW + m * 16 + lr) * 32 + swz;
#pragma unroll
  for (int n = 0; n < 4; ++n) boff[n] = ASH + (wc * 64 + n * 16 + lr) * 32 + swz;

  const int nt = K >> 5;
  // prologue: stage tile 0 into buffer 0
  gload_lds16(gA0, smem + stA0);
  if (MR == 128) gload_lds16(gA1, smem + stA1);
  gload_lds16(gB0, smem + stB0);
  gload_lds16(gB1, smem + stB1);
  __syncthreads();

  for (int t = 0; t < nt; ++t) {
    const int cur = (t & 1) * BUFS;
    if (t + 1 < nt) {  // issue next-tile stage BEFORE compute
      const int nxt = ((t + 1) & 1) * BUFS;
      const int k1 = (t + 1) << 5;
      gload_lds16(gA0 + k1, smem + nxt + stA0);
      if (MR == 128) gload_lds16(gA1 + k1, smem + nxt + stA1);
      gload_lds16(gB0 + k1, smem + nxt + stB0);
      gload_lds16(gB1 + k1, smem + nxt + stB1);
    }
    bfrag8 af[MFRAG], bf[4];
#pragma unroll
    for (int m = 0; m < MFRAG; ++m) af[m] = *(const bfrag8*)(smem + cur + aoff[m]);
#pragma unroll
    for (int n = 0; n < 4; ++n) bf[n] = *(const bfrag8*)(smem + cur + boff[n]);
#pragma unroll
    for (int m = 0; m < MFRAG; ++m)
#pragma unroll
      for (int n = 0; n < 4; ++n)
        acc[m][n] = __builtin_amdgcn_mfma_f32_16x16x32_bf16(af[m], bf[n], acc[m][n], 0, 0, 0);
    __syncthreads();  // drains next-tile loads + protects buffer reuse
  }

  if (Cp || Cbp) {
#pragma unroll
    for (int m = 0; m < MFRAG; ++m) {
#pragma unroll
      for (int r = 0; r < 4; ++r) {
        int row = bm * MR + wr * RW + m * 16 + (l >> 4) * 4 + r;
        float rd = rowDivp ? 1.f / rowDivp[(long)bz * M + row] : 1.f;
#pragma unroll
        for (int n = 0; n < 4; ++n) {
          int col = bn * 128 + wc * 64 + n * 16 + lr;
          float v = acc[m][n][r];
          if (biasp) v += biasp[col];
          v *= rd;
          if (relu) v = fmaxf(v, 0.f);
          if (Cp) Cp[(long)row * N + col] = v;
          if (Cbp) Cbp[(long)row * N + col] = f2bf(v);
        }
      }
    }
  }
  if (CT) {
    auto Ts = (unsigned short(*)[MR + 8])smem;
#pragma unroll
    for (int ch = 0; ch < 2; ++ch) {
      __syncthreads();
      if (wc == ch) {
#pragma unroll
        for (int m = 0; m < MFRAG; ++m) {
#pragma unroll
          for (int r = 0; r < 4; ++r) {
            int rowl = wr * RW + m * 16 + (l >> 4) * 4 + r;
            float rd = rowDivp ? 1.f / rowDivp[(long)bz * M + bm * MR + rowl] : 1.f;
#pragma unroll
            for (int n = 0; n < 4; ++n) {
              int col = bn * 128 + wc * 64 + n * 16 + lr;
              float v = acc[m][n][r];
              if (biasp) v += biasp[col];
              v *= rd;
              if (relu) v = fmaxf(v, 0.f);
              Ts[n * 16 + lr][rowl] = f2bf(v);
            }
          }
        }
      }
      __syncthreads();
      int trow = tid >> 2, tc = (tid & 3) * (MR / 4);
      int colg = bn * 128 + ch * 64 + trow;
      int rowg = bm * MR + tc;
      unsigned short* dp = CTp + (long)(rowg >> 8) * sCT + (long)colg * 256 + (rowg & 255);
#pragma unroll
      for (int j = 0; j < MR / 32; ++j)
        *(us8*)(dp + j * 8) = *(const us8*)&Ts[trow][tc + j * 8];
    }
  }
}

// ---------------- fused attention (0..511, register-prefetched k) + asp (512..1023) ---
__global__ __launch_bounds__(256) void attn_asp(
    const unsigned short* __restrict__ qbf, const unsigned short* __restrict__ kbf,
    const float* __restrict__ srcm, float* __restrict__ adj_s,
    unsigned short* __restrict__ adjsbf,
    const unsigned short* __restrict__ xbf, const unsigned short* __restrict__ wdT,
    const float* __restrict__ amask, const float* __restrict__ bd,
    unsigned short* __restrict__ aspbf) {
  int t = threadIdx.x;
  int w = t >> 6, l = t & 63;
  int lr = l & 15, kg = (l >> 4) * 8;
  if (blockIdx.x >= 512) {  // ---- asp projection ----
    int l0 = (blockIdx.x - 512) << 4;
    const unsigned short* ap = xbf + (long)(l0 + lr) * D_ + kg;
    const unsigned short* bp = wdT + (long)(w * 16 + lr) * D_ + kg;
    f32x4 acc = {};
#pragma unroll
    for (int k0 = 0; k0 < D_; k0 += 32) {
      bfrag8 af = *(const bfrag8*)(ap + k0);
      bfrag8 bf = *(const bfrag8*)(bp + k0);
      acc = __builtin_amdgcn_mfma_f32_16x16x32_bf16(af, bf, acc, 0, 0, 0);
    }
    int col = w * 16 + lr;
#pragma unroll
    for (int r = 0; r < 4; ++r) {
      int row = l0 + (l >> 4) * 4 + r;
      float v = acc[r] * amask[row] + bd[col];
      aspbf[(long)row * DK_ + col] = f2bf(v);
    }
    return;
  }
  int blk = blockIdx.x;
  int b = blk >> 4, l0 = (blk & 15) << 4;
  int rbase = (l >> 4) * 4;
  __shared__ float red[6][2][16][8];
  float acc[4][4] = {};
  float cmv[4];
#pragma unroll
  for (int ct = 0; ct < 4; ++ct) cmv[ct] = srcm[b * L_ + w * 64 + ct * 16 + lr];

#pragma unroll 1
  for (int hp = 0; hp < 6; ++hp) {
    const unsigned short* ap = qbf + ((long)b * L_ + l0 + lr) * D_ + hp * 128 + kg;
    bfrag8 a00 = *(const bfrag8*)ap;
    bfrag8 a01 = *(const bfrag8*)(ap + 32);
    bfrag8 a10 = *(const bfrag8*)(ap + 64);
    bfrag8 a11 = *(const bfrag8*)(ap + 96);
    bfrag8 kv[4][4];
#pragma unroll
    for (int ct = 0; ct < 4; ++ct) {
      const unsigned short* bp =
          kbf + ((long)b * L_ + w * 64 + ct * 16 + lr) * D_ + hp * 128 + kg;
      kv[ct][0] = *(const bfrag8*)bp;
      kv[ct][1] = *(const bfrag8*)(bp + 32);
      kv[ct][2] = *(const bfrag8*)(bp + 64);
      kv[ct][3] = *(const bfrag8*)(bp + 96);
    }
    float sv0[4][4], sv1[4][4];
#pragma unroll
    for (int ct = 0; ct < 4; ++ct) {
      f32x4 c0 = {}, c1 = {};
      c0 = __builtin_amdgcn_mfma_f32_16x16x32_bf16(a00, kv[ct][0], c0, 0, 0, 0);
      c0 = __builtin_amdgcn_mfma_f32_16x16x32_bf16(a01, kv[ct][1], c0, 0, 0, 0);
      c1 = __builtin_amdgcn_mfma_f32_16x16x32_bf16(a10, kv[ct][2], c1, 0, 0, 0);
      c1 = __builtin_amdgcn_mfma_f32_16x16x32_bf16(a11, kv[ct][3], c1, 0, 0, 0);
      bool msk = (cmv[ct] == 0.f);
#pragma unroll
      for (int r = 0; r < 4; ++r) {
        sv0[ct][r] = msk ? -1e9f : c0[r] * 0.125f;
        sv1[ct][r] = msk ? -1e9f : c1[r] * 0.125f;
      }
    }
    float mx0a[4], mx1a[4];
#pragma unroll
    for (int r = 0; r < 4; ++r) {
      float m0 = fmaxf(fmaxf(sv0[0][r], sv0[1][r]), fmaxf(sv0[2][r], sv0[3][r]));
      float m1 = fmaxf(fmaxf(sv1[0][r], sv1[1][r]), fmaxf(sv1[2][r], sv1[3][r]));
#pragma unroll
      for (int o = 1; o < 16; o <<= 1) {
        m0 = fmaxf(m0, __shfl_xor(m0, o, 64));
        m1 = fmaxf(m1, __shfl_xor(m1, o, 64));
      }
      mx0a[r] = m0; mx1a[r] = m1;
      float s0 = 0.f, s1 = 0.f;
#pragma unroll
      for (int ct = 0; ct < 4; ++ct) {
        float e0 = __expf(sv0[ct][r] - m0);
        float e1 = __expf(sv1[ct][r] - m1);
        sv0[ct][r] = e0; sv1[ct][r] = e1;
        s0 += e0; s1 += e1;
      }
#pragma unroll
      for (int o = 1; o < 16; o <<= 1) {
        s0 += __shfl_xor(s0, o, 64);
        s1 += __shfl_xor(s1, o, 64);
      }
      if (lr == 0) {
        red[hp][0][rbase + r][w] = m0;
        red[hp][0][rbase + r][4 + w] = s0;
        red[hp][1][rbase + r][w] = m1;
        red[hp][1][rbase + r][4 + w] = s1;
      }
    }
    __syncthreads();
#pragma unroll
    for (int r = 0; r < 4; ++r) {
      f32x4 m4 = *(const f32x4*)&red[hp][0][rbase + r][0];
      f32x4 s4 = *(const f32x4*)&red[hp][0][rbase + r][4];
      float mt = fmaxf(fmaxf(m4[0], m4[1]), fmaxf(m4[2], m4[3]));
      float tot = s4[0] * __expf(m4[0] - mt) + s4[1] * __expf(m4[1] - mt) +
                  s4[2] * __expf(m4[2] - mt) + s4[3] * __expf(m4[3] - mt);
      float sc0 = __expf(mx0a[r] - mt) * __builtin_amdgcn_rcpf(tot);
      f32x4 n4 = *(const f32x4*)&red[hp][1][rbase + r][0];
      f32x4 t4 = *(const f32x4*)&red[hp][1][rbase + r][4];
      float nt = fmaxf(fmaxf(n4[0], n4[1]), fmaxf(n4[2], n4[3]));
      float tt = t4[0] * __expf(n4[0] - nt) + t4[1] * __expf(n4[1] - nt) +
                 t4[2] * __expf(n4[2] - nt) + t4[3] * __expf(n4[3] - nt);
      float sc1 = __expf(mx1a[r] - nt) * __builtin_amdgcn_rcpf(tt);
#pragma unroll
      for (int ct = 0; ct < 4; ++ct)
        acc[ct][r] += sv0[ct][r] * sc0 + sv1[ct][r] * sc1;
    }
  }

#pragma unroll
  for (int r = 0; r < 4; ++r) {
    int row = l0 + rbase + r;
    float rm = srcm[b * L_ + row];
#pragma unroll
    for (int ct = 0; ct < 4; ++ct) {
      int col = w * 64 + ct * 16 + lr;
      float v = acc[ct][r] * (1.f / H_);
      if (col == row) v = 1.f;
      v *= rm;
      long idx = ((long)b * L_ + row) * L_ + col;
      adj_s[idx] = v;
      adjsbf[idx] = f2bf(v);
    }
  }
}

// ---------------- tmpA[b,h] = aspbf[b] @ Wm[h], MFMA, no LDS ----------------
__global__ __launch_bounds__(256) void asp_wm_v2(const unsigned short* __restrict__ aspbf,
                                                 const unsigned short* __restrict__ wmT,
                                                 unsigned short* __restrict__ tmpA) {
  int bh = blockIdx.x;
  int b = bh / H_, h = bh % H_;
  int t = threadIdx.x;
  int w = t >> 6, l = t & 63;
  int lr = l & 15, kg = (l >> 4) * 8;
  const unsigned short* wp = wmT + h * 4096;
  f32x4 acc[4][4] = {};
#pragma unroll
  for (int ks = 0; ks < 2; ++ks) {
    int k0 = ks * 32;
    bfrag8 af[4], bf[4];
#pragma unroll
    for (int m = 0; m < 4; ++m)
      af[m] = *(const bfrag8*)(aspbf + (long)(b * L_ + w * 64 + m * 16 + lr) * DK_ + k0 + kg);
#pragma unroll
    for (int n = 0; n < 4; ++n)
      bf[n] = *(const bfrag8*)(wp + (n * 16 + lr) * 64 + k0 + kg);
#pragma unroll
    for (int m = 0; m < 4; ++m)
#pragma unroll
      for (int n = 0; n < 4; ++n)
        acc[m][n] = __builtin_amdgcn_mfma_f32_16x16x32_bf16(af[m], bf[n], acc[m][n], 0, 0, 0);
  }
#pragma unroll
  for (int m = 0; m < 4; ++m)
#pragma unroll
    for (int n = 0; n < 4; ++n)
#pragma unroll
      for (int r = 0; r < 4; ++r) {
        int row = w * 64 + m * 16 + (l >> 4) * 4 + r;
        int col = n * 16 + lr;
        tmpA[(((long)b * H_ + h) * L_ + row) * DK_ + col] = f2bf(acc[m][n][r]);
      }
}

// ---------------- fused S-GEMM + row softmax (LDS-staged bf16) ----------------
__global__ __launch_bounds__(256) void gemm_sfmx(
    const unsigned short* __restrict__ u1, const unsigned short* __restrict__ g1,
    unsigned short* __restrict__ P1,
    const unsigned short* __restrict__ u2, const unsigned short* __restrict__ g2,
    unsigned short* __restrict__ P2) {
  int bm = blockIdx.x;
  int bz = blockIdx.y;
  const unsigned short* Ap; const unsigned short* Bp; unsigned short* Pp;
  if (bz < 32) {
    Ap = u1 + (long)bz * L_ * MEM_; Bp = g1 + (long)bz * L_ * MEM_;
    Pp = P1 + (long)bz * L_ * L_;
  } else {
    int z = bz - 32;
    Ap = u2 + (long)z * L_ * MEM_; Bp = g2 + (long)z * L_ * MEM_;
    Pp = P2 + (long)z * L_ * L_;
  }
  __shared__ unsigned short As[64][40];
  __shared__ unsigned short Bs[256][40];
  __shared__ float redm[2][64];
  __shared__ float reds[2][64];
  const int t = threadIdx.x;
  const int l = t & 63, w = t >> 6;
  const int wr = w >> 1, wc = w & 1;
  const int lr = l & 15, kg = (l >> 4) * 8;
  f32x4 acc[2][8] = {};
  const int arA = t >> 2, akA = (t & 3) * 8;

  for (int k0 = 0; k0 < MEM_; k0 += 32) {
    *(us8*)&As[arA][akA] = *(const us8*)(Ap + (long)(bm * 64 + arA) * MEM_ + k0 + akA);
#pragma unroll
    for (int j = 0; j < 4; ++j)
      *(us8*)&Bs[t][j * 8] = *(const us8*)(Bp + (long)t * MEM_ + k0 + j * 8);
    __syncthreads();
    bfrag8 af[2], bf[8];
#pragma unroll
    for (int m = 0; m < 2; ++m) af[m] = *(const bfrag8*)&As[wr * 32 + m * 16 + lr][kg];
#pragma unroll
    for (int n = 0; n < 8; ++n) bf[n] = *(const bfrag8*)&Bs[wc * 128 + n * 16 + lr][kg];
#pragma unroll
    for (int m = 0; m < 2; ++m)
#pragma unroll
      for (int n = 0; n < 8; ++n)
        acc[m][n] = __builtin_amdgcn_mfma_f32_16x16x32_bf16(af[m], bf[n], acc[m][n], 0, 0, 0);
    __syncthreads();
  }

#pragma unroll
  for (int m = 0; m < 2; ++m) {
#pragma unroll
    for (int r = 0; r < 4; ++r) {
      int lrow = wr * 32 + m * 16 + (l >> 4) * 4 + r;
      float mx = -1e30f;
#pragma unroll
      for (int n = 0; n < 8; ++n) mx = fmaxf(mx, acc[m][n][r]);
#pragma unroll
      for (int o = 1; o < 16; o <<= 1) mx = fmaxf(mx, __shfl_xor(mx, o, 64));
      if (lr == 0) redm[wc][lrow] = mx;
    }
  }
  __syncthreads();
#pragma unroll
  for (int m = 0; m < 2; ++m) {
#pragma unroll
    for (int r = 0; r < 4; ++r) {
      int lrow = wr * 32 + m * 16 + (l >> 4) * 4 + r;
      float mx = fmaxf(redm[0][lrow], redm[1][lrow]);
      float s = 0.f;
#pragma unroll
      for (int n = 0; n < 8; ++n) {
        float e = __expf(acc[m][n][r] - mx);
        acc[m][n][r] = e;
        s += e;
      }
#pragma unroll
      for (int o = 1; o < 16; o <<= 1) s += __shfl_xor(s, o, 64);
      if (lr == 0) reds[wc][lrow] = s;
    }
  }
  __syncthreads();
#pragma unroll
  for (int m = 0; m < 2; ++m) {
#pragma unroll
    for (int r = 0; r < 4; ++r) {
      int lrow = wr * 32 + m * 16 + (l >> 4) * 4 + r;
      float inv = 1.f / (reds[0][lrow] + reds[1][lrow]);
      int row = bm * 64 + lrow;
#pragma unroll
      for (int n = 0; n < 8; ++n) {
        int col = wc * 128 + n * 16 + lr;
        Pp[(long)row * L_ + col] = f2bf(acc[m][n][r] * inv);
      }
    }
  }
}

// ---------------- asps_mean via MFMA ----------------
__global__ __launch_bounds__(256) void asps_mean_v2(
    const unsigned short* __restrict__ tmpA,
    const unsigned short* __restrict__ kbf,
    const float* __restrict__ bias_m,
    float* __restrict__ asps_mean) {
  int blk = blockIdx.x;
  int b = blk >> 4, l0 = (blk & 15) << 4;
  int t = threadIdx.x;
  int w = t >> 6, l = t & 63;
  int lr = l & 15, kg = (l >> 4) * 8;
  float bm = bias_m[0];
  float accg[4][4] = {};
  for (int h = 0; h < H_; ++h) {
    const unsigned short* ap = tmpA + (((long)b * H_ + h) * L_ + l0 + lr) * 64 + kg;
    bfrag8 af0 = *(const bfrag8*)ap;
    bfrag8 af1 = *(const bfrag8*)(ap + 32);
#pragma unroll
    for (int ct = 0; ct < 4; ++ct) {
      const unsigned short* bp =
          kbf + ((long)b * L_ + w * 64 + ct * 16 + lr) * D_ + h * 64 + kg;
      bfrag8 bf0 = *(const bfrag8*)bp;
      bfrag8 bf1 = *(const bfrag8*)(bp + 32);
      f32x4 accl = {};
      accl = __builtin_amdgcn_mfma_f32_16x16x32_bf16(af0, bf0, accl, 0, 0, 0);
      accl = __builtin_amdgcn_mfma_f32_16x16x32_bf16(af1, bf1, accl, 0, 0, 0);
#pragma unroll
      for (int r = 0; r < 4; ++r) accg[ct][r] += tanh_fast(accl[r] + bm);
    }
  }
#pragma unroll
  for (int ct = 0; ct < 4; ++ct) {
    int col = w * 64 + ct * 16 + lr;
#pragma unroll
    for (int r = 0; r < 4; ++r) {
      int row = l0 + (l >> 4) * 4 + r;
      asps_mean[((long)b * L_ + row) * L_ + col] = accg[ct][r] * (1.f / H_);
    }
  }
}

// ---------------- avgH ----------------
__global__ __launch_bounds__(1024) void avgh_kernel(const float* __restrict__ asps_mean,
                                                    float* __restrict__ avgH) {
  int b = blockIdx.x;
  int m = threadIdx.x & 255, q = threadIdx.x >> 8;
  __shared__ float part[4][256];
  float s = 0.f;
  for (int l = q * 64; l < q * 64 + 64; ++l)
    s += asps_mean[((long)b * L_ + l) * L_ + m];
  part[q][m] = s;
  __syncthreads();
  if (q == 0)
    avgH[b * L_ + m] = (part[0][m] + part[1][m] + part[2][m] + part[3][m]) * (1.f / L_);
}

// ---------------- fused adj_ag + KL partials + row denominators ----------------
__global__ __launch_bounds__(256) void adjag_kl(const float* __restrict__ asps_mean,
                                                const float* __restrict__ avgH,
                                                const float* __restrict__ amask,
                                                const float* __restrict__ adjr,
                                                const float* __restrict__ adj_s,
                                                float* __restrict__ adj_ag,
                                                unsigned short* __restrict__ adjagbf,
                                                float* __restrict__ klpart,
                                                float* __restrict__ den_s,
                                                float* __restrict__ den_ag) {
  long row = blockIdx.x;               // b*L + l
  int m = threadIdx.x;
  int l = (int)(row & 255);
  int b = (int)(row >> 8);
  long idx = row * L_ + m;
  bool rowa = amask[b * L_ + l] > 0.f;
  bool cola = amask[b * L_ + m] > 0.f;
  float asa;
  if (rowa && cola) asa = (l >= m) ? avgH[b * L_ + m] : avgH[b * L_ + l];
  else if (rowa)    asa = avgH[b * L_ + m];
  else if (cola)    asa = avgH[b * L_ + l];
  else              asa = asps_mean[idx];
  float r = (asa > 0.25f) ? 1.f : expf(adjr[idx]);
  float a = r * asa;
  adj_ag[idx] = a;
  adjagbf[idx] = f2bf(a);

  __shared__ float red[4];
  float s = adj_s[idx];
  float sum_s = blkRedSum(s, red);
  float sum_a = blkRedSum(a, red);
  float mx_s = blkRedMax(s, red);
  float mx_a = blkRedMax(a, red);
  float es = expf(s - mx_s), ea = expf(a - mx_a);
  float ses = blkRedSum(es, red);
  float sea = blkRedSum(ea, red);
  float logq = (s - mx_s) - logf(ses);
  float logp = (a - mx_a) - logf(sea);
  float term = (es / ses) * (logq - logp);
  float kp = blkRedSum(term, red);
  if (m == 0) {
    klpart[row] = kp;
    den_s[row] = sum_s + 1.f;
    den_ag[row] = sum_a + 1.f;
  }
}

// ---------------- classifier head (+ KL finish at blockIdx == B_) ----------------
__global__ __launch_bounds__(256) void final_kernel(const unsigned short* __restrict__ o_ag,
                                                    const unsigned short* __restrict__ o_s,
                                                    const float* __restrict__ pooled,
                                                    const float* __restrict__ amask,
                                                    const float* __restrict__ wc,
                                                    const float* __restrict__ bc,
                                                    const float* __restrict__ klpart,
                                                    float* __restrict__ dout) {
  int b = blockIdx.x, t = threadIdx.x;
  __shared__ float red[4];
  if (b == B_) {  // KL finish
    float s = 0.f;
    for (int i = t; i < B_ * L_; i += 256) s += klpart[i];
    s = blkRedSum(s, red);
    if (t == 0) dout[96] = expf(-s * 0.1f);
    return;
  }
  __shared__ float cS[1536];
  __shared__ float maskS[256];
  maskS[t] = amask[b * L_ + t];
  float wn = blkRedSum(maskS[t], red);
  for (int e = t; e < MEM_; e += 256) {
    float s1 = 0.f, s2 = 0.f;
    for (int l = 0; l < L_; ++l) {
      float mk = maskS[l];
      if (mk != 0.f) {
        s1 += mk * bf2f(o_ag[((long)b * L_ + l) * MEM_ + e]);
        s2 += mk * bf2f(o_s[((long)b * L_ + l) * MEM_ + e]);
      }
    }
    cS[e] = s1 / wn;
    cS[MEM_ + e] = s2 / wn;
  }
  for (int j = t; j < D_; j += 256) cS[2 * MEM_ + j] = pooled[b * D_ + j];
  __syncthreads();
  float p0 = 0.f, p1 = 0.f, p2 = 0.f;
  for (int j = t; j < 1536; j += 256) {
    float v = cS[j];
    p0 += v * wc[j * 3 + 0];
    p1 += v * wc[j * 3 + 1];
    p2 += v * wc[j * 3 + 2];
  }
  p0 = blkRedSum(p0, red);
  p1 = blkRedSum(p1, red);
  p2 = blkRedSum(p2, red);
  if (t == 0) {
    dout[b * 3 + 0] = p0 + bc[0];
    dout[b * 3 + 1] = p1 + bc[1];
    dout[b * 3 + 2] = p2 + bc[2];
  }
}

extern "C" void kernel_launch(void* const* d_in, const int* in_sizes, int n_in,
                              void* d_out, int out_size, void* d_ws, size_t ws_size,
                              hipStream_t stream) {
  const float* seq    = (const float*)d_in[0];
  const float* pooled = (const float*)d_in[1];
  const float* adjr   = (const float*)d_in[2];
  const float* srcm   = (const float*)d_in[3];
  const float* amask  = (const float*)d_in[4];
  const float* ln_g   = (const float*)d_in[5];
  const float* ln_b   = (const float*)d_in[6];
  const float* wq     = (const float*)d_in[7];
  const float* bq     = (const float*)d_in[8];
  const float* wk     = (const float*)d_in[9];
  const float* bk     = (const float*)d_in[10];
  const float* wd     = (const float*)d_in[11];
  const float* bd     = (const float*)d_in[12];
  const float* wm     = (const float*)d_in[13];
  const float* bm     = (const float*)d_in[14];
  const float* wa0    = (const float*)d_in[15];
  const float* ba0    = (const float*)d_in[16];
  const float* wa1    = (const float*)d_in[17];
  const float* ba1    = (const float*)d_in[18];
  const float* ws0    = (const float*)d_in[19];
  const float* bs0    = (const float*)d_in[20];
  const float* ws1    = (const float*)d_in[21];
  const float* bs1    = (const float*)d_in[22];
  const float* aff1   = (const float*)d_in[23];
  const float* aff2   = (const float*)d_in[24];
  const float* wc     = (const float*)d_in[25];
  const float* bc     = (const float*)d_in[26];

  float* ws = (float*)d_ws;
  float* S0 = ws;
  float* S1 = S0 + 6291456;
  float* S2 = S1 + 3145728;
  float* S3 = S2 + 3145728;
  float* S4 = S3 + 3145728;
  float* S5 = S4 + 524288;
  float* adj_s  = S5 + 2097152;
  float* adj_ag = adj_s + 2097152;
  unsigned short* adjsbf  = (unsigned short*)(adj_ag + 2097152);
  unsigned short* adjagbf = adjsbf + 2097152;
  unsigned short* wT      = adjagbf + 2097152;
  unsigned short* wqT   = wT;
  unsigned short* wkT   = wT + 589824;
  unsigned short* wa0T  = wT + 1179648;
  unsigned short* ws0T  = wT + 1474560;
  unsigned short* wa1T  = wT + 1769472;
  unsigned short* ws1T  = wT + 1916928;
  unsigned short* aff1T = wT + 2064384;
  unsigned short* aff2T = wT + 2211840;
  float* tail   = (float*)(wT + 2359296);
  float* avgH   = tail;
  float* den_s  = avgH + 8192;
  float* den_ag = den_s + 8192;
  float* klp    = den_ag + 8192;

  float* x = S0;
  unsigned short* o_agbf = (unsigned short*)S0;
  unsigned short* o_sbf  = o_agbf + 3145728;
  unsigned short* gTag   = o_agbf + 6291456;
  unsigned short* gTs    = o_agbf + 9437184;
  unsigned short* xbf    = (unsigned short*)S1;
  unsigned short* qbf    = (unsigned short*)S2;
  unsigned short* tmpA   = (unsigned short*)S2;
  unsigned short* g_agbf = (unsigned short*)S2;
  unsigned short* g_sbf  = g_agbf + 3145728;
  unsigned short* kbf    = (unsigned short*)S3;
  unsigned short* tTag   = (unsigned short*)S3;
  unsigned short* tTs    = tTag + 3145728;
  unsigned short* u1bf   = (unsigned short*)S3;
  unsigned short* u2bf   = u1bf + 3145728;
  unsigned short* aspbf  = (unsigned short*)S4;
  unsigned short* wdT    = aspbf + 524288;
  unsigned short* wmT    = wdT + 49152;
  float* asps = S5;
  unsigned short* P1bf = (unsigned short*)S5;
  unsigned short* P2bf = P1bf + 2097152;
  float* dout = (float*)d_out;

  const long sAdjSh = (long)L_ * L_;
  const long sMemSh = (long)L_ * MEM_;

  prep_kernel<<<600 + B_ * L_, 256, 0, stream>>>(
      seq, ln_g, ln_b, x, xbf, wq, wqT, wk, wkT, wa0, wa0T, ws0, ws0T,
      wa1, wa1T, ws1, ws1T, aff1, aff1T, aff2, aff2T, wd, wdT, wm, wmT);
  // paired q/k projections (MR=128 for reuse, pipelined staging)
  gemm_bb<128><<<dim3(6, 64, 2), 256, 0, stream>>>(
      xbf, wqT, nullptr, qbf, nullptr, 8192, 768, 768, 0, 0, 0, 0, bq, nullptr, 0,
      xbf, wkT, nullptr, kbf, nullptr, bk, nullptr, 1);
  attn_asp<<<1024, 256, 0, stream>>>(qbf, kbf, srcm, adj_s, adjsbf,
                                     xbf, wdT, amask, bd, aspbf);
  asp_wm_v2<<<B_ * H_, 256, 0, stream>>>(aspbf, wmT, tmpA);
  asps_mean_v2<<<B_ * 16, 256, 0, stream>>>(tmpA, kbf, bm, asps);
  avgh_kernel<<<B_, 1024, 0, stream>>>(asps, avgH);
  adjag_kl<<<B_ * L_, 256, 0, stream>>>(asps, avgH, amask, adjr, adj_s,
                                        adj_ag, adjagbf, klp, den_s, den_ag);

  for (int li = 0; li < 2; ++li) {
    int Kd = li ? MEM_ : D_;
    const unsigned short* inag = li ? o_agbf : xbf;
    const unsigned short* ins  = li ? o_sbf : xbf;
    const unsigned short* wAT = li ? wa1T : wa0T;
    const float* bA = li ? ba1 : ba0;
    const unsigned short* wST = li ? ws1T : ws0T;
    const float* bS = li ? bs1 : bs0;
    gemm_bb<64><<<dim3(3, 128, 2), 256, 0, stream>>>(
        inag, wAT, nullptr, nullptr, tTag, 8192, MEM_, Kd, 0, 0, 0, sMemSh,
        nullptr, nullptr, 0,
        ins, wST, nullptr, nullptr, tTs, nullptr, nullptr, 1);
    gemm_bb<64><<<dim3(3, 4, 64), 256, 0, stream>>>(
        adjagbf, tTag, nullptr, g_agbf, gTag, L_, MEM_, L_, sAdjSh, sMemSh, sMemSh,
        sMemSh, bA, den_ag, 1,
        adjsbf, tTs, nullptr, g_sbf, gTs, bS, den_s, 32);
    gemm_bb<64><<<dim3(3, 128, 2), 256, 0, stream>>>(
        g_agbf, aff1T, nullptr, u1bf, nullptr, 8192, MEM_, MEM_, 0, 0, 0, 0,
        nullptr, nullptr, 0,
        g_sbf, aff2T, nullptr, u2bf, nullptr, nullptr, nullptr, 1);
    gemm_sfmx<<<dim3(4, 64), 256, 0, stream>>>(u1bf, g_sbf, P1bf, u2bf, g_agbf, P2bf);
    gemm_bb<64><<<dim3(3, 4, 64), 256, 0, stream>>>(
        P1bf, gTs, nullptr, o_agbf, nullptr, L_, MEM_, L_, sAdjSh, sMemSh, sMemSh, 0,
        nullptr, nullptr, 0,
        P2bf, gTag, nullptr, o_sbf, nullptr, nullptr, nullptr, 32);
  }

  final_kernel<<<B_ + 1, 256, 0, stream>>>(o_agbf, o_sbf, pooled, amask, wc, bc,
                                           klp, dout);
}

// Round 14
// 395.225 us; speedup vs baseline: 1.5383x; 1.0324x over previous
//
#include <hip/hip_runtime.h>

#define B_ 32
#define L_ 256
#define D_ 768
#define H_ 12
#define DK_ 64
#define MEM_ 384

typedef __attribute__((ext_vector_type(8))) short bfrag8;    // 8 bf16 (4 VGPRs)
typedef __attribute__((ext_vector_type(8))) unsigned short us8;
typedef __attribute__((ext_vector_type(4))) float f32x4;

__device__ inline unsigned short f2bf(float f) {
  unsigned u = __float_as_uint(f);
  return (unsigned short)((u + 0x7fffu + ((u >> 16) & 1u)) >> 16);
}
__device__ inline float bf2f(unsigned short u) {
  return __uint_as_float(((unsigned)u) << 16);
}
__device__ inline float tanh_fast(float x) {
  x = fminf(fmaxf(x, -30.f), 30.f);
  float e = __expf(2.f * x);
  return (e - 1.f) * __builtin_amdgcn_rcpf(e + 1.f);
}
__device__ inline void gload_lds16(const unsigned short* g, unsigned short* l) {
  __builtin_amdgcn_global_load_lds(
      (__attribute__((address_space(1))) void*)(g),
      (__attribute__((address_space(3))) void*)(l), 16, 0, 0);
}

// ---------------- block reduce helpers ----------------
__device__ inline float waveRedSum(float v) {
#pragma unroll
  for (int o = 32; o; o >>= 1) v += __shfl_xor(v, o, 64);
  return v;
}
__device__ inline float waveRedMax(float v) {
#pragma unroll
  for (int o = 32; o; o >>= 1) v = fmaxf(v, __shfl_xor(v, o, 64));
  return v;
}
__device__ inline float blkRedSum(float v, float* red) {
  v = waveRedSum(v);
  int w = threadIdx.x >> 6;
  __syncthreads();
  if ((threadIdx.x & 63) == 0) red[w] = v;
  __syncthreads();
  return red[0] + red[1] + red[2] + red[3];
}
__device__ inline float blkRedMax(float v, float* red) {
  v = waveRedMax(v);
  int w = threadIdx.x >> 6;
  __syncthreads();
  if ((threadIdx.x & 63) == 0) red[w] = v;
  __syncthreads();
  return fmaxf(fmaxf(red[0], red[1]), fmaxf(red[2], red[3]));
}

// ---------------- prep: all weight transposes (blocks 0..599) + LayerNorm (600+) -----
__global__ __launch_bounds__(256) void prep_kernel(
    const float* __restrict__ seq, const float* __restrict__ lng,
    const float* __restrict__ lnb, float* __restrict__ xout,
    unsigned short* __restrict__ xbf,
    const float* __restrict__ wq, unsigned short* __restrict__ wqT,
    const float* __restrict__ wk, unsigned short* __restrict__ wkT,
    const float* __restrict__ wa0, unsigned short* __restrict__ wa0T,
    const float* __restrict__ ws0, unsigned short* __restrict__ ws0T,
    const float* __restrict__ wa1, unsigned short* __restrict__ wa1T,
    const float* __restrict__ ws1, unsigned short* __restrict__ ws1T,
    const float* __restrict__ aff1, unsigned short* __restrict__ aff1T,
    const float* __restrict__ aff2, unsigned short* __restrict__ aff2T,
    const float* __restrict__ wd, unsigned short* __restrict__ wdT,
    const float* __restrict__ wm, unsigned short* __restrict__ wmT) {
  int bid = blockIdx.x;
  if (bid >= 600) {  // ---- LayerNorm row ----
    long row = bid - 600;
    const float* p = seq + row * D_;
    float v[3];
#pragma unroll
    for (int i = 0; i < 3; ++i) v[i] = p[threadIdx.x + i * 256];
    __shared__ float red[4];
    float s = v[0] + v[1] + v[2];
    s = blkRedSum(s, red);
    float mu = s * (1.f / D_);
    float ss = 0.f;
#pragma unroll
    for (int i = 0; i < 3; ++i) { float d = v[i] - mu; ss += d * d; }
    ss = blkRedSum(ss, red);
    float sd = sqrtf(ss * (1.f / (D_ - 1)));
    float inv = 1.f / (sd + 1e-6f);
#pragma unroll
    for (int i = 0; i < 3; ++i) {
      int c = threadIdx.x + i * 256;
      float o = lng[c] * (v[i] - mu) * inv + lnb[c];
      xout[row * D_ + c] = o;
      xbf[row * D_ + c] = f2bf(o);
    }
    return;
  }
  const float* src; unsigned short* dst; int Rr, Cc, tIdx;
  if (bid < 144)      { src = wq;   dst = wqT;   Rr = 768; Cc = 768; tIdx = bid; }
  else if (bid < 288) { src = wk;   dst = wkT;   Rr = 768; Cc = 768; tIdx = bid - 144; }
  else if (bid < 360) { src = wa0;  dst = wa0T;  Rr = 768; Cc = 384; tIdx = bid - 288; }
  else if (bid < 432) { src = ws0;  dst = ws0T;  Rr = 768; Cc = 384; tIdx = bid - 360; }
  else if (bid < 468) { src = wa1;  dst = wa1T;  Rr = 384; Cc = 384; tIdx = bid - 432; }
  else if (bid < 504) { src = ws1;  dst = ws1T;  Rr = 384; Cc = 384; tIdx = bid - 468; }
  else if (bid < 540) { src = aff1; dst = aff1T; Rr = 384; Cc = 384; tIdx = bid - 504; }
  else if (bid < 576) { src = aff2; dst = aff2T; Rr = 384; Cc = 384; tIdx = bid - 540; }
  else if (bid < 588) { src = wd;   dst = wdT;   Rr = 768; Cc = 64;  tIdx = bid - 576; }
  else { int h = bid - 588; src = wm + h * 4096; dst = wmT + h * 4096; Rr = 64; Cc = 64; tIdx = 0; }
  __shared__ float tile[64][65];
  int nx = Cc >> 6;
  int c0 = (tIdx % nx) * 64, r0 = (tIdx / nx) * 64;
  int tx = threadIdx.x & 63, ty = threadIdx.x >> 6;
#pragma unroll
  for (int i = 0; i < 16; ++i)
    tile[ty + i * 4][tx] = src[(long)(r0 + ty + i * 4) * Cc + c0 + tx];
  __syncthreads();
#pragma unroll
  for (int i = 0; i < 16; ++i)
    dst[(long)(c0 + ty + i * 4) * Rr + r0 + tx] = f2bf(tile[tx][ty + i * 4]);
}

// ---------------- all-bf16 MFMA GEMM, DMA staging, BK=32, 2-phase double buffer ------
template <int MR>
__global__ __launch_bounds__(256) void gemm_bb(
    const unsigned short* __restrict__ A, const unsigned short* __restrict__ Bt,
    float* __restrict__ C, unsigned short* __restrict__ Cbf,
    unsigned short* __restrict__ CT,
    int M, int N, int K, long sA, long sB, long sC, long sCT,
    const float* __restrict__ bias, const float* __restrict__ rowDiv, int relu,
    const unsigned short* __restrict__ A2, const unsigned short* __restrict__ Bt2,
    float* __restrict__ C2, unsigned short* __restrict__ Cbf2,
    unsigned short* __restrict__ CT2,
    const float* __restrict__ bias2, const float* __restrict__ rowDiv2, int zsplit) {
  constexpr int MFRAG = MR / 32;
  constexpr int RW = MR / 2;
  constexpr int ASH = MR * 32;
  constexpr int BUFS = ASH + 4096;
  constexpr int TSH = 64 * (MR + 8);
  constexpr int SMN = (2 * BUFS > TSH) ? 2 * BUFS : TSH;
  __shared__ alignas(16) unsigned short smem[SMN];
  const int tid = threadIdx.x;
  const int bn = blockIdx.x, bm = blockIdx.y;
  int bz = blockIdx.z;
  const unsigned short* Ap = A; const unsigned short* Btp = Bt;
  float* Cp = C; unsigned short* Cbp = Cbf; unsigned short* CTp = CT;
  const float* biasp = bias; const float* rowDivp = rowDiv;
  if (zsplit > 0 && bz >= zsplit) {
    bz -= zsplit;
    Ap = A2; Btp = Bt2; Cp = C2; Cbp = Cbf2; CTp = CT2; biasp = bias2; rowDivp = rowDiv2;
  }
  Ap += (long)bz * sA; Btp += (long)bz * sB;
  if (Cp) Cp += (long)bz * sC;
  if (Cbp) Cbp += (long)bz * sC;
  if (CTp) CTp += (long)bz * sCT;

  f32x4 acc[MFRAG][4] = {};
  const int l = tid & 63, w = tid >> 6;
  const int wr = w >> 1, wc = w & 1;
  const int lr = l & 15, sg = l >> 4;

  const int rc = l >> 2;
  const int sslot = (l & 3) ^ ((rc >> 1) & 3);
  const unsigned short* gA0 = Ap + (long)(bm * MR + w * 16 + rc) * K + sslot * 8;
  const unsigned short* gA1 = (MR == 128)
      ? Ap + (long)(bm * MR + (w + 4) * 16 + rc) * K + sslot * 8 : nullptr;
  const unsigned short* gB0 = Btp + (long)(bn * 128 + w * 16 + rc) * K + sslot * 8;
  const unsigned short* gB1 = Btp + (long)(bn * 128 + (w + 4) * 16 + rc) * K + sslot * 8;
  const int stA0 = w * 512, stA1 = (w + 4) * 512;
  const int stB0 = ASH + w * 512, stB1 = ASH + (w + 4) * 512;

  const int swz = (sg ^ ((lr >> 1) & 3)) * 8;
  int aoff[MFRAG], boff[4];
#pragma unroll
  for (int m = 0; m < MFRAG; ++m) aoff[m] = (wr * RW + m * 16 + lr) * 32 + swz;
#pragma unroll
  for (int n = 0; n < 4; ++n) boff[n] = ASH + (wc * 64 + n * 16 + lr) * 32 + swz;

  const int nt = K >> 5;
  gload_lds16(gA0, smem + stA0);
  if (MR == 128) gload_lds16(gA1, smem + stA1);
  gload_lds16(gB0, smem + stB0);
  gload_lds16(gB1, smem + stB1);
  __syncthreads();

  for (int t = 0; t < nt; ++t) {
    const int cur = (t & 1) * BUFS;
    if (t + 1 < nt) {
      const int nxt = ((t + 1) & 1) * BUFS;
      const int k1 = (t + 1) << 5;
      gload_lds16(gA0 + k1, smem + nxt + stA0);
      if (MR == 128) gload_lds16(gA1 + k1, smem + nxt + stA1);
      gload_lds16(gB0 + k1, smem + nxt + stB0);
      gload_lds16(gB1 + k1, smem + nxt + stB1);
    }
    bfrag8 af[MFRAG], bf[4];
#pragma unroll
    for (int m = 0; m < MFRAG; ++m) af[m] = *(const bfrag8*)(smem + cur + aoff[m]);
#pragma unroll
    for (int n = 0; n < 4; ++n) bf[n] = *(const bfrag8*)(smem + cur + boff[n]);
#pragma unroll
    for (int m = 0; m < MFRAG; ++m)
#pragma unroll
      for (int n = 0; n < 4; ++n)
        acc[m][n] = __builtin_amdgcn_mfma_f32_16x16x32_bf16(af[m], bf[n], acc[m][n], 0, 0, 0);
    __syncthreads();
  }

  if (Cp || Cbp) {
#pragma unroll
    for (int m = 0; m < MFRAG; ++m) {
#pragma unroll
      for (int r = 0; r < 4; ++r) {
        int row = bm * MR + wr * RW + m * 16 + (l >> 4) * 4 + r;
        float rd = rowDivp ? 1.f / rowDivp[(long)bz * M + row] : 1.f;
#pragma unroll
        for (int n = 0; n < 4; ++n) {
          int col = bn * 128 + wc * 64 + n * 16 + lr;
          float v = acc[m][n][r];
          if (biasp) v += biasp[col];
          v *= rd;
          if (relu) v = fmaxf(v, 0.f);
          if (Cp) Cp[(long)row * N + col] = v;
          if (Cbp) Cbp[(long)row * N + col] = f2bf(v);
        }
      }
    }
  }
  if (CT) {
    auto Ts = (unsigned short(*)[MR + 8])smem;
#pragma unroll
    for (int ch = 0; ch < 2; ++ch) {
      __syncthreads();
      if (wc == ch) {
#pragma unroll
        for (int m = 0; m < MFRAG; ++m) {
#pragma unroll
          for (int r = 0; r < 4; ++r) {
            int rowl = wr * RW + m * 16 + (l >> 4) * 4 + r;
            float rd = rowDivp ? 1.f / rowDivp[(long)bz * M + bm * MR + rowl] : 1.f;
#pragma unroll
            for (int n = 0; n < 4; ++n) {
              int col = bn * 128 + wc * 64 + n * 16 + lr;
              float v = acc[m][n][r];
              if (biasp) v += biasp[col];
              v *= rd;
              if (relu) v = fmaxf(v, 0.f);
              Ts[n * 16 + lr][rowl] = f2bf(v);
            }
          }
        }
      }
      __syncthreads();
      int trow = tid >> 2, tc = (tid & 3) * (MR / 4);
      int colg = bn * 128 + ch * 64 + trow;
      int rowg = bm * MR + tc;
      unsigned short* dp = CTp + (long)(rowg >> 8) * sCT + (long)colg * 256 + (rowg & 255);
#pragma unroll
      for (int j = 0; j < MR / 32; ++j)
        *(us8*)(dp + j * 8) = *(const us8*)&Ts[trow][tc + j * 8];
    }
  }
}

// ---------------- attention halves (0..1023, XCD-grouped) + asp (1024..1535) ---------
// Attention block = (b, 16 rows, head-half): 3 head-pairs, per-head softmax sums
// accumulated into part[half] (f32, raw). Dispatch id mapping keeps all 32 blocks
// of one b on the same XCD (id ≡ b mod 8).
__global__ __launch_bounds__(256) void attn_asp(
    const unsigned short* __restrict__ qbf, const unsigned short* __restrict__ kbf,
    const float* __restrict__ srcm,
    float* __restrict__ part0, float* __restrict__ part1,
    const unsigned short* __restrict__ xbf, const unsigned short* __restrict__ wdT,
    const float* __restrict__ amask, const float* __restrict__ bd,
    unsigned short* __restrict__ aspbf) {
  int t = threadIdx.x;
  int w = t >> 6, l = t & 63;
  int lr = l & 15, kg = (l >> 4) * 8;
  if (blockIdx.x >= 1024) {  // ---- asp projection ----
    int l0 = (blockIdx.x - 1024) << 4;
    const unsigned short* ap = xbf + (long)(l0 + lr) * D_ + kg;
    const unsigned short* bp = wdT + (long)(w * 16 + lr) * D_ + kg;
    f32x4 acc = {};
#pragma unroll
    for (int k0 = 0; k0 < D_; k0 += 32) {
      bfrag8 af = *(const bfrag8*)(ap + k0);
      bfrag8 bf = *(const bfrag8*)(bp + k0);
      acc = __builtin_amdgcn_mfma_f32_16x16x32_bf16(af, bf, acc, 0, 0, 0);
    }
    int col = w * 16 + lr;
#pragma unroll
    for (int r = 0; r < 4; ++r) {
      int row = l0 + (l >> 4) * 4 + r;
      float v = acc[r] * amask[row] + bd[col];
      aspbf[(long)row * DK_ + col] = f2bf(v);
    }
    return;
  }
  // XCD-grouped decode: d = r + 8*bhi + 32*(l0c + 16*half), b = r + 8*bhi
  int d = blockIdx.x;
  int b = (d & 7) + 8 * ((d >> 3) & 3);
  int rest = d >> 5;
  int l0 = (rest & 15) << 4;
  int half = rest >> 4;
  int rbase = (l >> 4) * 4;
  __shared__ float red[3][2][16][8];
  float acc[4][4] = {};
  float cmv[4];
#pragma unroll
  for (int ct = 0; ct < 4; ++ct) cmv[ct] = srcm[b * L_ + w * 64 + ct * 16 + lr];

#pragma unroll 1
  for (int ph = 0; ph < 3; ++ph) {
    int hp = half * 3 + ph;
    const unsigned short* ap = qbf + ((long)b * L_ + l0 + lr) * D_ + hp * 128 + kg;
    bfrag8 a00 = *(const bfrag8*)ap;
    bfrag8 a01 = *(const bfrag8*)(ap + 32);
    bfrag8 a10 = *(const bfrag8*)(ap + 64);
    bfrag8 a11 = *(const bfrag8*)(ap + 96);
    bfrag8 kv[4][4];
#pragma unroll
    for (int ct = 0; ct < 4; ++ct) {
      const unsigned short* bp =
          kbf + ((long)b * L_ + w * 64 + ct * 16 + lr) * D_ + hp * 128 + kg;
      kv[ct][0] = *(const bfrag8*)bp;
      kv[ct][1] = *(const bfrag8*)(bp + 32);
      kv[ct][2] = *(const bfrag8*)(bp + 64);
      kv[ct][3] = *(const bfrag8*)(bp + 96);
    }
    float sv0[4][4], sv1[4][4];
#pragma unroll
    for (int ct = 0; ct < 4; ++ct) {
      f32x4 c0 = {}, c1 = {};
      c0 = __builtin_amdgcn_mfma_f32_16x16x32_bf16(a00, kv[ct][0], c0, 0, 0, 0);
      c0 = __builtin_amdgcn_mfma_f32_16x16x32_bf16(a01, kv[ct][1], c0, 0, 0, 0);
      c1 = __builtin_amdgcn_mfma_f32_16x16x32_bf16(a10, kv[ct][2], c1, 0, 0, 0);
      c1 = __builtin_amdgcn_mfma_f32_16x16x32_bf16(a11, kv[ct][3], c1, 0, 0, 0);
      bool msk = (cmv[ct] == 0.f);
#pragma unroll
      for (int r = 0; r < 4; ++r) {
        sv0[ct][r] = msk ? -1e9f : c0[r] * 0.125f;
        sv1[ct][r] = msk ? -1e9f : c1[r] * 0.125f;
      }
    }
    float mx0a[4], mx1a[4];
#pragma unroll
    for (int r = 0; r < 4; ++r) {
      float m0 = fmaxf(fmaxf(sv0[0][r], sv0[1][r]), fmaxf(sv0[2][r], sv0[3][r]));
      float m1 = fmaxf(fmaxf(sv1[0][r], sv1[1][r]), fmaxf(sv1[2][r], sv1[3][r]));
#pragma unroll
      for (int o = 1; o < 16; o <<= 1) {
        m0 = fmaxf(m0, __shfl_xor(m0, o, 64));
        m1 = fmaxf(m1, __shfl_xor(m1, o, 64));
      }
      mx0a[r] = m0; mx1a[r] = m1;
      float s0 = 0.f, s1 = 0.f;
#pragma unroll
      for (int ct = 0; ct < 4; ++ct) {
        float e0 = __expf(sv0[ct][r] - m0);
        float e1 = __expf(sv1[ct][r] - m1);
        sv0[ct][r] = e0; sv1[ct][r] = e1;
        s0 += e0; s1 += e1;
      }
#pragma unroll
      for (int o = 1; o < 16; o <<= 1) {
        s0 += __shfl_xor(s0, o, 64);
        s1 += __shfl_xor(s1, o, 64);
      }
      if (lr == 0) {
        red[ph][0][rbase + r][w] = m0;
        red[ph][0][rbase + r][4 + w] = s0;
        red[ph][1][rbase + r][w] = m1;
        red[ph][1][rbase + r][4 + w] = s1;
      }
    }
    __syncthreads();
#pragma unroll
    for (int r = 0; r < 4; ++r) {
      f32x4 m4 = *(const f32x4*)&red[ph][0][rbase + r][0];
      f32x4 s4 = *(const f32x4*)&red[ph][0][rbase + r][4];
      float mt = fmaxf(fmaxf(m4[0], m4[1]), fmaxf(m4[2], m4[3]));
      float tot = s4[0] * __expf(m4[0] - mt) + s4[1] * __expf(m4[1] - mt) +
                  s4[2] * __expf(m4[2] - mt) + s4[3] * __expf(m4[3] - mt);
      float sc0 = __expf(mx0a[r] - mt) * __builtin_amdgcn_rcpf(tot);
      f32x4 n4 = *(const f32x4*)&red[ph][1][rbase + r][0];
      f32x4 t4 = *(const f32x4*)&red[ph][1][rbase + r][4];
      float nt = fmaxf(fmaxf(n4[0], n4[1]), fmaxf(n4[2], n4[3]));
      float tt = t4[0] * __expf(n4[0] - nt) + t4[1] * __expf(n4[1] - nt) +
                 t4[2] * __expf(n4[2] - nt) + t4[3] * __expf(n4[3] - nt);
      float sc1 = __expf(mx1a[r] - nt) * __builtin_amdgcn_rcpf(tt);
#pragma unroll
      for (int ct = 0; ct < 4; ++ct)
        acc[ct][r] += sv0[ct][r] * sc0 + sv1[ct][r] * sc1;
    }
  }

  float* pp = half ? part1 : part0;
#pragma unroll
  for (int r = 0; r < 4; ++r) {
    int row = l0 + rbase + r;
#pragma unroll
    for (int ct = 0; ct < 4; ++ct) {
      int col = w * 64 + ct * 16 + lr;
      pp[((long)b * L_ + row) * L_ + col] = acc[ct][r];
    }
  }
}

// ---------------- tmpA[b,h] = aspbf[b] @ Wm[h], MFMA, no LDS ----------------
__global__ __launch_bounds__(256) void asp_wm_v2(const unsigned short* __restrict__ aspbf,
                                                 const unsigned short* __restrict__ wmT,
                                                 unsigned short* __restrict__ tmpA) {
  int bh = blockIdx.x;
  int b = bh / H_, h = bh % H_;
  int t = threadIdx.x;
  int w = t >> 6, l = t & 63;
  int lr = l & 15, kg = (l >> 4) * 8;
  const unsigned short* wp = wmT + h * 4096;
  f32x4 acc[4][4] = {};
#pragma unroll
  for (int ks = 0; ks < 2; ++ks) {
    int k0 = ks * 32;
    bfrag8 af[4], bf[4];
#pragma unroll
    for (int m = 0; m < 4; ++m)
      af[m] = *(const bfrag8*)(aspbf + (long)(b * L_ + w * 64 + m * 16 + lr) * DK_ + k0 + kg);
#pragma unroll
    for (int n = 0; n < 4; ++n)
      bf[n] = *(const bfrag8*)(wp + (n * 16 + lr) * 64 + k0 + kg);
#pragma unroll
    for (int m = 0; m < 4; ++m)
#pragma unroll
      for (int n = 0; n < 4; ++n)
        acc[m][n] = __builtin_amdgcn_mfma_f32_16x16x32_bf16(af[m], bf[n], acc[m][n], 0, 0, 0);
  }
#pragma unroll
  for (int m = 0; m < 4; ++m)
#pragma unroll
    for (int n = 0; n < 4; ++n)
#pragma unroll
      for (int r = 0; r < 4; ++r) {
        int row = w * 64 + m * 16 + (l >> 4) * 4 + r;
        int col = n * 16 + lr;
        tmpA[(((long)b * H_ + h) * L_ + row) * DK_ + col] = f2bf(acc[m][n][r]);
      }
}

// ---------------- fused S-GEMM + row softmax, 2-phase DMA staging ----------------
__global__ __launch_bounds__(256) void gemm_sfmx(
    const unsigned short* __restrict__ u1, const unsigned short* __restrict__ g1,
    unsigned short* __restrict__ P1,
    const unsigned short* __restrict__ u2, const unsigned short* __restrict__ g2,
    unsigned short* __restrict__ P2) {
  constexpr int ASH = 64 * 32;        // 2048 shorts (A tile)
  constexpr int BUFS = ASH + 8192;    // + B tile 256x32
  __shared__ alignas(16) unsigned short smem[2 * BUFS];
  __shared__ float redm[2][64];
  __shared__ float reds[2][64];
  int bm = blockIdx.x;
  int bz = blockIdx.y;
  const unsigned short* Ap; const unsigned short* Bp; unsigned short* Pp;
  if (bz < 32) {
    Ap = u1 + (long)bz * L_ * MEM_; Bp = g1 + (long)bz * L_ * MEM_;
    Pp = P1 + (long)bz * L_ * L_;
  } else {
    int z = bz - 32;
    Ap = u2 + (long)z * L_ * MEM_; Bp = g2 + (long)z * L_ * MEM_;
    Pp = P2 + (long)z * L_ * L_;
  }
  const int t = threadIdx.x;
  const int l = t & 63, w = t >> 6;
  const int wr = w >> 1, wc = w & 1;
  const int lr = l & 15, sg = l >> 4;
  f32x4 acc[2][8] = {};

  const int rc = l >> 2;
  const int sslot = (l & 3) ^ ((rc >> 1) & 3);
  const unsigned short* gA = Ap + (long)(bm * 64 + w * 16 + rc) * MEM_ + sslot * 8;
  const unsigned short* gB[4];
#pragma unroll
  for (int j = 0; j < 4; ++j)
    gB[j] = Bp + (long)(w * 64 + j * 16 + rc) * MEM_ + sslot * 8;
  const int stA = w * 512;
  int stB[4];
#pragma unroll
  for (int j = 0; j < 4; ++j) stB[j] = ASH + (w * 4 + j) * 512;

  const int swz = (sg ^ ((lr >> 1) & 3)) * 8;
  int aoff[2], boff[8];
#pragma unroll
  for (int m = 0; m < 2; ++m) aoff[m] = (wr * 32 + m * 16 + lr) * 32 + swz;
#pragma unroll
  for (int n = 0; n < 8; ++n) boff[n] = ASH + (wc * 128 + n * 16 + lr) * 32 + swz;

  // prologue
  gload_lds16(gA, smem + stA);
#pragma unroll
  for (int j = 0; j < 4; ++j) gload_lds16(gB[j], smem + stB[j]);
  __syncthreads();

  constexpr int NT = MEM_ / 32;  // 12
  for (int tt = 0; tt < NT; ++tt) {
    const int cur = (tt & 1) * BUFS;
    if (tt + 1 < NT) {
      const int nxt = ((tt + 1) & 1) * BUFS;
      const int k1 = (tt + 1) << 5;
      gload_lds16(gA + k1, smem + nxt + stA);
#pragma unroll
      for (int j = 0; j < 4; ++j) gload_lds16(gB[j] + k1, smem + nxt + stB[j]);
    }
    bfrag8 af[2], bf[8];
#pragma unroll
    for (int m = 0; m < 2; ++m) af[m] = *(const bfrag8*)(smem + cur + aoff[m]);
#pragma unroll
    for (int n = 0; n < 8; ++n) bf[n] = *(const bfrag8*)(smem + cur + boff[n]);
#pragma unroll
    for (int m = 0; m < 2; ++m)
#pragma unroll
      for (int n = 0; n < 8; ++n)
        acc[m][n] = __builtin_amdgcn_mfma_f32_16x16x32_bf16(af[m], bf[n], acc[m][n], 0, 0, 0);
    __syncthreads();
  }

#pragma unroll
  for (int m = 0; m < 2; ++m) {
#pragma unroll
    for (int r = 0; r < 4; ++r) {
      int lrow = wr * 32 + m * 16 + (l >> 4) * 4 + r;
      float mx = -1e30f;
#pragma unroll
      for (int n = 0; n < 8; ++n) mx = fmaxf(mx, acc[m][n][r]);
#pragma unroll
      for (int o = 1; o < 16; o <<= 1) mx = fmaxf(mx, __shfl_xor(mx, o, 64));
      if (lr == 0) redm[wc][lrow] = mx;
    }
  }
  __syncthreads();
#pragma unroll
  for (int m = 0; m < 2; ++m) {
#pragma unroll
    for (int r = 0; r < 4; ++r) {
      int lrow = wr * 32 + m * 16 + (l >> 4) * 4 + r;
      float mx = fmaxf(redm[0][lrow], redm[1][lrow]);
      float s = 0.f;
#pragma unroll
      for (int n = 0; n < 8; ++n) {
        float e = __expf(acc[m][n][r] - mx);
        acc[m][n][r] = e;
        s += e;
      }
#pragma unroll
      for (int o = 1; o < 16; o <<= 1) s += __shfl_xor(s, o, 64);
      if (lr == 0) reds[wc][lrow] = s;
    }
  }
  __syncthreads();
#pragma unroll
  for (int m = 0; m < 2; ++m) {
#pragma unroll
    for (int r = 0; r < 4; ++r) {
      int lrow = wr * 32 + m * 16 + (l >> 4) * 4 + r;
      float inv = 1.f / (reds[0][lrow] + reds[1][lrow]);
      int row = bm * 64 + lrow;
#pragma unroll
      for (int n = 0; n < 8; ++n) {
        int col = wc * 128 + n * 16 + lr;
        Pp[(long)row * L_ + col] = f2bf(acc[m][n][r] * inv);
      }
    }
  }
}

// ---------------- asps_mean via MFMA ----------------
__global__ __launch_bounds__(256) void asps_mean_v2(
    const unsigned short* __restrict__ tmpA,
    const unsigned short* __restrict__ kbf,
    const float* __restrict__ bias_m,
    float* __restrict__ asps_mean) {
  int blk = blockIdx.x;
  int b = blk >> 4, l0 = (blk & 15) << 4;
  int t = threadIdx.x;
  int w = t >> 6, l = t & 63;
  int lr = l & 15, kg = (l >> 4) * 8;
  float bm = bias_m[0];
  float accg[4][4] = {};
  for (int h = 0; h < H_; ++h) {
    const unsigned short* ap = tmpA + (((long)b * H_ + h) * L_ + l0 + lr) * 64 + kg;
    bfrag8 af0 = *(const bfrag8*)ap;
    bfrag8 af1 = *(const bfrag8*)(ap + 32);
#pragma unroll
    for (int ct = 0; ct < 4; ++ct) {
      const unsigned short* bp =
          kbf + ((long)b * L_ + w * 64 + ct * 16 + lr) * D_ + h * 64 + kg;
      bfrag8 bf0 = *(const bfrag8*)bp;
      bfrag8 bf1 = *(const bfrag8*)(bp + 32);
      f32x4 accl = {};
      accl = __builtin_amdgcn_mfma_f32_16x16x32_bf16(af0, bf0, accl, 0, 0, 0);
      accl = __builtin_amdgcn_mfma_f32_16x16x32_bf16(af1, bf1, accl, 0, 0, 0);
#pragma unroll
      for (int r = 0; r < 4; ++r) accg[ct][r] += tanh_fast(accl[r] + bm);
    }
  }
#pragma unroll
  for (int ct = 0; ct < 4; ++ct) {
    int col = w * 64 + ct * 16 + lr;
#pragma unroll
    for (int r = 0; r < 4; ++r) {
      int row = l0 + (l >> 4) * 4 + r;
      asps_mean[((long)b * L_ + row) * L_ + col] = accg[ct][r] * (1.f / H_);
    }
  }
}

// ---------------- avgH ----------------
__global__ __launch_bounds__(1024) void avgh_kernel(const float* __restrict__ asps_mean,
                                                    float* __restrict__ avgH) {
  int b = blockIdx.x;
  int m = threadIdx.x & 255, q = threadIdx.x >> 8;
  __shared__ float part[4][256];
  float s = 0.f;
  for (int l = q * 64; l < q * 64 + 64; ++l)
    s += asps_mean[((long)b * L_ + l) * L_ + m];
  part[q][m] = s;
  __syncthreads();
  if (q == 0)
    avgH[b * L_ + m] = (part[0][m] + part[1][m] + part[2][m] + part[3][m]) * (1.f / L_);
}

// ---------------- fused adj combine + adj_ag + KL partials + denominators ------------
// Reads attention partial sums (part0+part1), finishes adj_s (diag/mask) -> adjsbf;
// computes adj_ag -> adjagbf; KL row partials and denominators. No f32 adj stores.
__global__ __launch_bounds__(256) void adjag_kl(const float* __restrict__ part0,
                                                const float* __restrict__ part1,
                                                const float* __restrict__ srcm,
                                                const float* __restrict__ asps_mean,
                                                const float* __restrict__ avgH,
                                                const float* __restrict__ amask,
                                                const float* __restrict__ adjr,
                                                unsigned short* __restrict__ adjsbf,
                                                unsigned short* __restrict__ adjagbf,
                                                float* __restrict__ klpart,
                                                float* __restrict__ den_s,
                                                float* __restrict__ den_ag) {
  long row = blockIdx.x;               // b*L + l
  int m = threadIdx.x;
  int l = (int)(row & 255);
  int b = (int)(row >> 8);
  long idx = row * L_ + m;
  // finish adj_s
  float s = (part0[idx] + part1[idx]) * (1.f / H_);
  if (m == l) s = 1.f;
  s *= srcm[b * L_ + l];
  adjsbf[idx] = f2bf(s);
  // adj_ag
  bool rowa = amask[b * L_ + l] > 0.f;
  bool cola = amask[b * L_ + m] > 0.f;
  float asa;
  if (rowa && cola) asa = (l >= m) ? avgH[b * L_ + m] : avgH[b * L_ + l];
  else if (rowa)    asa = avgH[b * L_ + m];
  else if (cola)    asa = avgH[b * L_ + l];
  else              asa = asps_mean[idx];
  float r = (asa > 0.25f) ? 1.f : expf(adjr[idx]);
  float a = r * asa;
  adjagbf[idx] = f2bf(a);

  __shared__ float red[4];
  float sum_s = blkRedSum(s, red);
  float sum_a = blkRedSum(a, red);
  float mx_s = blkRedMax(s, red);
  float mx_a = blkRedMax(a, red);
  float es = expf(s - mx_s), ea = expf(a - mx_a);
  float ses = blkRedSum(es, red);
  float sea = blkRedSum(ea, red);
  float logq = (s - mx_s) - logf(ses);
  float logp = (a - mx_a) - logf(sea);
  float term = (es / ses) * (logq - logp);
  float kp = blkRedSum(term, red);
  if (m == 0) {
    klpart[row] = kp;
    den_s[row] = sum_s + 1.f;
    den_ag[row] = sum_a + 1.f;
  }
}

// ---------------- classifier head (+ KL finish at blockIdx == B_) ----------------
__global__ __launch_bounds__(256) void final_kernel(const unsigned short* __restrict__ o_ag,
                                                    const unsigned short* __restrict__ o_s,
                                                    const float* __restrict__ pooled,
                                                    const float* __restrict__ amask,
                                                    const float* __restrict__ wc,
                                                    const float* __restrict__ bc,
                                                    const float* __restrict__ klpart,
                                                    float* __restrict__ dout) {
  int b = blockIdx.x, t = threadIdx.x;
  __shared__ float red[4];
  if (b == B_) {  // KL finish
    float s = 0.f;
    for (int i = t; i < B_ * L_; i += 256) s += klpart[i];
    s = blkRedSum(s, red);
    if (t == 0) dout[96] = expf(-s * 0.1f);
    return;
  }
  __shared__ float cS[1536];
  __shared__ float maskS[256];
  maskS[t] = amask[b * L_ + t];
  float wn = blkRedSum(maskS[t], red);
  for (int e = t; e < MEM_; e += 256) {
    float s1 = 0.f, s2 = 0.f;
    for (int l = 0; l < L_; ++l) {
      float mk = maskS[l];
      if (mk != 0.f) {
        s1 += mk * bf2f(o_ag[((long)b * L_ + l) * MEM_ + e]);
        s2 += mk * bf2f(o_s[((long)b * L_ + l) * MEM_ + e]);
      }
    }
    cS[e] = s1 / wn;
    cS[MEM_ + e] = s2 / wn;
  }
  for (int j = t; j < D_; j += 256) cS[2 * MEM_ + j] = pooled[b * D_ + j];
  __syncthreads();
  float p0 = 0.f, p1 = 0.f, p2 = 0.f;
  for (int j = t; j < 1536; j += 256) {
    float v = cS[j];
    p0 += v * wc[j * 3 + 0];
    p1 += v * wc[j * 3 + 1];
    p2 += v * wc[j * 3 + 2];
  }
  p0 = blkRedSum(p0, red);
  p1 = blkRedSum(p1, red);
  p2 = blkRedSum(p2, red);
  if (t == 0) {
    dout[b * 3 + 0] = p0 + bc[0];
    dout[b * 3 + 1] = p1 + bc[1];
    dout[b * 3 + 2] = p2 + bc[2];
  }
}

extern "C" void kernel_launch(void* const* d_in, const int* in_sizes, int n_in,
                              void* d_out, int out_size, void* d_ws, size_t ws_size,
                              hipStream_t stream) {
  const float* seq    = (const float*)d_in[0];
  const float* pooled = (const float*)d_in[1];
  const float* adjr   = (const float*)d_in[2];
  const float* srcm   = (const float*)d_in[3];
  const float* amask  = (const float*)d_in[4];
  const float* ln_g   = (const float*)d_in[5];
  const float* ln_b   = (const float*)d_in[6];
  const float* wq     = (const float*)d_in[7];
  const float* bq     = (const float*)d_in[8];
  const float* wk     = (const float*)d_in[9];
  const float* bk     = (const float*)d_in[10];
  const float* wd     = (const float*)d_in[11];
  const float* bd     = (const float*)d_in[12];
  const float* wm     = (const float*)d_in[13];
  const float* bm     = (const float*)d_in[14];
  const float* wa0    = (const float*)d_in[15];
  const float* ba0    = (const float*)d_in[16];
  const float* wa1    = (const float*)d_in[17];
  const float* ba1    = (const float*)d_in[18];
  const float* ws0    = (const float*)d_in[19];
  const float* bs0    = (const float*)d_in[20];
  const float* ws1    = (const float*)d_in[21];
  const float* bs1    = (const float*)d_in[22];
  const float* aff1   = (const float*)d_in[23];
  const float* aff2   = (const float*)d_in[24];
  const float* wc     = (const float*)d_in[25];
  const float* bc     = (const float*)d_in[26];

  float* ws = (float*)d_ws;
  float* S0 = ws;
  float* S1 = S0 + 6291456;
  float* S2 = S1 + 3145728;
  float* S3 = S2 + 3145728;
  float* S4 = S3 + 3145728;
  float* S5 = S4 + 524288;
  float* part0  = S5 + 2097152;          // attn partial (old adj_s region)
  float* part1  = part0 + 2097152;       // attn partial (old adj_ag region)
  unsigned short* adjsbf  = (unsigned short*)(part1 + 2097152);
  unsigned short* adjagbf = adjsbf + 2097152;
  unsigned short* wT      = adjagbf + 2097152;
  unsigned short* wqT   = wT;
  unsigned short* wkT   = wT + 589824;
  unsigned short* wa0T  = wT + 1179648;
  unsigned short* ws0T  = wT + 1474560;
  unsigned short* wa1T  = wT + 1769472;
  unsigned short* ws1T  = wT + 1916928;
  unsigned short* aff1T = wT + 2064384;
  unsigned short* aff2T = wT + 2211840;
  float* tail   = (float*)(wT + 2359296);
  float* avgH   = tail;
  float* den_s  = avgH + 8192;
  float* den_ag = den_s + 8192;
  float* klp    = den_ag + 8192;

  float* x = S0;
  unsigned short* o_agbf = (unsigned short*)S0;
  unsigned short* o_sbf  = o_agbf + 3145728;
  unsigned short* gTag   = o_agbf + 6291456;
  unsigned short* gTs    = o_agbf + 9437184;
  unsigned short* xbf    = (unsigned short*)S1;
  unsigned short* qbf    = (unsigned short*)S2;
  unsigned short* tmpA   = (unsigned short*)S2;
  unsigned short* g_agbf = (unsigned short*)S2;
  unsigned short* g_sbf  = g_agbf + 3145728;
  unsigned short* kbf    = (unsigned short*)S3;
  unsigned short* tTag   = (unsigned short*)S3;
  unsigned short* tTs    = tTag + 3145728;
  unsigned short* u1bf   = (unsigned short*)S3;
  unsigned short* u2bf   = u1bf + 3145728;
  unsigned short* aspbf  = (unsigned short*)S4;
  unsigned short* wdT    = aspbf + 524288;
  unsigned short* wmT    = wdT + 49152;
  float* asps = S5;
  unsigned short* P1bf = (unsigned short*)S5;
  unsigned short* P2bf = P1bf + 2097152;
  float* dout = (float*)d_out;

  const long sAdjSh = (long)L_ * L_;
  const long sMemSh = (long)L_ * MEM_;

  prep_kernel<<<600 + B_ * L_, 256, 0, stream>>>(
      seq, ln_g, ln_b, x, xbf, wq, wqT, wk, wkT, wa0, wa0T, ws0, ws0T,
      wa1, wa1T, ws1, ws1T, aff1, aff1T, aff2, aff2T, wd, wdT, wm, wmT);
  gemm_bb<128><<<dim3(6, 64, 2), 256, 0, stream>>>(
      xbf, wqT, nullptr, qbf, nullptr, 8192, 768, 768, 0, 0, 0, 0, bq, nullptr, 0,
      xbf, wkT, nullptr, kbf, nullptr, bk, nullptr, 1);
  attn_asp<<<1536, 256, 0, stream>>>(qbf, kbf, srcm, part0, part1,
                                     xbf, wdT, amask, bd, aspbf);
  asp_wm_v2<<<B_ * H_, 256, 0, stream>>>(aspbf, wmT, tmpA);
  asps_mean_v2<<<B_ * 16, 256, 0, stream>>>(tmpA, kbf, bm, asps);
  avgh_kernel<<<B_, 1024, 0, stream>>>(asps, avgH);
  adjag_kl<<<B_ * L_, 256, 0, stream>>>(part0, part1, srcm, asps, avgH, amask, adjr,
                                        adjsbf, adjagbf, klp, den_s, den_ag);

  for (int li = 0; li < 2; ++li) {
    int Kd = li ? MEM_ : D_;
    const unsigned short* inag = li ? o_agbf : xbf;
    const unsigned short* ins  = li ? o_sbf : xbf;
    const unsigned short* wAT = li ? wa1T : wa0T;
    const float* bA = li ? ba1 : ba0;
    const unsigned short* wST = li ? ws1T : ws0T;
    const float* bS = li ? bs1 : bs0;
    gemm_bb<64><<<dim3(3, 128, 2), 256, 0, stream>>>(
        inag, wAT, nullptr, nullptr, tTag, 8192, MEM_, Kd, 0, 0, 0, sMemSh,
        nullptr, nullptr, 0,
        ins, wST, nullptr, nullptr, tTs, nullptr, nullptr, 1);
    gemm_bb<64><<<dim3(3, 4, 64), 256, 0, stream>>>(
        adjagbf, tTag, nullptr, g_agbf, gTag, L_, MEM_, L_, sAdjSh, sMemSh, sMemSh,
        sMemSh, bA, den_ag, 1,
        adjsbf, tTs, nullptr, g_sbf, gTs, bS, den_s, 32);
    gemm_bb<64><<<dim3(3, 128, 2), 256, 0, stream>>>(
        g_agbf, aff1T, nullptr, u1bf, nullptr, 8192, MEM_, MEM_, 0, 0, 0, 0,
        nullptr, nullptr, 0,
        g_sbf, aff2T, nullptr, u2bf, nullptr, nullptr, nullptr, 1);
    gemm_sfmx<<<dim3(4, 64), 256, 0, stream>>>(u1bf, g_sbf, P1bf, u2bf, g_agbf, P2bf);
    gemm_bb<64><<<dim3(3, 4, 64), 256, 0, stream>>>(
        P1bf, gTs, nullptr, o_agbf, nullptr, L_, MEM_, L_, sAdjSh, sMemSh, sMemSh, 0,
        nullptr, nullptr, 0,
        P2bf, gTag, nullptr, o_sbf, nullptr, nullptr, nullptr, 32);
  }

  final_kernel<<<B_ + 1, 256, 0, stream>>>(o_agbf, o_sbf, pooled, amask, wc, bc,
                                           klp, dout);
}